// Round 8
// baseline (1707.007 us; speedup 1.0000x reference)
//
#include <hip/hip_runtime.h>

#define N_NODES 100000
#define N_EDGES 1200000
#define DIM_IN 128
#define DIM_H 64
#define DIM_H2 128
#define DIM_OUT 112
#define N_LAYERS 7

__device__ __forceinline__ float wsum(float v) {
#pragma unroll
  for (int m = 1; m < 64; m <<= 1) v += __shfl_xor(v, m, 64);
  return v;
}

// bf16 pack/unpack: bf16->f32 is just <<16 (bit ops, no cvt instruction)
__device__ __forceinline__ unsigned bf16rne(float f) {
  unsigned u = __float_as_uint(f);
  return (u + 0x7fffu + ((u >> 16) & 1u)) >> 16;
}
__device__ __forceinline__ unsigned pack2bf(float lo, float hi) {
  return bf16rne(lo) | (bf16rne(hi) << 16);
}
__device__ __forceinline__ float bflo(unsigned p) { return __uint_as_float(p << 16); }
__device__ __forceinline__ float bfhi(unsigned p) { return __uint_as_float(p & 0xffff0000u); }

// ---------------- preprocessing: CSR build (dst-sorted) ----------------

__global__ void k_zero_i(int* __restrict__ p, int n) {
  int i = blockIdx.x * 256 + threadIdx.x;
  if (i < n) p[i] = 0;
}

__global__ void k_hist(const int* __restrict__ dst, int* __restrict__ counts) {
  int e = blockIdx.x * 256 + threadIdx.x;
  if (e < N_EDGES) atomicAdd(&counts[dst[e]], 1);
}

__global__ void k_scan1(const int* __restrict__ counts, int* __restrict__ bsums) {
  __shared__ int sd[256];
  int t = threadIdx.x;
  int i = blockIdx.x * 256 + t;
  sd[t] = (i < N_NODES) ? counts[i] : 0;
  __syncthreads();
  for (int s = 128; s > 0; s >>= 1) {
    if (t < s) sd[t] += sd[t + s];
    __syncthreads();
  }
  if (t == 0) bsums[blockIdx.x] = sd[0];
}

__global__ void k_scan2(int* __restrict__ bsums, int nb) {
  __shared__ int sd[512];
  int t = threadIdx.x;
  int v = (t < nb) ? bsums[t] : 0;
  sd[t] = v;
  __syncthreads();
  for (int o = 1; o < 512; o <<= 1) {
    int add = (t >= o) ? sd[t - o] : 0;
    __syncthreads();
    sd[t] += add;
    __syncthreads();
  }
  if (t < nb) bsums[t] = sd[t] - v;  // exclusive
}

__global__ void k_scan3(const int* __restrict__ counts, const int* __restrict__ bsums,
                        int* __restrict__ offs) {
  __shared__ int sd[256];
  int t = threadIdx.x;
  int i = blockIdx.x * 256 + t;
  int v = (i < N_NODES) ? counts[i] : 0;
  sd[t] = v;
  __syncthreads();
  for (int o = 1; o < 256; o <<= 1) {
    int add = (t >= o) ? sd[t - o] : 0;
    __syncthreads();
    sd[t] += add;
    __syncthreads();
  }
  int excl = sd[t] - v + bsums[blockIdx.x];
  if (i < N_NODES) offs[i] = excl;
  if (i == N_NODES - 1) offs[N_NODES] = excl + v;  // = E
}

__global__ void k_copy_i(const int* __restrict__ a, int* __restrict__ b, int n) {
  int i = blockIdx.x * 256 + threadIdx.x;
  if (i < n) b[i] = a[i];
}

__global__ void k_scatter(const int* __restrict__ src, const int* __restrict__ dst,
                          int* __restrict__ cursor, int* __restrict__ ssrc) {
  int e = blockIdx.x * 256 + threadIdx.x;
  if (e < N_EDGES) {
    int d = dst[e];
    int p = atomicAdd(&cursor[d], 1);
    ssrc[p] = src[e];
  }
}

// ---------------- encoder: h = x @ enc_W + enc_b ----------------

__global__ __launch_bounds__(256, 3) void k_encoder(const float* __restrict__ x,
                                                    const float* __restrict__ W,
                                                    const float* __restrict__ bias,
                                                    float* __restrict__ h) {
  __shared__ float sx[32][DIM_IN];           // 16KB
  __shared__ float sW[DIM_IN * DIM_H];       // 32KB
  int t = threadIdx.x;
  int node0 = blockIdx.x * 32;
  for (int i = t; i < DIM_IN * DIM_H; i += 256) sW[i] = W[i];
  for (int i = t; i < 32 * DIM_IN; i += 256) {
    int r = i >> 7, c = i & 127;
    sx[r][c] = x[(size_t)(node0 + r) * DIM_IN + c];
  }
  __syncthreads();
  int w = t >> 6, lane = t & 63;
  float acc[8];
#pragma unroll
  for (int j = 0; j < 8; j++) acc[j] = 0.f;
  for (int k0 = 0; k0 < DIM_IN; k0 += 4) {
    float w0 = sW[(k0 + 0) * DIM_H + lane];
    float w1 = sW[(k0 + 1) * DIM_H + lane];
    float w2 = sW[(k0 + 2) * DIM_H + lane];
    float w3 = sW[(k0 + 3) * DIM_H + lane];
#pragma unroll
    for (int j = 0; j < 8; j++) {
      float4 a = *(const float4*)&sx[w * 8 + j][k0];
      acc[j] += a.x * w0 + a.y * w1 + a.z * w2 + a.w * w3;
    }
  }
  float bv = bias[lane];
#pragma unroll
  for (int j = 0; j < 8; j++) {
    int v = node0 + w * 8 + j;
    h[(size_t)v * DIM_H + lane] = acc[j] + bv;
  }
}

// ---------------- fused GENConv layer: edge-softmax-agg + MsgNorm + MLP ------
// Edge phase (wave per node, lane=channel, per-channel softmax lane-local)
// writes hmid directly to sx[] in LDS — no global intermediate. Then the R7
// proven MLP skeleton (bf16-packed weights in LDS, single W2 restage).
// RACE NOTE: edge phase gathers from xin (prev layer's prenorm buffer) while
// epilogue writes rnext — these MUST be different buffers (host ping-pongs).
// h-state (hres/hout) is only accessed at the owning node -> in-place safe.
// LDS 40KB -> 4 blocks/CU. Do NOT raise min-waves (R5/R6 spill).

__global__ __launch_bounds__(256, 2) void k_layer(const float* __restrict__ xin,
                                                  const float* __restrict__ hres,
                                                  float* __restrict__ hout,
                                                  float* __restrict__ rnext,
                                                  const int* __restrict__ ssrc,
                                                  const int* __restrict__ offs,
                                                  const float* __restrict__ t_arr,
                                                  const float* __restrict__ sc_arr,
                                                  const float* __restrict__ W1,
                                                  const float* __restrict__ b1,
                                                  const float* __restrict__ g1,
                                                  const float* __restrict__ bb1,
                                                  const float* __restrict__ W2,
                                                  const float* __restrict__ b2,
                                                  const float* __restrict__ gn,
                                                  const float* __restrict__ bn,
                                                  int layer, int residual) {
  __shared__ unsigned sWp[4096];        // 16KB: W1 as bf16 pairs, then W2
  __shared__ float sx[32][DIM_H];       // 8KB  (edge-phase output = MLP input)
  __shared__ float su[32][DIM_H2];      // 16KB
  int t = threadIdx.x;
  int node0 = blockIdx.x * 32;
  int w = t >> 6, lane = t & 63;
  // stage W1 packed: sWp[kp*128 + c] = (bf(W1[2kp+1][c])<<16) | bf(W1[2kp][c])
  for (int i = t; i < 4096; i += 256) {
    int c = i & 127, kp = i >> 7;
    sWp[i] = pack2bf(W1[(size_t)(2 * kp) * DIM_H2 + c], W1[(size_t)(2 * kp + 1) * DIM_H2 + c]);
  }
  // edge phase: per-channel softmax aggregation + MsgNorm for this wave's 8 nodes
  {
    float tval = t_arr[layer];
    float sc = sc_arr[layer];
    for (int j = 0; j < 8; j++) {
      int v = node0 + w * 8 + j;
      int beg = offs[v], end = offs[v + 1];
      float xv = xin[(size_t)v * DIM_H + lane];
      float D0 = 0.f, S0 = 0.f, D1 = 0.f, S1 = 0.f;
      float D2 = 0.f, S2 = 0.f, D3 = 0.f, S3 = 0.f;
      int e = beg;
      for (; e + 3 < end; e += 4) {
        int s0 = ssrc[e], s1 = ssrc[e + 1], s2 = ssrc[e + 2], s3 = ssrc[e + 3];
        float x0 = xin[(size_t)s0 * DIM_H + lane];
        float x1 = xin[(size_t)s1 * DIM_H + lane];
        float x2 = xin[(size_t)s2 * DIM_H + lane];
        float x3 = xin[(size_t)s3 * DIM_H + lane];
        float m0 = fmaxf(x0, 0.f) + 1e-7f;
        float m1 = fmaxf(x1, 0.f) + 1e-7f;
        float m2 = fmaxf(x2, 0.f) + 1e-7f;
        float m3 = fmaxf(x3, 0.f) + 1e-7f;
        float e0 = __expf(tval * m0);
        float e1 = __expf(tval * m1);
        float e2 = __expf(tval * m2);
        float e3 = __expf(tval * m3);
        D0 += e0; S0 += m0 * e0;
        D1 += e1; S1 += m1 * e1;
        D2 += e2; S2 += m2 * e2;
        D3 += e3; S3 += m3 * e3;
      }
      for (; e < end; ++e) {
        int s0 = ssrc[e];
        float x0 = xin[(size_t)s0 * DIM_H + lane];
        float m0 = fmaxf(x0, 0.f) + 1e-7f;
        float e0 = __expf(tval * m0);
        D0 += e0; S0 += m0 * e0;
      }
      float D = (D0 + D1) + (D2 + D3);
      float S = (S0 + S1) + (S2 + S3);
      float agg = (end > beg) ? (S / D) : 0.f;
      float na = wsum(agg * agg);
      float nx2 = wsum(xv * xv);
      float msg = agg / fmaxf(sqrtf(na), 1e-12f);
      sx[w * 8 + j][lane] = xv + sc * msg * sqrtf(nx2);
    }
  }
  __syncthreads();  // sWp staged (sx rows are read only by the wave that wrote them)
  float a0[8], a1[8];
#pragma unroll
  for (int j = 0; j < 8; j++) { a0[j] = 0.f; a1[j] = 0.f; }
  for (int k0 = 0; k0 < DIM_H; k0 += 4) {
    int kp = k0 >> 1;
    unsigned pa0 = sWp[kp * 128 + lane];
    unsigned pa1 = sWp[(kp + 1) * 128 + lane];
    unsigned pb0 = sWp[kp * 128 + 64 + lane];
    unsigned pb1 = sWp[(kp + 1) * 128 + 64 + lane];
    float wa0 = bflo(pa0), wa1 = bfhi(pa0), wa2 = bflo(pa1), wa3 = bfhi(pa1);
    float wb0 = bflo(pb0), wb1 = bfhi(pb0), wb2 = bflo(pb1), wb3 = bfhi(pb1);
#pragma unroll
    for (int j = 0; j < 8; j++) {
      float4 a = *(const float4*)&sx[w * 8 + j][k0];
      a0[j] += a.x * wa0 + a.y * wa1 + a.z * wa2 + a.w * wa3;
      a1[j] += a.x * wb0 + a.y * wb1 + a.z * wb2 + a.w * wb3;
    }
  }
  float bias0 = b1[lane], bias1 = b1[64 + lane];
  float gg0 = g1[lane], gg1 = g1[64 + lane];
  float be0 = bb1[lane], be1 = bb1[64 + lane];
#pragma unroll
  for (int j = 0; j < 8; j++) {
    float u0 = a0[j] + bias0, u1 = a1[j] + bias1;
    float s = wsum(u0 + u1);
    float s2 = wsum(u0 * u0 + u1 * u1);
    float mu = s * (1.f / 128.f);
    float var = s2 * (1.f / 128.f) - mu * mu;
    float rs = rsqrtf(var + 1e-5f);
    u0 = fmaxf((u0 - mu) * rs * gg0 + be0, 0.f);
    u1 = fmaxf((u1 - mu) * rs * gg1 + be1, 0.f);
    su[w * 8 + j][lane] = u0;
    su[w * 8 + j][64 + lane] = u1;
  }
  __syncthreads();  // all GEMM1 sWp reads + su writes done
  // stage W2 packed: sWp[kp*64 + c], kp in [0,64)
  for (int i = t; i < 4096; i += 256) {
    int c = i & 63, kp = i >> 6;
    sWp[i] = pack2bf(W2[(size_t)(2 * kp) * DIM_H + c], W2[(size_t)(2 * kp + 1) * DIM_H + c]);
  }
  __syncthreads();
  float acc[8];
#pragma unroll
  for (int j = 0; j < 8; j++) acc[j] = 0.f;
  for (int k0 = 0; k0 < DIM_H2; k0 += 4) {
    int kp = k0 >> 1;
    unsigned p0 = sWp[kp * 64 + lane];
    unsigned p1 = sWp[(kp + 1) * 64 + lane];
    float wv0 = bflo(p0), wv1 = bfhi(p0), wv2 = bflo(p1), wv3 = bfhi(p1);
#pragma unroll
    for (int j = 0; j < 8; j++) {
      float4 a = *(const float4*)&su[w * 8 + j][k0];
      acc[j] += a.x * wv0 + a.y * wv1 + a.z * wv2 + a.w * wv3;
    }
  }
  float b2v = b2[lane];
  float gv = gn[lane], bv = bn[lane];
#pragma unroll
  for (int j = 0; j < 8; j++) {
    int v = node0 + w * 8 + j;
    float o = acc[j] + b2v;
    if (residual) o += hres[(size_t)v * DIM_H + lane];
    hout[(size_t)v * DIM_H + lane] = o;
    // fused pre-norm for next stage: relu(LN(o, gn, bn))
    float s = wsum(o);
    float s2 = wsum(o * o);
    float mu = s * (1.f / 64.f);
    float var = s2 * (1.f / 64.f) - mu * mu;
    float rs = rsqrtf(var + 1e-5f);
    rnext[(size_t)v * DIM_H + lane] = fmaxf((o - mu) * rs * gv + bv, 0.f);
  }
}

// ---------------- final: out = rB @ lin_W + lin_b (rB pre-normed) ------------
// Spill-proof shape: thread = (channel c, 4-node group), NO per-thread arrays.

__global__ void k_final(const float* __restrict__ rB, const float* __restrict__ W,
                        const float* __restrict__ bias, float* __restrict__ out) {
  __shared__ float sW[DIM_H * DIM_OUT];  // 28KB
  __shared__ float sx[8][DIM_H];         // 2KB
  int t = threadIdx.x;
  int node0 = blockIdx.x * 8;
  for (int i = t; i < DIM_H * DIM_OUT; i += 256) sW[i] = W[i];
  for (int i = t; i < 8 * DIM_H; i += 256) sx[i >> 6][i & 63] = rB[(size_t)node0 * DIM_H + i];
  __syncthreads();
  int c = t & 127, g = t >> 7;
  int cc = (c < DIM_OUT) ? c : 0;  // keep inactive lanes in-bounds
  int r0 = g * 4;
  float a0 = 0.f, a1 = 0.f, a2 = 0.f, a3 = 0.f;
  for (int k = 0; k < DIM_H; ++k) {
    float wv = sW[k * DIM_OUT + cc];
    a0 += wv * sx[r0 + 0][k];
    a1 += wv * sx[r0 + 1][k];
    a2 += wv * sx[r0 + 2][k];
    a3 += wv * sx[r0 + 3][k];
  }
  if (c < DIM_OUT) {
    float bv = bias[c];
    out[(size_t)(node0 + r0 + 0) * DIM_OUT + c] = a0 + bv;
    out[(size_t)(node0 + r0 + 1) * DIM_OUT + c] = a1 + bv;
    out[(size_t)(node0 + r0 + 2) * DIM_OUT + c] = a2 + bv;
    out[(size_t)(node0 + r0 + 3) * DIM_OUT + c] = a3 + bv;
  }
}

// ---------------- launch ----------------

extern "C" void kernel_launch(void* const* d_in, const int* in_sizes, int n_in,
                              void* d_out, int out_size, void* d_ws, size_t ws_size,
                              hipStream_t stream) {
  const float* x = (const float*)d_in[0];
  const int* ei = (const int*)d_in[1];
  const float* encW = (const float*)d_in[2];
  const float* encb = (const float*)d_in[3];
  const float* t_arr = (const float*)d_in[4];
  const float* sc_arr = (const float*)d_in[5];
  const float* W1 = (const float*)d_in[6];
  const float* b1 = (const float*)d_in[7];
  const float* g1 = (const float*)d_in[8];
  const float* bb1 = (const float*)d_in[9];
  const float* W2 = (const float*)d_in[10];
  const float* b2 = (const float*)d_in[11];
  const float* ng = (const float*)d_in[12];
  const float* nbias = (const float*)d_in[13];
  const float* linW = (const float*)d_in[14];
  const float* linb = (const float*)d_in[15];

  // Buffer plan (ping-pong to avoid the in-kernel gather/write race):
  //   hA: encoder out; layer0 edge input; then becomes an r ping-pong buffer
  //   rB: r ping-pong buffer
  //   mC: h-state (written by layer0, in-place updated by layers 1..6)
  float* hA = (float*)d_ws;                          // N*64 f32
  float* rB = hA + (size_t)N_NODES * DIM_H;          // N*64
  float* mC = rB + (size_t)N_NODES * DIM_H;          // N*64
  int* ssrc = (int*)(mC + (size_t)N_NODES * DIM_H);  // E
  int* offs = ssrc + N_EDGES;                        // N+1
  int* cursor = offs + (N_NODES + 1);                // N
  int* counts = cursor + N_NODES;                    // N
  int* bsums = counts + N_NODES;                     // <=512

  const int* srcI = ei;
  const int* dstI = ei + N_EDGES;

  const int nbScan = (N_NODES + 255) / 256;  // 391
  const int nbEdge = (N_EDGES + 255) / 256;  // 4688

  // CSR build (dst-sorted src list)
  k_zero_i<<<nbScan, 256, 0, stream>>>(counts, N_NODES);
  k_hist<<<nbEdge, 256, 0, stream>>>(dstI, counts);
  k_scan1<<<nbScan, 256, 0, stream>>>(counts, bsums);
  k_scan2<<<1, 512, 0, stream>>>(bsums, nbScan);
  k_scan3<<<nbScan, 256, 0, stream>>>(counts, bsums, offs);
  k_copy_i<<<nbScan, 256, 0, stream>>>(offs, cursor, N_NODES);
  k_scatter<<<nbEdge, 256, 0, stream>>>(srcI, dstI, cursor, ssrc);

  // encoder
  k_encoder<<<N_NODES / 32, 256, 0, stream>>>(x, encW, encb, hA);

  // layer 0: edge input = hA, h-state -> mC, rnext -> rB (nrm_1), no residual
  k_layer<<<N_NODES / 32, 256, 0, stream>>>(
      hA, mC, mC, rB, ssrc, offs, t_arr, sc_arr, W1, b1, g1, bb1, W2, b2,
      ng + 1 * DIM_H, nbias + 1 * DIM_H, 0, 0);

  // layers 1..6: edge input = r-ping, rnext = r-pong (hA free after layer 0);
  // h-state mC updated in place; nrm index i+1 (nrm_0 after layer 6)
  for (int i = 1; i < N_LAYERS; i++) {
    int nx = (i + 1 < N_LAYERS) ? (i + 1) : 0;
    const float* rin = (i & 1) ? rB : hA;
    float* rout = (i & 1) ? hA : rB;
    k_layer<<<N_NODES / 32, 256, 0, stream>>>(
        rin, mC, mC, rout, ssrc, offs, t_arr, sc_arr,
        W1 + (size_t)i * DIM_H * DIM_H2, b1 + i * DIM_H2, g1 + i * DIM_H2,
        bb1 + i * DIM_H2, W2 + (size_t)i * DIM_H2 * DIM_H, b2 + i * DIM_H,
        ng + nx * DIM_H, nbias + nx * DIM_H, i, 1);
  }

  // after layer 6 (i=6 even -> rout = rB): rB = relu(LN(h, nrm_0)); pure GEMM
  k_final<<<N_NODES / 8, 256, 0, stream>>>(rB, linW, linb, (float*)d_out);
}

// Round 9
// 1493.325 us; speedup vs baseline: 1.1431x; 1.1431x over previous
//
#include <hip/hip_runtime.h>

#define N_NODES 100000
#define N_EDGES 1200000
#define DIM_IN 128
#define DIM_H 64
#define DIM_H2 128
#define DIM_OUT 112
#define N_LAYERS 7

__device__ __forceinline__ float wsum(float v) {
#pragma unroll
  for (int m = 1; m < 64; m <<= 1) v += __shfl_xor(v, m, 64);
  return v;
}

// bf16 pack/unpack: bf16->f32 is just <<16 (bit ops, no cvt instruction)
__device__ __forceinline__ unsigned bf16rne(float f) {
  unsigned u = __float_as_uint(f);
  return (u + 0x7fffu + ((u >> 16) & 1u)) >> 16;
}
__device__ __forceinline__ unsigned pack2bf(float lo, float hi) {
  return bf16rne(lo) | (bf16rne(hi) << 16);
}
__device__ __forceinline__ float bflo(unsigned p) { return __uint_as_float(p << 16); }
__device__ __forceinline__ float bfhi(unsigned p) { return __uint_as_float(p & 0xffff0000u); }
__device__ __forceinline__ float bfu(unsigned short u) {
  return __uint_as_float(((unsigned)u) << 16);
}

// ---------------- preprocessing: CSR build (dst-sorted) ----------------

__global__ void k_zero_i(int* __restrict__ p, int n) {
  int i = blockIdx.x * 256 + threadIdx.x;
  if (i < n) p[i] = 0;
}

__global__ void k_hist(const int* __restrict__ dst, int* __restrict__ counts) {
  int e = blockIdx.x * 256 + threadIdx.x;
  if (e < N_EDGES) atomicAdd(&counts[dst[e]], 1);
}

__global__ void k_scan1(const int* __restrict__ counts, int* __restrict__ bsums) {
  __shared__ int sd[256];
  int t = threadIdx.x;
  int i = blockIdx.x * 256 + t;
  sd[t] = (i < N_NODES) ? counts[i] : 0;
  __syncthreads();
  for (int s = 128; s > 0; s >>= 1) {
    if (t < s) sd[t] += sd[t + s];
    __syncthreads();
  }
  if (t == 0) bsums[blockIdx.x] = sd[0];
}

__global__ void k_scan2(int* __restrict__ bsums, int nb) {
  __shared__ int sd[512];
  int t = threadIdx.x;
  int v = (t < nb) ? bsums[t] : 0;
  sd[t] = v;
  __syncthreads();
  for (int o = 1; o < 512; o <<= 1) {
    int add = (t >= o) ? sd[t - o] : 0;
    __syncthreads();
    sd[t] += add;
    __syncthreads();
  }
  if (t < nb) bsums[t] = sd[t] - v;  // exclusive
}

__global__ void k_scan3(const int* __restrict__ counts, const int* __restrict__ bsums,
                        int* __restrict__ offs) {
  __shared__ int sd[256];
  int t = threadIdx.x;
  int i = blockIdx.x * 256 + t;
  int v = (i < N_NODES) ? counts[i] : 0;
  sd[t] = v;
  __syncthreads();
  for (int o = 1; o < 256; o <<= 1) {
    int add = (t >= o) ? sd[t - o] : 0;
    __syncthreads();
    sd[t] += add;
    __syncthreads();
  }
  int excl = sd[t] - v + bsums[blockIdx.x];
  if (i < N_NODES) offs[i] = excl;
  if (i == N_NODES - 1) offs[N_NODES] = excl + v;  // = E
}

__global__ void k_copy_i(const int* __restrict__ a, int* __restrict__ b, int n) {
  int i = blockIdx.x * 256 + threadIdx.x;
  if (i < n) b[i] = a[i];
}

__global__ void k_scatter(const int* __restrict__ src, const int* __restrict__ dst,
                          int* __restrict__ cursor, int* __restrict__ ssrc) {
  int e = blockIdx.x * 256 + threadIdx.x;
  if (e < N_EDGES) {
    int d = dst[e];
    int p = atomicAdd(&cursor[d], 1);
    ssrc[p] = src[e];
  }
}

// ---------------- encoder: hBf = bf16(x @ enc_W + enc_b) ----------------
// Output feeds only layer-0's gather (h-state f32 is produced by layer-0 MLP).

__global__ __launch_bounds__(256, 3) void k_encoder(const float* __restrict__ x,
                                                    const float* __restrict__ W,
                                                    const float* __restrict__ bias,
                                                    unsigned short* __restrict__ hBf) {
  __shared__ float sx[32][DIM_IN];           // 16KB
  __shared__ float sW[DIM_IN * DIM_H];       // 32KB
  int t = threadIdx.x;
  int node0 = blockIdx.x * 32;
  for (int i = t; i < DIM_IN * DIM_H; i += 256) sW[i] = W[i];
  for (int i = t; i < 32 * DIM_IN; i += 256) {
    int r = i >> 7, c = i & 127;
    sx[r][c] = x[(size_t)(node0 + r) * DIM_IN + c];
  }
  __syncthreads();
  int w = t >> 6, lane = t & 63;
  float acc[8];
#pragma unroll
  for (int j = 0; j < 8; j++) acc[j] = 0.f;
  for (int k0 = 0; k0 < DIM_IN; k0 += 4) {
    float w0 = sW[(k0 + 0) * DIM_H + lane];
    float w1 = sW[(k0 + 1) * DIM_H + lane];
    float w2 = sW[(k0 + 2) * DIM_H + lane];
    float w3 = sW[(k0 + 3) * DIM_H + lane];
#pragma unroll
    for (int j = 0; j < 8; j++) {
      float4 a = *(const float4*)&sx[w * 8 + j][k0];
      acc[j] += a.x * w0 + a.y * w1 + a.z * w2 + a.w * w3;
    }
  }
  float bv = bias[lane];
#pragma unroll
  for (int j = 0; j < 8; j++) {
    int v = node0 + w * 8 + j;
    hBf[(size_t)v * DIM_H + lane] = (unsigned short)bf16rne(acc[j] + bv);
  }
}

// ---------------- edge aggregation + MsgNorm (bf16 gather) ----------------
// wave per node, lane = channel; per-channel softmax lane-local.
// xin is bf16: a wave's gather row = 128B (2 cache lines, was 4 in f32).
// No LDS -> 8 blocks/CU, 32 waves: max outstanding gathers. 4-way unroll.

__global__ __launch_bounds__(256) void k_edge(const unsigned short* __restrict__ xin,
                                              const int* __restrict__ ssrc,
                                              const int* __restrict__ offs,
                                              const float* __restrict__ t_arr,
                                              const float* __restrict__ sc_arr, int layer,
                                              float* __restrict__ hmid) {
  int v = blockIdx.x * 4 + (threadIdx.x >> 6);
  int lane = threadIdx.x & 63;
  float tval = t_arr[layer];
  float sc = sc_arr[layer];
  int beg = offs[v], end = offs[v + 1];
  float xv = bfu(xin[(size_t)v * DIM_H + lane]);
  float D0 = 0.f, S0 = 0.f, D1 = 0.f, S1 = 0.f;
  float D2 = 0.f, S2 = 0.f, D3 = 0.f, S3 = 0.f;
  int e = beg;
  for (; e + 3 < end; e += 4) {
    int s0 = ssrc[e], s1 = ssrc[e + 1], s2 = ssrc[e + 2], s3 = ssrc[e + 3];
    float x0 = bfu(xin[(size_t)s0 * DIM_H + lane]);
    float x1 = bfu(xin[(size_t)s1 * DIM_H + lane]);
    float x2 = bfu(xin[(size_t)s2 * DIM_H + lane]);
    float x3 = bfu(xin[(size_t)s3 * DIM_H + lane]);
    float m0 = fmaxf(x0, 0.f) + 1e-7f;
    float m1 = fmaxf(x1, 0.f) + 1e-7f;
    float m2 = fmaxf(x2, 0.f) + 1e-7f;
    float m3 = fmaxf(x3, 0.f) + 1e-7f;
    float e0 = __expf(tval * m0);
    float e1 = __expf(tval * m1);
    float e2 = __expf(tval * m2);
    float e3 = __expf(tval * m3);
    D0 += e0; S0 += m0 * e0;
    D1 += e1; S1 += m1 * e1;
    D2 += e2; S2 += m2 * e2;
    D3 += e3; S3 += m3 * e3;
  }
  for (; e < end; ++e) {
    int s0 = ssrc[e];
    float x0 = bfu(xin[(size_t)s0 * DIM_H + lane]);
    float m0 = fmaxf(x0, 0.f) + 1e-7f;
    float e0 = __expf(tval * m0);
    D0 += e0; S0 += m0 * e0;
  }
  float D = (D0 + D1) + (D2 + D3);
  float S = (S0 + S1) + (S2 + S3);
  float agg = (end > beg) ? (S / D) : 0.f;
  float na = wsum(agg * agg);
  float nx = wsum(xv * xv);
  float msg = agg / fmaxf(sqrtf(na), 1e-12f);
  hmid[(size_t)v * DIM_H + lane] = xv + sc * msg * sqrtf(nx);
}

// ---------------- GENConv MLP + fused next pre-norm ----------------
// out = relu(LN(h@W1+b1))@W2+b2 (+res) -> hout (f32); rnext = bf16(relu(LN(..)))
// R7 proven skeleton: bf16-packed weights in LDS, single W2 restage, (256,2).
// LDS 40KB -> 4 blocks/CU. Do NOT multi-restage or raise min-waves (R5/R6 spill).

__global__ __launch_bounds__(256, 2) void k_mlp(const float* __restrict__ xin,
                                                const float* __restrict__ hres,
                                                float* __restrict__ hout,
                                                unsigned short* __restrict__ rnext,
                                                const float* __restrict__ W1,
                                                const float* __restrict__ b1,
                                                const float* __restrict__ g1,
                                                const float* __restrict__ bb1,
                                                const float* __restrict__ W2,
                                                const float* __restrict__ b2,
                                                const float* __restrict__ gn,
                                                const float* __restrict__ bn, int residual) {
  __shared__ unsigned sWp[4096];        // 16KB: W1 as bf16 pairs, then W2
  __shared__ float sx[32][DIM_H];       // 8KB
  __shared__ float su[32][DIM_H2];      // 16KB
  int t = threadIdx.x;
  int node0 = blockIdx.x * 32;
  // stage W1 packed: sWp[kp*128 + c] = (bf(W1[2kp+1][c])<<16) | bf(W1[2kp][c])
  for (int i = t; i < 4096; i += 256) {
    int c = i & 127, kp = i >> 7;  // consecutive t -> consecutive c: coalesced
    sWp[i] = pack2bf(W1[(size_t)(2 * kp) * DIM_H2 + c], W1[(size_t)(2 * kp + 1) * DIM_H2 + c]);
  }
  for (int i = t; i < 32 * DIM_H; i += 256) {
    int r = i >> 6, c = i & 63;
    sx[r][c] = xin[(size_t)(node0 + r) * DIM_H + c];
  }
  __syncthreads();
  int w = t >> 6, lane = t & 63;
  float a0[8], a1[8];
#pragma unroll
  for (int j = 0; j < 8; j++) { a0[j] = 0.f; a1[j] = 0.f; }
  for (int k0 = 0; k0 < DIM_H; k0 += 4) {
    int kp = k0 >> 1;
    unsigned pa0 = sWp[kp * 128 + lane];
    unsigned pa1 = sWp[(kp + 1) * 128 + lane];
    unsigned pb0 = sWp[kp * 128 + 64 + lane];
    unsigned pb1 = sWp[(kp + 1) * 128 + 64 + lane];
    float wa0 = bflo(pa0), wa1 = bfhi(pa0), wa2 = bflo(pa1), wa3 = bfhi(pa1);
    float wb0 = bflo(pb0), wb1 = bfhi(pb0), wb2 = bflo(pb1), wb3 = bfhi(pb1);
#pragma unroll
    for (int j = 0; j < 8; j++) {
      float4 a = *(const float4*)&sx[w * 8 + j][k0];
      a0[j] += a.x * wa0 + a.y * wa1 + a.z * wa2 + a.w * wa3;
      a1[j] += a.x * wb0 + a.y * wb1 + a.z * wb2 + a.w * wb3;
    }
  }
  float bias0 = b1[lane], bias1 = b1[64 + lane];
  float gg0 = g1[lane], gg1 = g1[64 + lane];
  float be0 = bb1[lane], be1 = bb1[64 + lane];
#pragma unroll
  for (int j = 0; j < 8; j++) {
    float u0 = a0[j] + bias0, u1 = a1[j] + bias1;
    float s = wsum(u0 + u1);
    float s2 = wsum(u0 * u0 + u1 * u1);
    float mu = s * (1.f / 128.f);
    float var = s2 * (1.f / 128.f) - mu * mu;
    float rs = rsqrtf(var + 1e-5f);
    u0 = fmaxf((u0 - mu) * rs * gg0 + be0, 0.f);
    u1 = fmaxf((u1 - mu) * rs * gg1 + be1, 0.f);
    su[w * 8 + j][lane] = u0;
    su[w * 8 + j][64 + lane] = u1;
  }
  __syncthreads();  // all GEMM1 sWp reads + su writes done
  // stage W2 packed: sWp[kp*64 + c], kp in [0,64)
  for (int i = t; i < 4096; i += 256) {
    int c = i & 63, kp = i >> 6;
    sWp[i] = pack2bf(W2[(size_t)(2 * kp) * DIM_H + c], W2[(size_t)(2 * kp + 1) * DIM_H + c]);
  }
  __syncthreads();
  float acc[8];
#pragma unroll
  for (int j = 0; j < 8; j++) acc[j] = 0.f;
  for (int k0 = 0; k0 < DIM_H2; k0 += 4) {
    int kp = k0 >> 1;
    unsigned p0 = sWp[kp * 64 + lane];
    unsigned p1 = sWp[(kp + 1) * 64 + lane];
    float wv0 = bflo(p0), wv1 = bfhi(p0), wv2 = bflo(p1), wv3 = bfhi(p1);
#pragma unroll
    for (int j = 0; j < 8; j++) {
      float4 a = *(const float4*)&su[w * 8 + j][k0];
      acc[j] += a.x * wv0 + a.y * wv1 + a.z * wv2 + a.w * wv3;
    }
  }
  float b2v = b2[lane];
  float gv = gn[lane], bv = bn[lane];
#pragma unroll
  for (int j = 0; j < 8; j++) {
    int v = node0 + w * 8 + j;
    float o = acc[j] + b2v;
    if (residual) o += hres[(size_t)v * DIM_H + lane];
    hout[(size_t)v * DIM_H + lane] = o;
    // fused pre-norm for next stage: bf16(relu(LN(o, gn, bn)))
    float s = wsum(o);
    float s2 = wsum(o * o);
    float mu = s * (1.f / 64.f);
    float var = s2 * (1.f / 64.f) - mu * mu;
    float rs = rsqrtf(var + 1e-5f);
    float r = fmaxf((o - mu) * rs * gv + bv, 0.f);
    rnext[(size_t)v * DIM_H + lane] = (unsigned short)bf16rne(r);
  }
}

// ---------------- final: out = rB @ lin_W + lin_b (rB pre-normed, bf16) ------
// Spill-proof shape: thread = (channel c, 4-node group), NO per-thread arrays.

__global__ void k_final(const unsigned short* __restrict__ rB, const float* __restrict__ W,
                        const float* __restrict__ bias, float* __restrict__ out) {
  __shared__ float sW[DIM_H * DIM_OUT];  // 28KB
  __shared__ float sx[8][DIM_H];         // 2KB
  int t = threadIdx.x;
  int node0 = blockIdx.x * 8;
  for (int i = t; i < DIM_H * DIM_OUT; i += 256) sW[i] = W[i];
  for (int i = t; i < 8 * DIM_H; i += 256) sx[i >> 6][i & 63] = bfu(rB[(size_t)node0 * DIM_H + i]);
  __syncthreads();
  int c = t & 127, g = t >> 7;
  int cc = (c < DIM_OUT) ? c : 0;  // keep inactive lanes in-bounds
  int r0 = g * 4;
  float a0 = 0.f, a1 = 0.f, a2 = 0.f, a3 = 0.f;
  for (int k = 0; k < DIM_H; ++k) {
    float wv = sW[k * DIM_OUT + cc];
    a0 += wv * sx[r0 + 0][k];
    a1 += wv * sx[r0 + 1][k];
    a2 += wv * sx[r0 + 2][k];
    a3 += wv * sx[r0 + 3][k];
  }
  if (c < DIM_OUT) {
    float bv = bias[c];
    out[(size_t)(node0 + r0 + 0) * DIM_OUT + c] = a0 + bv;
    out[(size_t)(node0 + r0 + 1) * DIM_OUT + c] = a1 + bv;
    out[(size_t)(node0 + r0 + 2) * DIM_OUT + c] = a2 + bv;
    out[(size_t)(node0 + r0 + 3) * DIM_OUT + c] = a3 + bv;
  }
}

// ---------------- launch ----------------

extern "C" void kernel_launch(void* const* d_in, const int* in_sizes, int n_in,
                              void* d_out, int out_size, void* d_ws, size_t ws_size,
                              hipStream_t stream) {
  const float* x = (const float*)d_in[0];
  const int* ei = (const int*)d_in[1];
  const float* encW = (const float*)d_in[2];
  const float* encb = (const float*)d_in[3];
  const float* t_arr = (const float*)d_in[4];
  const float* sc_arr = (const float*)d_in[5];
  const float* W1 = (const float*)d_in[6];
  const float* b1 = (const float*)d_in[7];
  const float* g1 = (const float*)d_in[8];
  const float* bb1 = (const float*)d_in[9];
  const float* W2 = (const float*)d_in[10];
  const float* b2 = (const float*)d_in[11];
  const float* ng = (const float*)d_in[12];
  const float* nbias = (const float*)d_in[13];
  const float* linW = (const float*)d_in[14];
  const float* linb = (const float*)d_in[15];

  // Buffers: hA f32 h-state; mC f32 edge-out; rBf/hBf bf16 gather operands.
  // Split kernels serialize on the stream, so a single rBf is race-free.
  float* hA = (float*)d_ws;                                   // N*64 f32
  float* mC = hA + (size_t)N_NODES * DIM_H;                   // N*64 f32
  unsigned short* rBf = (unsigned short*)(mC + (size_t)N_NODES * DIM_H);  // N*64 bf16
  unsigned short* hBf = rBf + (size_t)N_NODES * DIM_H;        // N*64 bf16
  int* ssrc = (int*)(hBf + (size_t)N_NODES * DIM_H);          // E
  int* offs = ssrc + N_EDGES;                                 // N+1
  int* cursor = offs + (N_NODES + 1);                         // N
  int* counts = cursor + N_NODES;                             // N
  int* bsums = counts + N_NODES;                              // <=512

  const int* srcI = ei;
  const int* dstI = ei + N_EDGES;

  const int nbScan = (N_NODES + 255) / 256;  // 391
  const int nbEdge = (N_EDGES + 255) / 256;  // 4688

  // CSR build (dst-sorted src list)
  k_zero_i<<<nbScan, 256, 0, stream>>>(counts, N_NODES);
  k_hist<<<nbEdge, 256, 0, stream>>>(dstI, counts);
  k_scan1<<<nbScan, 256, 0, stream>>>(counts, bsums);
  k_scan2<<<1, 512, 0, stream>>>(bsums, nbScan);
  k_scan3<<<nbScan, 256, 0, stream>>>(counts, bsums, offs);
  k_copy_i<<<nbScan, 256, 0, stream>>>(offs, cursor, N_NODES);
  k_scatter<<<nbEdge, 256, 0, stream>>>(srcI, dstI, cursor, ssrc);

  // encoder -> hBf (bf16)
  k_encoder<<<N_NODES / 32, 256, 0, stream>>>(x, encW, encb, hBf);

  // layers 0..6: gather(bf16) -> mC(f32) -> MLP -> hA(f32) + rBf(bf16)
  for (int i = 0; i < N_LAYERS; i++) {
    int nx = (i + 1 < N_LAYERS) ? (i + 1) : 0;
    const unsigned short* gin = (i == 0) ? hBf : rBf;
    k_edge<<<N_NODES / 4, 256, 0, stream>>>(gin, ssrc, offs, t_arr, sc_arr, i, mC);
    k_mlp<<<N_NODES / 32, 256, 0, stream>>>(
        mC, hA, hA, rBf, W1 + (size_t)i * DIM_H * DIM_H2, b1 + i * DIM_H2, g1 + i * DIM_H2,
        bb1 + i * DIM_H2, W2 + (size_t)i * DIM_H2 * DIM_H, b2 + i * DIM_H,
        ng + nx * DIM_H, nbias + nx * DIM_H, (i > 0) ? 1 : 0);
  }

  // final: rBf = bf16(relu(LN(h, nrm_0))); pure GEMM
  k_final<<<N_NODES / 8, 256, 0, stream>>>(rBf, linW, linb, (float*)d_out);
}

// Round 10
// 1170.193 us; speedup vs baseline: 1.4587x; 1.2761x over previous
//
#include <hip/hip_runtime.h>

#define N_NODES 100000
#define N_EDGES 1200000
#define DIM_IN 128
#define DIM_H 64
#define DIM_H2 128
#define DIM_OUT 112
#define N_LAYERS 7

typedef __attribute__((ext_vector_type(8))) short bf16x8;
typedef __attribute__((ext_vector_type(4))) float f32x4;

__device__ __forceinline__ float wsum(float v) {
#pragma unroll
  for (int m = 1; m < 64; m <<= 1) v += __shfl_xor(v, m, 64);
  return v;
}

// bf16 pack/unpack: bf16->f32 is just <<16 (bit ops, no cvt instruction)
__device__ __forceinline__ unsigned bf16rne(float f) {
  unsigned u = __float_as_uint(f);
  return (u + 0x7fffu + ((u >> 16) & 1u)) >> 16;
}
__device__ __forceinline__ unsigned pack2bf(float lo, float hi) {
  return bf16rne(lo) | (bf16rne(hi) << 16);
}
__device__ __forceinline__ float bfu(unsigned short u) {
  return __uint_as_float(((unsigned)u) << 16);
}

// ---------------- preprocessing: CSR build (dst-sorted) ----------------

__global__ void k_zero_i(int* __restrict__ p, int n) {
  int i = blockIdx.x * 256 + threadIdx.x;
  if (i < n) p[i] = 0;
}

__global__ void k_hist(const int* __restrict__ dst, int* __restrict__ counts) {
  int e = blockIdx.x * 256 + threadIdx.x;
  if (e < N_EDGES) atomicAdd(&counts[dst[e]], 1);
}

__global__ void k_scan1(const int* __restrict__ counts, int* __restrict__ bsums) {
  __shared__ int sd[256];
  int t = threadIdx.x;
  int i = blockIdx.x * 256 + t;
  sd[t] = (i < N_NODES) ? counts[i] : 0;
  __syncthreads();
  for (int s = 128; s > 0; s >>= 1) {
    if (t < s) sd[t] += sd[t + s];
    __syncthreads();
  }
  if (t == 0) bsums[blockIdx.x] = sd[0];
}

__global__ void k_scan2(int* __restrict__ bsums, int nb) {
  __shared__ int sd[512];
  int t = threadIdx.x;
  int v = (t < nb) ? bsums[t] : 0;
  sd[t] = v;
  __syncthreads();
  for (int o = 1; o < 512; o <<= 1) {
    int add = (t >= o) ? sd[t - o] : 0;
    __syncthreads();
    sd[t] += add;
    __syncthreads();
  }
  if (t < nb) bsums[t] = sd[t] - v;  // exclusive
}

__global__ void k_scan3(const int* __restrict__ counts, const int* __restrict__ bsums,
                        int* __restrict__ offs) {
  __shared__ int sd[256];
  int t = threadIdx.x;
  int i = blockIdx.x * 256 + t;
  int v = (i < N_NODES) ? counts[i] : 0;
  sd[t] = v;
  __syncthreads();
  for (int o = 1; o < 256; o <<= 1) {
    int add = (t >= o) ? sd[t - o] : 0;
    __syncthreads();
    sd[t] += add;
    __syncthreads();
  }
  int excl = sd[t] - v + bsums[blockIdx.x];
  if (i < N_NODES) offs[i] = excl;
  if (i == N_NODES - 1) offs[N_NODES] = excl + v;  // = E
}

__global__ void k_copy_i(const int* __restrict__ a, int* __restrict__ b, int n) {
  int i = blockIdx.x * 256 + threadIdx.x;
  if (i < n) b[i] = a[i];
}

__global__ void k_scatter(const int* __restrict__ src, const int* __restrict__ dst,
                          int* __restrict__ cursor, int* __restrict__ ssrc) {
  int e = blockIdx.x * 256 + threadIdx.x;
  if (e < N_EDGES) {
    int d = dst[e];
    int p = atomicAdd(&cursor[d], 1);
    ssrc[p] = src[e];
  }
}

// ---------------- encoder: hBf = bf16(x @ enc_W + enc_b) ----------------

__global__ __launch_bounds__(256, 3) void k_encoder(const float* __restrict__ x,
                                                    const float* __restrict__ W,
                                                    const float* __restrict__ bias,
                                                    unsigned short* __restrict__ hBf) {
  __shared__ float sx[32][DIM_IN];           // 16KB
  __shared__ float sW[DIM_IN * DIM_H];       // 32KB
  int t = threadIdx.x;
  int node0 = blockIdx.x * 32;
  for (int i = t; i < DIM_IN * DIM_H; i += 256) sW[i] = W[i];
  for (int i = t; i < 32 * DIM_IN; i += 256) {
    int r = i >> 7, c = i & 127;
    sx[r][c] = x[(size_t)(node0 + r) * DIM_IN + c];
  }
  __syncthreads();
  int w = t >> 6, lane = t & 63;
  float acc[8];
#pragma unroll
  for (int j = 0; j < 8; j++) acc[j] = 0.f;
  for (int k0 = 0; k0 < DIM_IN; k0 += 4) {
    float w0 = sW[(k0 + 0) * DIM_H + lane];
    float w1 = sW[(k0 + 1) * DIM_H + lane];
    float w2 = sW[(k0 + 2) * DIM_H + lane];
    float w3 = sW[(k0 + 3) * DIM_H + lane];
#pragma unroll
    for (int j = 0; j < 8; j++) {
      float4 a = *(const float4*)&sx[w * 8 + j][k0];
      acc[j] += a.x * w0 + a.y * w1 + a.z * w2 + a.w * w3;
    }
  }
  float bv = bias[lane];
#pragma unroll
  for (int j = 0; j < 8; j++) {
    int v = node0 + w * 8 + j;
    hBf[(size_t)v * DIM_H + lane] = (unsigned short)bf16rne(acc[j] + bv);
  }
}

// ---------------- edge aggregation + MsgNorm (bf16 gather) ----------------
// wave per node, lane = channel; per-channel softmax lane-local.

__global__ __launch_bounds__(256) void k_edge(const unsigned short* __restrict__ xin,
                                              const int* __restrict__ ssrc,
                                              const int* __restrict__ offs,
                                              const float* __restrict__ t_arr,
                                              const float* __restrict__ sc_arr, int layer,
                                              float* __restrict__ hmid) {
  int v = blockIdx.x * 4 + (threadIdx.x >> 6);
  int lane = threadIdx.x & 63;
  float tval = t_arr[layer];
  float sc = sc_arr[layer];
  int beg = offs[v], end = offs[v + 1];
  float xv = bfu(xin[(size_t)v * DIM_H + lane]);
  float D0 = 0.f, S0 = 0.f, D1 = 0.f, S1 = 0.f;
  float D2 = 0.f, S2 = 0.f, D3 = 0.f, S3 = 0.f;
  int e = beg;
  for (; e + 3 < end; e += 4) {
    int s0 = ssrc[e], s1 = ssrc[e + 1], s2 = ssrc[e + 2], s3 = ssrc[e + 3];
    float x0 = bfu(xin[(size_t)s0 * DIM_H + lane]);
    float x1 = bfu(xin[(size_t)s1 * DIM_H + lane]);
    float x2 = bfu(xin[(size_t)s2 * DIM_H + lane]);
    float x3 = bfu(xin[(size_t)s3 * DIM_H + lane]);
    float m0 = fmaxf(x0, 0.f) + 1e-7f;
    float m1 = fmaxf(x1, 0.f) + 1e-7f;
    float m2 = fmaxf(x2, 0.f) + 1e-7f;
    float m3 = fmaxf(x3, 0.f) + 1e-7f;
    float e0 = __expf(tval * m0);
    float e1 = __expf(tval * m1);
    float e2 = __expf(tval * m2);
    float e3 = __expf(tval * m3);
    D0 += e0; S0 += m0 * e0;
    D1 += e1; S1 += m1 * e1;
    D2 += e2; S2 += m2 * e2;
    D3 += e3; S3 += m3 * e3;
  }
  for (; e < end; ++e) {
    int s0 = ssrc[e];
    float x0 = bfu(xin[(size_t)s0 * DIM_H + lane]);
    float m0 = fmaxf(x0, 0.f) + 1e-7f;
    float e0 = __expf(tval * m0);
    D0 += e0; S0 += m0 * e0;
  }
  float D = (D0 + D1) + (D2 + D3);
  float S = (S0 + S1) + (S2 + S3);
  float agg = (end > beg) ? (S / D) : 0.f;
  float na = wsum(agg * agg);
  float nx = wsum(xv * xv);
  float msg = agg / fmaxf(sqrtf(na), 1e-12f);
  hmid[(size_t)v * DIM_H + lane] = xv + sc * msg * sqrtf(nx);
}

// ---------------- GENConv MLP via MFMA + fused next pre-norm ----------------
// GEMM1: C1[32,128] = X[32,64] @ W1; LN+relu -> U bf16; GEMM2: C2[32,64] =
// U @ W2; epilogue: +b2 (+res) -> hout f32, prenorm -> rnext bf16.
// mfma_f32_16x16x32_bf16, m89/m93-verified layouts: A [m][k] row-major
// (lane: row=l&15, k=(l>>4)*8+e contiguous -> one b128), B as [n][k] (B^T,
// same recipe), D: row=(l>>4)*4+r, col=l&15. LDS strides 36/68 uints keep
// 16B alignment and break power-of-2 bank stride. 5 barrier phases; single
// W2 restage (R7-proven; NOT the R5/R6 in-loop restage that spilled).

__global__ __launch_bounds__(256, 2) void k_mlp(const float* __restrict__ xin,
                                                const float* __restrict__ hres,
                                                float* __restrict__ hout,
                                                unsigned short* __restrict__ rnext,
                                                const float* __restrict__ W1,
                                                const float* __restrict__ b1,
                                                const float* __restrict__ g1,
                                                const float* __restrict__ bb1,
                                                const float* __restrict__ W2,
                                                const float* __restrict__ b2,
                                                const float* __restrict__ gn,
                                                const float* __restrict__ bn, int residual) {
  __shared__ __attribute__((aligned(16))) unsigned sWb[128 * 36];  // 18.4KB: W1 [n<128][kp<32] s36; then W2 [n<64][kp<64] s68
  __shared__ __attribute__((aligned(16))) unsigned sxp[32 * 36];   // 4.6KB:  X packed [row][kp<32] s36
  __shared__ __attribute__((aligned(16))) float sf[32 * 132];      // 16.9KB: C1 [row][c<128] s132; then C2 [row][c<64] s68
  __shared__ __attribute__((aligned(16))) unsigned sub[32 * 68];   // 8.7KB:  U packed [row][kp<64] s68
  int t = threadIdx.x;
  int node0 = blockIdx.x * 32;
  int w = t >> 6, lane = t & 63;
  int fr = lane & 15, fq = lane >> 4;

  // phase 1: stage W1 (bf16-pair, [n][kp]) + X (bf16-pair, [row][kp])
  for (int i = t; i < 4096; i += 256) {
    int n = i & 127, kp = i >> 7;  // consecutive t -> consecutive n: coalesced
    sWb[n * 36 + kp] = pack2bf(W1[(size_t)(2 * kp) * DIM_H2 + n],
                               W1[(size_t)(2 * kp + 1) * DIM_H2 + n]);
  }
  for (int i = t; i < 1024; i += 256) {
    int row = i >> 5, kp = i & 31;
    float2 xv = *(const float2*)&xin[(size_t)(node0 + row) * DIM_H + 2 * kp];
    sxp[row * 36 + kp] = pack2bf(xv.x, xv.y);
  }
  __syncthreads();

  // phase 2: GEMM1 — wave w owns n-tiles {2w, 2w+1}, m-tiles {0,1}
  {
    f32x4 acc00 = {0.f, 0.f, 0.f, 0.f}, acc01 = acc00, acc10 = acc00, acc11 = acc00;
#pragma unroll
    for (int s = 0; s < 2; s++) {
      int kp0 = s * 16 + fq * 4;
      bf16x8 a0 = *(const bf16x8*)&sxp[(0 * 16 + fr) * 36 + kp0];
      bf16x8 a1 = *(const bf16x8*)&sxp[(1 * 16 + fr) * 36 + kp0];
      bf16x8 w0 = *(const bf16x8*)&sWb[((2 * w) * 16 + fr) * 36 + kp0];
      bf16x8 w1 = *(const bf16x8*)&sWb[((2 * w + 1) * 16 + fr) * 36 + kp0];
      acc00 = __builtin_amdgcn_mfma_f32_16x16x32_bf16(a0, w0, acc00, 0, 0, 0);
      acc01 = __builtin_amdgcn_mfma_f32_16x16x32_bf16(a0, w1, acc01, 0, 0, 0);
      acc10 = __builtin_amdgcn_mfma_f32_16x16x32_bf16(a1, w0, acc10, 0, 0, 0);
      acc11 = __builtin_amdgcn_mfma_f32_16x16x32_bf16(a1, w1, acc11, 0, 0, 0);
    }
#pragma unroll
    for (int r = 0; r < 4; r++) {
      sf[(fq * 4 + r) * 132 + (2 * w) * 16 + fr] = acc00[r];
      sf[(fq * 4 + r) * 132 + (2 * w + 1) * 16 + fr] = acc01[r];
      sf[(16 + fq * 4 + r) * 132 + (2 * w) * 16 + fr] = acc10[r];
      sf[(16 + fq * 4 + r) * 132 + (2 * w + 1) * 16 + fr] = acc11[r];
    }
  }
  __syncthreads();

  // phase 3: restage W2 ([n<64][kp<64] s68) + LN/relu/pack U (wave w: rows w*8..+7)
  for (int i = t; i < 4096; i += 256) {
    int n = i & 63, kp = i >> 6;
    sWb[n * 68 + kp] = pack2bf(W2[(size_t)(2 * kp) * DIM_H + n],
                               W2[(size_t)(2 * kp + 1) * DIM_H + n]);
  }
  {
    float bias0 = b1[lane], bias1 = b1[64 + lane];
    float gg0 = g1[lane], gg1 = g1[64 + lane];
    float be0 = bb1[lane], be1 = bb1[64 + lane];
#pragma unroll
    for (int j = 0; j < 8; j++) {
      int row = w * 8 + j;
      float u0 = sf[row * 132 + lane] + bias0;
      float u1 = sf[row * 132 + 64 + lane] + bias1;
      float s = wsum(u0 + u1);
      float s2 = wsum(u0 * u0 + u1 * u1);
      float mu = s * (1.f / 128.f);
      float var = s2 * (1.f / 128.f) - mu * mu;
      float rs = rsqrtf(var + 1e-5f);
      u0 = fmaxf((u0 - mu) * rs * gg0 + be0, 0.f);
      u1 = fmaxf((u1 - mu) * rs * gg1 + be1, 0.f);
      // pack channels (2*lane, 2*lane+1) into sub[row][kp=lane]:
      // c<64 lives in u0 of lane c; c>=64 in u1 of lane c-64.
      int c2 = (2 * lane) & 63;
      float e0 = __shfl(u0, c2, 64), f0 = __shfl(u1, c2, 64);
      float e1 = __shfl(u0, c2 + 1, 64), f1 = __shfl(u1, c2 + 1, 64);
      float lo = (lane < 32) ? e0 : f0;
      float hi = (lane < 32) ? e1 : f1;
      sub[row * 68 + lane] = pack2bf(lo, hi);
    }
  }
  __syncthreads();

  // phase 4: GEMM2 — wave w: m-tile w>>1, n-tiles {2*(w&1), 2*(w&1)+1}
  {
    int mt = w >> 1, nt0 = (w & 1) * 2;
    f32x4 acc0 = {0.f, 0.f, 0.f, 0.f}, acc1 = acc0;
#pragma unroll
    for (int s = 0; s < 4; s++) {
      int kp0 = s * 16 + fq * 4;
      bf16x8 a = *(const bf16x8*)&sub[(mt * 16 + fr) * 68 + kp0];
      bf16x8 w0 = *(const bf16x8*)&sWb[(nt0 * 16 + fr) * 68 + kp0];
      bf16x8 w1 = *(const bf16x8*)&sWb[((nt0 + 1) * 16 + fr) * 68 + kp0];
      acc0 = __builtin_amdgcn_mfma_f32_16x16x32_bf16(a, w0, acc0, 0, 0, 0);
      acc1 = __builtin_amdgcn_mfma_f32_16x16x32_bf16(a, w1, acc1, 0, 0, 0);
    }
#pragma unroll
    for (int r = 0; r < 4; r++) {
      sf[(mt * 16 + fq * 4 + r) * 68 + nt0 * 16 + fr] = acc0[r];
      sf[(mt * 16 + fq * 4 + r) * 68 + (nt0 + 1) * 16 + fr] = acc1[r];
    }
  }
  __syncthreads();

  // phase 5: epilogue — +b2 (+res) -> hout f32; prenorm -> rnext bf16
  {
    float b2v = b2[lane], gv = gn[lane], bv = bn[lane];
#pragma unroll
    for (int j = 0; j < 8; j++) {
      int row = w * 8 + j;
      int v = node0 + row;
      float o = sf[row * 68 + lane] + b2v;
      if (residual) o += hres[(size_t)v * DIM_H + lane];
      hout[(size_t)v * DIM_H + lane] = o;
      float s = wsum(o);
      float s2 = wsum(o * o);
      float mu = s * (1.f / 64.f);
      float var = s2 * (1.f / 64.f) - mu * mu;
      float rs = rsqrtf(var + 1e-5f);
      float r = fmaxf((o - mu) * rs * gv + bv, 0.f);
      rnext[(size_t)v * DIM_H + lane] = (unsigned short)bf16rne(r);
    }
  }
}

// ---------------- final: out = rB @ lin_W + lin_b (rB pre-normed, bf16) ------
// Spill-proof shape: thread = (channel c, 4-node group), NO per-thread arrays.

__global__ void k_final(const unsigned short* __restrict__ rB, const float* __restrict__ W,
                        const float* __restrict__ bias, float* __restrict__ out) {
  __shared__ float sW[DIM_H * DIM_OUT];  // 28KB
  __shared__ float sx[8][DIM_H];         // 2KB
  int t = threadIdx.x;
  int node0 = blockIdx.x * 8;
  for (int i = t; i < DIM_H * DIM_OUT; i += 256) sW[i] = W[i];
  for (int i = t; i < 8 * DIM_H; i += 256) sx[i >> 6][i & 63] = bfu(rB[(size_t)node0 * DIM_H + i]);
  __syncthreads();
  int c = t & 127, g = t >> 7;
  int cc = (c < DIM_OUT) ? c : 0;  // keep inactive lanes in-bounds
  int r0 = g * 4;
  float a0 = 0.f, a1 = 0.f, a2 = 0.f, a3 = 0.f;
  for (int k = 0; k < DIM_H; ++k) {
    float wv = sW[k * DIM_OUT + cc];
    a0 += wv * sx[r0 + 0][k];
    a1 += wv * sx[r0 + 1][k];
    a2 += wv * sx[r0 + 2][k];
    a3 += wv * sx[r0 + 3][k];
  }
  if (c < DIM_OUT) {
    float bv = bias[c];
    out[(size_t)(node0 + r0 + 0) * DIM_OUT + c] = a0 + bv;
    out[(size_t)(node0 + r0 + 1) * DIM_OUT + c] = a1 + bv;
    out[(size_t)(node0 + r0 + 2) * DIM_OUT + c] = a2 + bv;
    out[(size_t)(node0 + r0 + 3) * DIM_OUT + c] = a3 + bv;
  }
}

// ---------------- launch ----------------

extern "C" void kernel_launch(void* const* d_in, const int* in_sizes, int n_in,
                              void* d_out, int out_size, void* d_ws, size_t ws_size,
                              hipStream_t stream) {
  const float* x = (const float*)d_in[0];
  const int* ei = (const int*)d_in[1];
  const float* encW = (const float*)d_in[2];
  const float* encb = (const float*)d_in[3];
  const float* t_arr = (const float*)d_in[4];
  const float* sc_arr = (const float*)d_in[5];
  const float* W1 = (const float*)d_in[6];
  const float* b1 = (const float*)d_in[7];
  const float* g1 = (const float*)d_in[8];
  const float* bb1 = (const float*)d_in[9];
  const float* W2 = (const float*)d_in[10];
  const float* b2 = (const float*)d_in[11];
  const float* ng = (const float*)d_in[12];
  const float* nbias = (const float*)d_in[13];
  const float* linW = (const float*)d_in[14];
  const float* linb = (const float*)d_in[15];

  float* hA = (float*)d_ws;                                   // N*64 f32 h-state
  float* mC = hA + (size_t)N_NODES * DIM_H;                   // N*64 f32 edge-out
  unsigned short* rBf = (unsigned short*)(mC + (size_t)N_NODES * DIM_H);  // N*64 bf16
  unsigned short* hBf = rBf + (size_t)N_NODES * DIM_H;        // N*64 bf16
  int* ssrc = (int*)(hBf + (size_t)N_NODES * DIM_H);          // E
  int* offs = ssrc + N_EDGES;                                 // N+1
  int* cursor = offs + (N_NODES + 1);                         // N
  int* counts = cursor + N_NODES;                             // N
  int* bsums = counts + N_NODES;                              // <=512

  const int* srcI = ei;
  const int* dstI = ei + N_EDGES;

  const int nbScan = (N_NODES + 255) / 256;  // 391
  const int nbEdge = (N_EDGES + 255) / 256;  // 4688

  // CSR build (dst-sorted src list)
  k_zero_i<<<nbScan, 256, 0, stream>>>(counts, N_NODES);
  k_hist<<<nbEdge, 256, 0, stream>>>(dstI, counts);
  k_scan1<<<nbScan, 256, 0, stream>>>(counts, bsums);
  k_scan2<<<1, 512, 0, stream>>>(bsums, nbScan);
  k_scan3<<<nbScan, 256, 0, stream>>>(counts, bsums, offs);
  k_copy_i<<<nbScan, 256, 0, stream>>>(offs, cursor, N_NODES);
  k_scatter<<<nbEdge, 256, 0, stream>>>(srcI, dstI, cursor, ssrc);

  // encoder -> hBf (bf16)
  k_encoder<<<N_NODES / 32, 256, 0, stream>>>(x, encW, encb, hBf);

  // layers 0..6: gather(bf16) -> mC(f32) -> MFMA MLP -> hA(f32) + rBf(bf16)
  for (int i = 0; i < N_LAYERS; i++) {
    int nx = (i + 1 < N_LAYERS) ? (i + 1) : 0;
    const unsigned short* gin = (i == 0) ? hBf : rBf;
    k_edge<<<N_NODES / 4, 256, 0, stream>>>(gin, ssrc, offs, t_arr, sc_arr, i, mC);
    k_mlp<<<N_NODES / 32, 256, 0, stream>>>(
        mC, hA, hA, rBf, W1 + (size_t)i * DIM_H * DIM_H2, b1 + i * DIM_H2, g1 + i * DIM_H2,
        bb1 + i * DIM_H2, W2 + (size_t)i * DIM_H2 * DIM_H, b2 + i * DIM_H,
        ng + nx * DIM_H, nbias + nx * DIM_H, (i > 0) ? 1 : 0);
  }

  // final: rBf = bf16(relu(LN(h, nrm_0))); pure GEMM
  k_final<<<N_NODES / 8, 256, 0, stream>>>(rBf, linW, linb, (float*)d_out);
}

// Round 11
// 1102.465 us; speedup vs baseline: 1.5484x; 1.0614x over previous
//
#include <hip/hip_runtime.h>

#define N_NODES 100000
#define N_EDGES 1200000
#define DIM_IN 128
#define DIM_H 64
#define DIM_H2 128
#define DIM_OUT 112
#define N_LAYERS 7

// pre-packed weight sizes (uints), padded strides baked in
#define W1P_SZ 4608  // 128 n * 36 kp-stride (kp<32 valid)
#define W2P_SZ 4352  // 64 n * 68 kp-stride (kp<64 valid)

typedef __attribute__((ext_vector_type(8))) short bf16x8;
typedef __attribute__((ext_vector_type(4))) float f32x4;

__device__ __forceinline__ float wsum(float v) {
#pragma unroll
  for (int m = 1; m < 64; m <<= 1) v += __shfl_xor(v, m, 64);
  return v;
}

// bf16 pack/unpack: bf16->f32 is just <<16 (bit ops, no cvt instruction)
__device__ __forceinline__ unsigned bf16rne(float f) {
  unsigned u = __float_as_uint(f);
  return (u + 0x7fffu + ((u >> 16) & 1u)) >> 16;
}
__device__ __forceinline__ unsigned pack2bf(float lo, float hi) {
  return bf16rne(lo) | (bf16rne(hi) << 16);
}
__device__ __forceinline__ float bfu(unsigned short u) {
  return __uint_as_float(((unsigned)u) << 16);
}

// ---------------- preprocessing: CSR build (dst-sorted) ----------------

__global__ void k_zero_i(int* __restrict__ p, int n) {
  int i = blockIdx.x * 256 + threadIdx.x;
  if (i < n) p[i] = 0;
}

__global__ void k_hist(const int* __restrict__ dst, int* __restrict__ counts) {
  int e = blockIdx.x * 256 + threadIdx.x;
  if (e < N_EDGES) atomicAdd(&counts[dst[e]], 1);
}

__global__ void k_scan1(const int* __restrict__ counts, int* __restrict__ bsums) {
  __shared__ int sd[256];
  int t = threadIdx.x;
  int i = blockIdx.x * 256 + t;
  sd[t] = (i < N_NODES) ? counts[i] : 0;
  __syncthreads();
  for (int s = 128; s > 0; s >>= 1) {
    if (t < s) sd[t] += sd[t + s];
    __syncthreads();
  }
  if (t == 0) bsums[blockIdx.x] = sd[0];
}

__global__ void k_scan2(int* __restrict__ bsums, int nb) {
  __shared__ int sd[512];
  int t = threadIdx.x;
  int v = (t < nb) ? bsums[t] : 0;
  sd[t] = v;
  __syncthreads();
  for (int o = 1; o < 512; o <<= 1) {
    int add = (t >= o) ? sd[t - o] : 0;
    __syncthreads();
    sd[t] += add;
    __syncthreads();
  }
  if (t < nb) bsums[t] = sd[t] - v;  // exclusive
}

__global__ void k_scan3(const int* __restrict__ counts, const int* __restrict__ bsums,
                        int* __restrict__ offs) {
  __shared__ int sd[256];
  int t = threadIdx.x;
  int i = blockIdx.x * 256 + t;
  int v = (i < N_NODES) ? counts[i] : 0;
  sd[t] = v;
  __syncthreads();
  for (int o = 1; o < 256; o <<= 1) {
    int add = (t >= o) ? sd[t - o] : 0;
    __syncthreads();
    sd[t] += add;
    __syncthreads();
  }
  int excl = sd[t] - v + bsums[blockIdx.x];
  if (i < N_NODES) offs[i] = excl;
  if (i == N_NODES - 1) offs[N_NODES] = excl + v;  // = E
}

__global__ void k_copy_i(const int* __restrict__ a, int* __restrict__ b, int n) {
  int i = blockIdx.x * 256 + threadIdx.x;
  if (i < n) b[i] = a[i];
}

// XCD-partitioned scatter: block b handles only dst in [(b&7)*12500, +12500).
// Under %8 round-robin block->XCD dispatch, each partition's ssrc region
// (contiguous ~600KB) is written by one XCD -> no cross-XCD line ping-pong
// (R10: 83MB WRITE for 4.8MB of data). Correct for ANY block->XCD mapping.
__global__ void k_scatter(const int* __restrict__ src, const int* __restrict__ dst,
                          int* __restrict__ cursor, int* __restrict__ ssrc) {
  int part = blockIdx.x & 7;
  int e = (blockIdx.x >> 3) * 256 + threadIdx.x;
  if (e < N_EDGES) {
    int d = dst[e];
    if ((unsigned)(d - part * (N_NODES / 8)) < (unsigned)(N_NODES / 8)) {
      int p = atomicAdd(&cursor[d], 1);
      ssrc[p] = src[e];
    }
  }
}

// ---------------- weight pre-pack (once per launch, ~2us) ----------------
// W1p[L][n*36+kp] = pack2bf(W1[L][2kp][n], W1[L][2kp+1][n]); W2p same s68.
__global__ void k_prepack(const float* __restrict__ W1, const float* __restrict__ W2,
                          unsigned* __restrict__ W1p, unsigned* __restrict__ W2p) {
  int L = blockIdx.y;
  const float* w1 = W1 + (size_t)L * DIM_H * DIM_H2;
  const float* w2 = W2 + (size_t)L * DIM_H2 * DIM_H;
  unsigned* o1 = W1p + (size_t)L * W1P_SZ;
  unsigned* o2 = W2p + (size_t)L * W2P_SZ;
  for (int i = blockIdx.x * 256 + threadIdx.x; i < W1P_SZ; i += gridDim.x * 256) {
    int n = i / 36, kp = i - n * 36;
    o1[i] = (kp < 32) ? pack2bf(w1[(size_t)(2 * kp) * DIM_H2 + n],
                                w1[(size_t)(2 * kp + 1) * DIM_H2 + n]) : 0u;
  }
  for (int i = blockIdx.x * 256 + threadIdx.x; i < W2P_SZ; i += gridDim.x * 256) {
    int n = i / 68, kp = i - n * 68;
    o2[i] = (kp < 64) ? pack2bf(w2[(size_t)(2 * kp) * DIM_H + n],
                                w2[(size_t)(2 * kp + 1) * DIM_H + n]) : 0u;
  }
}

// ---------------- encoder: hBf = bf16(x @ enc_W + enc_b) ----------------

__global__ __launch_bounds__(256, 3) void k_encoder(const float* __restrict__ x,
                                                    const float* __restrict__ W,
                                                    const float* __restrict__ bias,
                                                    unsigned short* __restrict__ hBf) {
  __shared__ float sx[32][DIM_IN];           // 16KB
  __shared__ float sW[DIM_IN * DIM_H];       // 32KB
  int t = threadIdx.x;
  int node0 = blockIdx.x * 32;
  for (int i = t; i < DIM_IN * DIM_H; i += 256) sW[i] = W[i];
  for (int i = t; i < 32 * DIM_IN; i += 256) {
    int r = i >> 7, c = i & 127;
    sx[r][c] = x[(size_t)(node0 + r) * DIM_IN + c];
  }
  __syncthreads();
  int w = t >> 6, lane = t & 63;
  float acc[8];
#pragma unroll
  for (int j = 0; j < 8; j++) acc[j] = 0.f;
  for (int k0 = 0; k0 < DIM_IN; k0 += 4) {
    float w0 = sW[(k0 + 0) * DIM_H + lane];
    float w1 = sW[(k0 + 1) * DIM_H + lane];
    float w2 = sW[(k0 + 2) * DIM_H + lane];
    float w3 = sW[(k0 + 3) * DIM_H + lane];
#pragma unroll
    for (int j = 0; j < 8; j++) {
      float4 a = *(const float4*)&sx[w * 8 + j][k0];
      acc[j] += a.x * w0 + a.y * w1 + a.z * w2 + a.w * w3;
    }
  }
  float bv = bias[lane];
#pragma unroll
  for (int j = 0; j < 8; j++) {
    int v = node0 + w * 8 + j;
    hBf[(size_t)v * DIM_H + lane] = (unsigned short)bf16rne(acc[j] + bv);
  }
}

// ---------------- edge aggregation + MsgNorm (bf16 gather, bf16 out) --------
// wave per node, lane = channel; per-channel softmax lane-local.
// Output bf16 = exactly the rounding k_mlp applied at X-pack anyway.

__global__ __launch_bounds__(256) void k_edge(const unsigned short* __restrict__ xin,
                                              const int* __restrict__ ssrc,
                                              const int* __restrict__ offs,
                                              const float* __restrict__ t_arr,
                                              const float* __restrict__ sc_arr, int layer,
                                              unsigned short* __restrict__ hmid) {
  int v = blockIdx.x * 4 + (threadIdx.x >> 6);
  int lane = threadIdx.x & 63;
  float tval = t_arr[layer];
  float sc = sc_arr[layer];
  int beg = offs[v], end = offs[v + 1];
  float xv = bfu(xin[(size_t)v * DIM_H + lane]);
  float D0 = 0.f, S0 = 0.f, D1 = 0.f, S1 = 0.f;
  float D2 = 0.f, S2 = 0.f, D3 = 0.f, S3 = 0.f;
  int e = beg;
  for (; e + 3 < end; e += 4) {
    int s0 = ssrc[e], s1 = ssrc[e + 1], s2 = ssrc[e + 2], s3 = ssrc[e + 3];
    float x0 = bfu(xin[(size_t)s0 * DIM_H + lane]);
    float x1 = bfu(xin[(size_t)s1 * DIM_H + lane]);
    float x2 = bfu(xin[(size_t)s2 * DIM_H + lane]);
    float x3 = bfu(xin[(size_t)s3 * DIM_H + lane]);
    float m0 = fmaxf(x0, 0.f) + 1e-7f;
    float m1 = fmaxf(x1, 0.f) + 1e-7f;
    float m2 = fmaxf(x2, 0.f) + 1e-7f;
    float m3 = fmaxf(x3, 0.f) + 1e-7f;
    float e0 = __expf(tval * m0);
    float e1 = __expf(tval * m1);
    float e2 = __expf(tval * m2);
    float e3 = __expf(tval * m3);
    D0 += e0; S0 += m0 * e0;
    D1 += e1; S1 += m1 * e1;
    D2 += e2; S2 += m2 * e2;
    D3 += e3; S3 += m3 * e3;
  }
  for (; e < end; ++e) {
    int s0 = ssrc[e];
    float x0 = bfu(xin[(size_t)s0 * DIM_H + lane]);
    float m0 = fmaxf(x0, 0.f) + 1e-7f;
    float e0 = __expf(tval * m0);
    D0 += e0; S0 += m0 * e0;
  }
  float D = (D0 + D1) + (D2 + D3);
  float S = (S0 + S1) + (S2 + S3);
  float agg = (end > beg) ? (S / D) : 0.f;
  float na = wsum(agg * agg);
  float nx = wsum(xv * xv);
  float msg = agg / fmaxf(sqrtf(na), 1e-12f);
  hmid[(size_t)v * DIM_H + lane] = (unsigned short)bf16rne(xv + sc * msg * sqrtf(nx));
}

// ---------------- GENConv MLP via MFMA + fused next pre-norm ----------------
// Same verified MFMA layouts as R10 (passed, absmax 0.0046). Differences:
// weights arrive PRE-PACKED (uint4 copies, no pack VALU, half the bytes),
// X arrives bf16 (raw uint copies), U stored via direct ushort stores (no
// pack shuffles). 5 barrier phases; single W2 restage.

__global__ __launch_bounds__(256, 2) void k_mlp(const unsigned short* __restrict__ xin,
                                                const float* __restrict__ hres,
                                                float* __restrict__ hout,
                                                unsigned short* __restrict__ rnext,
                                                const unsigned* __restrict__ W1p,
                                                const float* __restrict__ b1,
                                                const float* __restrict__ g1,
                                                const float* __restrict__ bb1,
                                                const unsigned* __restrict__ W2p,
                                                const float* __restrict__ b2,
                                                const float* __restrict__ gn,
                                                const float* __restrict__ bn, int residual) {
  __shared__ __attribute__((aligned(16))) unsigned sWb[W1P_SZ];          // 18.4KB: W1 s36, then W2 s68
  __shared__ __attribute__((aligned(16))) unsigned sxp[32 * 36];         // 4.6KB:  X packed [row][kp<32] s36
  __shared__ __attribute__((aligned(16))) float sf[32 * 132];            // 16.9KB: C1 [row][c<128] s132; then C2 s68
  __shared__ __attribute__((aligned(16))) unsigned short subu[32 * 136]; // 8.7KB:  U bf16 [row][c<128] s136
  int t = threadIdx.x;
  int node0 = blockIdx.x * 32;
  int w = t >> 6, lane = t & 63;
  int fr = lane & 15, fq = lane >> 4;

  // phase 1: stage W1 (uint4 copies) + X (raw uint copies of bf16 pairs)
  {
    const uint4* w1v = (const uint4*)W1p;  // 1152 uint4
    for (int i = t; i < W1P_SZ / 4; i += 256) *(uint4*)&sWb[i * 4] = w1v[i];
    const unsigned* mc32 = (const unsigned*)xin;
    for (int i = t; i < 1024; i += 256)
      sxp[(i >> 5) * 36 + (i & 31)] = mc32[(size_t)node0 * 32 + i];
  }
  __syncthreads();

  // phase 2: GEMM1 — wave w owns n-tiles {2w, 2w+1}, m-tiles {0,1}
  {
    f32x4 acc00 = {0.f, 0.f, 0.f, 0.f}, acc01 = acc00, acc10 = acc00, acc11 = acc00;
#pragma unroll
    for (int s = 0; s < 2; s++) {
      int kp0 = s * 16 + fq * 4;
      bf16x8 a0 = *(const bf16x8*)&sxp[(0 * 16 + fr) * 36 + kp0];
      bf16x8 a1 = *(const bf16x8*)&sxp[(1 * 16 + fr) * 36 + kp0];
      bf16x8 w0 = *(const bf16x8*)&sWb[((2 * w) * 16 + fr) * 36 + kp0];
      bf16x8 w1 = *(const bf16x8*)&sWb[((2 * w + 1) * 16 + fr) * 36 + kp0];
      acc00 = __builtin_amdgcn_mfma_f32_16x16x32_bf16(a0, w0, acc00, 0, 0, 0);
      acc01 = __builtin_amdgcn_mfma_f32_16x16x32_bf16(a0, w1, acc01, 0, 0, 0);
      acc10 = __builtin_amdgcn_mfma_f32_16x16x32_bf16(a1, w0, acc10, 0, 0, 0);
      acc11 = __builtin_amdgcn_mfma_f32_16x16x32_bf16(a1, w1, acc11, 0, 0, 0);
    }
#pragma unroll
    for (int r = 0; r < 4; r++) {
      sf[(fq * 4 + r) * 132 + (2 * w) * 16 + fr] = acc00[r];
      sf[(fq * 4 + r) * 132 + (2 * w + 1) * 16 + fr] = acc01[r];
      sf[(16 + fq * 4 + r) * 132 + (2 * w) * 16 + fr] = acc10[r];
      sf[(16 + fq * 4 + r) * 132 + (2 * w + 1) * 16 + fr] = acc11[r];
    }
  }
  __syncthreads();

  // phase 3: restage W2 (uint4 copies) + LN/relu -> U bf16 (direct stores)
  {
    const uint4* w2v = (const uint4*)W2p;  // 1088 uint4
    for (int i = t; i < W2P_SZ / 4; i += 256) *(uint4*)&sWb[i * 4] = w2v[i];
    float bias0 = b1[lane], bias1 = b1[64 + lane];
    float gg0 = g1[lane], gg1 = g1[64 + lane];
    float be0 = bb1[lane], be1 = bb1[64 + lane];
#pragma unroll
    for (int j = 0; j < 8; j++) {
      int row = w * 8 + j;
      float u0 = sf[row * 132 + lane] + bias0;
      float u1 = sf[row * 132 + 64 + lane] + bias1;
      float s = wsum(u0 + u1);
      float s2 = wsum(u0 * u0 + u1 * u1);
      float mu = s * (1.f / 128.f);
      float var = s2 * (1.f / 128.f) - mu * mu;
      float rs = rsqrtf(var + 1e-5f);
      u0 = fmaxf((u0 - mu) * rs * gg0 + be0, 0.f);
      u1 = fmaxf((u1 - mu) * rs * gg1 + be1, 0.f);
      subu[row * 136 + lane] = (unsigned short)bf16rne(u0);
      subu[row * 136 + 64 + lane] = (unsigned short)bf16rne(u1);
    }
  }
  __syncthreads();

  // phase 4: GEMM2 — wave w: m-tile w>>1, n-tiles {2*(w&1), 2*(w&1)+1}
  {
    int mt = w >> 1, nt0 = (w & 1) * 2;
    f32x4 acc0 = {0.f, 0.f, 0.f, 0.f}, acc1 = acc0;
#pragma unroll
    for (int s = 0; s < 4; s++) {
      int kp0 = s * 16 + fq * 4;
      bf16x8 a = *(const bf16x8*)&subu[(mt * 16 + fr) * 136 + 2 * kp0];
      bf16x8 w0 = *(const bf16x8*)&sWb[(nt0 * 16 + fr) * 68 + kp0];
      bf16x8 w1 = *(const bf16x8*)&sWb[((nt0 + 1) * 16 + fr) * 68 + kp0];
      acc0 = __builtin_amdgcn_mfma_f32_16x16x32_bf16(a, w0, acc0, 0, 0, 0);
      acc1 = __builtin_amdgcn_mfma_f32_16x16x32_bf16(a, w1, acc1, 0, 0, 0);
    }
#pragma unroll
    for (int r = 0; r < 4; r++) {
      sf[(mt * 16 + fq * 4 + r) * 68 + nt0 * 16 + fr] = acc0[r];
      sf[(mt * 16 + fq * 4 + r) * 68 + (nt0 + 1) * 16 + fr] = acc1[r];
    }
  }
  __syncthreads();

  // phase 5: epilogue — +b2 (+res) -> hout f32; prenorm -> rnext bf16
  {
    float b2v = b2[lane], gv = gn[lane], bv = bn[lane];
#pragma unroll
    for (int j = 0; j < 8; j++) {
      int row = w * 8 + j;
      int v = node0 + row;
      float o = sf[row * 68 + lane] + b2v;
      if (residual) o += hres[(size_t)v * DIM_H + lane];
      hout[(size_t)v * DIM_H + lane] = o;
      float s = wsum(o);
      float s2 = wsum(o * o);
      float mu = s * (1.f / 64.f);
      float var = s2 * (1.f / 64.f) - mu * mu;
      float rs = rsqrtf(var + 1e-5f);
      float r = fmaxf((o - mu) * rs * gv + bv, 0.f);
      rnext[(size_t)v * DIM_H + lane] = (unsigned short)bf16rne(r);
    }
  }
}

// ---------------- final: out = rB @ lin_W + lin_b (rB pre-normed, bf16) ------

__global__ void k_final(const unsigned short* __restrict__ rB, const float* __restrict__ W,
                        const float* __restrict__ bias, float* __restrict__ out) {
  __shared__ float sW[DIM_H * DIM_OUT];  // 28KB
  __shared__ float sx[8][DIM_H];         // 2KB
  int t = threadIdx.x;
  int node0 = blockIdx.x * 8;
  for (int i = t; i < DIM_H * DIM_OUT; i += 256) sW[i] = W[i];
  for (int i = t; i < 8 * DIM_H; i += 256) sx[i >> 6][i & 63] = bfu(rB[(size_t)node0 * DIM_H + i]);
  __syncthreads();
  int c = t & 127, g = t >> 7;
  int cc = (c < DIM_OUT) ? c : 0;  // keep inactive lanes in-bounds
  int r0 = g * 4;
  float a0 = 0.f, a1 = 0.f, a2 = 0.f, a3 = 0.f;
  for (int k = 0; k < DIM_H; ++k) {
    float wv = sW[k * DIM_OUT + cc];
    a0 += wv * sx[r0 + 0][k];
    a1 += wv * sx[r0 + 1][k];
    a2 += wv * sx[r0 + 2][k];
    a3 += wv * sx[r0 + 3][k];
  }
  if (c < DIM_OUT) {
    float bv = bias[c];
    out[(size_t)(node0 + r0 + 0) * DIM_OUT + c] = a0 + bv;
    out[(size_t)(node0 + r0 + 1) * DIM_OUT + c] = a1 + bv;
    out[(size_t)(node0 + r0 + 2) * DIM_OUT + c] = a2 + bv;
    out[(size_t)(node0 + r0 + 3) * DIM_OUT + c] = a3 + bv;
  }
}

// ---------------- launch ----------------

extern "C" void kernel_launch(void* const* d_in, const int* in_sizes, int n_in,
                              void* d_out, int out_size, void* d_ws, size_t ws_size,
                              hipStream_t stream) {
  const float* x = (const float*)d_in[0];
  const int* ei = (const int*)d_in[1];
  const float* encW = (const float*)d_in[2];
  const float* encb = (const float*)d_in[3];
  const float* t_arr = (const float*)d_in[4];
  const float* sc_arr = (const float*)d_in[5];
  const float* W1 = (const float*)d_in[6];
  const float* b1 = (const float*)d_in[7];
  const float* g1 = (const float*)d_in[8];
  const float* bb1 = (const float*)d_in[9];
  const float* W2 = (const float*)d_in[10];
  const float* b2 = (const float*)d_in[11];
  const float* ng = (const float*)d_in[12];
  const float* nbias = (const float*)d_in[13];
  const float* linW = (const float*)d_in[14];
  const float* linb = (const float*)d_in[15];

  float* hA = (float*)d_ws;                                             // N*64 f32 h-state
  unsigned short* mCbf = (unsigned short*)(hA + (size_t)N_NODES * DIM_H);  // N*64 bf16 edge-out
  unsigned short* rBf = mCbf + (size_t)N_NODES * DIM_H;                 // N*64 bf16
  unsigned short* hBf = rBf + (size_t)N_NODES * DIM_H;                  // N*64 bf16
  int* ssrc = (int*)(hBf + (size_t)N_NODES * DIM_H);                    // E
  int* offs = ssrc + N_EDGES;                                           // N+1
  int* cursor = offs + (N_NODES + 1);                                   // N
  int* counts = cursor + N_NODES;                                       // N
  int* bsums = counts + N_NODES;                                        // <=512
  unsigned* W1p = (unsigned*)(((uintptr_t)(bsums + 512) + 15) & ~(uintptr_t)15);  // 7*4608
  unsigned* W2p = W1p + (size_t)N_LAYERS * W1P_SZ;                      // 7*4352

  const int* srcI = ei;
  const int* dstI = ei + N_EDGES;

  const int nbScan = (N_NODES + 255) / 256;  // 391
  const int nbEdge = (N_EDGES + 255) / 256;  // 4688

  // CSR build (dst-sorted src list) + weight pre-pack
  k_zero_i<<<nbScan, 256, 0, stream>>>(counts, N_NODES);
  k_hist<<<nbEdge, 256, 0, stream>>>(dstI, counts);
  k_prepack<<<dim3(3, N_LAYERS), 256, 0, stream>>>(W1, W2, W1p, W2p);
  k_scan1<<<nbScan, 256, 0, stream>>>(counts, bsums);
  k_scan2<<<1, 512, 0, stream>>>(bsums, nbScan);
  k_scan3<<<nbScan, 256, 0, stream>>>(counts, bsums, offs);
  k_copy_i<<<nbScan, 256, 0, stream>>>(offs, cursor, N_NODES);
  k_scatter<<<8 * nbEdge, 256, 0, stream>>>(srcI, dstI, cursor, ssrc);

  // encoder -> hBf (bf16)
  k_encoder<<<N_NODES / 32, 256, 0, stream>>>(x, encW, encb, hBf);

  // layers 0..6: gather(bf16) -> mCbf(bf16) -> MFMA MLP -> hA(f32) + rBf(bf16)
  for (int i = 0; i < N_LAYERS; i++) {
    int nx = (i + 1 < N_LAYERS) ? (i + 1) : 0;
    const unsigned short* gin = (i == 0) ? hBf : rBf;
    k_edge<<<N_NODES / 4, 256, 0, stream>>>(gin, ssrc, offs, t_arr, sc_arr, i, mCbf);
    k_mlp<<<N_NODES / 32, 256, 0, stream>>>(
        mCbf, hA, hA, rBf, W1p + (size_t)i * W1P_SZ, b1 + i * DIM_H2, g1 + i * DIM_H2,
        bb1 + i * DIM_H2, W2p + (size_t)i * W2P_SZ, b2 + i * DIM_H,
        ng + nx * DIM_H, nbias + nx * DIM_H, (i > 0) ? 1 : 0);
  }

  // final: rBf = bf16(relu(LN(h, nrm_0))); pure GEMM
  k_final<<<N_NODES / 8, 256, 0, stream>>>(rBf, linW, linb, (float*)d_out);
}

// Round 12
// 954.658 us; speedup vs baseline: 1.7881x; 1.1548x over previous
//
#include <hip/hip_runtime.h>

#define N_NODES 100000
#define N_EDGES 1200000
#define DIM_IN 128
#define DIM_H 64
#define DIM_H2 128
#define DIM_OUT 112
#define N_LAYERS 7

// pre-packed weight sizes (uints), padded strides baked in
#define W1P_SZ 4608  // 128 n * 36 kp-stride (kp<32 valid)
#define W2P_SZ 4352  // 64 n * 68 kp-stride (kp<64 valid)
#define WEP_SZ 4352  // encoder: 64 n * 68 kp-stride (kp<64 valid)

typedef __attribute__((ext_vector_type(8))) short bf16x8;
typedef __attribute__((ext_vector_type(4))) float f32x4;

__device__ __forceinline__ float wsum(float v) {
#pragma unroll
  for (int m = 1; m < 64; m <<= 1) v += __shfl_xor(v, m, 64);
  return v;
}

// bf16 pack/unpack: bf16->f32 is just <<16 (bit ops, no cvt instruction)
__device__ __forceinline__ unsigned bf16rne(float f) {
  unsigned u = __float_as_uint(f);
  return (u + 0x7fffu + ((u >> 16) & 1u)) >> 16;
}
__device__ __forceinline__ unsigned pack2bf(float lo, float hi) {
  return bf16rne(lo) | (bf16rne(hi) << 16);
}
__device__ __forceinline__ float bflo(unsigned p) { return __uint_as_float(p << 16); }
__device__ __forceinline__ float bfhi(unsigned p) { return __uint_as_float(p & 0xffff0000u); }
__device__ __forceinline__ float bfu(unsigned short u) {
  return __uint_as_float(((unsigned)u) << 16);
}

// ---------------- preprocessing: CSR build (dst-sorted) ----------------

__global__ void k_zero_i(int* __restrict__ p, int n) {
  int i = blockIdx.x * 256 + threadIdx.x;
  if (i < n) p[i] = 0;
}

__global__ void k_hist(const int* __restrict__ dst, int* __restrict__ counts) {
  int e = blockIdx.x * 256 + threadIdx.x;
  if (e < N_EDGES) atomicAdd(&counts[dst[e]], 1);
}

__global__ void k_scan1(const int* __restrict__ counts, int* __restrict__ bsums) {
  __shared__ int sd[256];
  int t = threadIdx.x;
  int i = blockIdx.x * 256 + t;
  sd[t] = (i < N_NODES) ? counts[i] : 0;
  __syncthreads();
  for (int s = 128; s > 0; s >>= 1) {
    if (t < s) sd[t] += sd[t + s];
    __syncthreads();
  }
  if (t == 0) bsums[blockIdx.x] = sd[0];
}

__global__ void k_scan2(int* __restrict__ bsums, int nb) {
  __shared__ int sd[512];
  int t = threadIdx.x;
  int v = (t < nb) ? bsums[t] : 0;
  sd[t] = v;
  __syncthreads();
  for (int o = 1; o < 512; o <<= 1) {
    int add = (t >= o) ? sd[t - o] : 0;
    __syncthreads();
    sd[t] += add;
    __syncthreads();
  }
  if (t < nb) bsums[t] = sd[t] - v;  // exclusive
}

__global__ void k_scan3(const int* __restrict__ counts, const int* __restrict__ bsums,
                        int* __restrict__ offs) {
  __shared__ int sd[256];
  int t = threadIdx.x;
  int i = blockIdx.x * 256 + t;
  int v = (i < N_NODES) ? counts[i] : 0;
  sd[t] = v;
  __syncthreads();
  for (int o = 1; o < 256; o <<= 1) {
    int add = (t >= o) ? sd[t - o] : 0;
    __syncthreads();
    sd[t] += add;
    __syncthreads();
  }
  int excl = sd[t] - v + bsums[blockIdx.x];
  if (i < N_NODES) offs[i] = excl;
  if (i == N_NODES - 1) offs[N_NODES] = excl + v;  // = E
}

__global__ void k_copy_i(const int* __restrict__ a, int* __restrict__ b, int n) {
  int i = blockIdx.x * 256 + threadIdx.x;
  if (i < n) b[i] = a[i];
}

// XCD-partitioned scatter (R11-proven): block b handles dst in [(b&7)*12500,+12500)
__global__ void k_scatter(const int* __restrict__ src, const int* __restrict__ dst,
                          int* __restrict__ cursor, int* __restrict__ ssrc) {
  int part = blockIdx.x & 7;
  int e = (blockIdx.x >> 3) * 256 + threadIdx.x;
  if (e < N_EDGES) {
    int d = dst[e];
    if ((unsigned)(d - part * (N_NODES / 8)) < (unsigned)(N_NODES / 8)) {
      int p = atomicAdd(&cursor[d], 1);
      ssrc[p] = src[e];
    }
  }
}

// ---------------- weight pre-pack (once per launch) ----------------
// W1p[L][n*36+kp] = pack2bf(W1[L][2kp][n], W1[L][2kp+1][n]); W2p same s68.
__global__ void k_prepack(const float* __restrict__ W1, const float* __restrict__ W2,
                          unsigned* __restrict__ W1p, unsigned* __restrict__ W2p) {
  int L = blockIdx.y;
  const float* w1 = W1 + (size_t)L * DIM_H * DIM_H2;
  const float* w2 = W2 + (size_t)L * DIM_H2 * DIM_H;
  unsigned* o1 = W1p + (size_t)L * W1P_SZ;
  unsigned* o2 = W2p + (size_t)L * W2P_SZ;
  for (int i = blockIdx.x * 256 + threadIdx.x; i < W1P_SZ; i += gridDim.x * 256) {
    int n = i / 36, kp = i - n * 36;
    o1[i] = (kp < 32) ? pack2bf(w1[(size_t)(2 * kp) * DIM_H2 + n],
                                w1[(size_t)(2 * kp + 1) * DIM_H2 + n]) : 0u;
  }
  for (int i = blockIdx.x * 256 + threadIdx.x; i < W2P_SZ; i += gridDim.x * 256) {
    int n = i / 68, kp = i - n * 68;
    o2[i] = (kp < 64) ? pack2bf(w2[(size_t)(2 * kp) * DIM_H + n],
                                w2[(size_t)(2 * kp + 1) * DIM_H + n]) : 0u;
  }
}

// encoder weights: encW [128][64] -> Wp [n<64][kp<64] stride 68 (W2 format)
__global__ void k_prepack_enc(const float* __restrict__ W, unsigned* __restrict__ Wp) {
  for (int i = blockIdx.x * 256 + threadIdx.x; i < WEP_SZ; i += gridDim.x * 256) {
    int n = i / 68, kp = i - n * 68;
    Wp[i] = (kp < 64) ? pack2bf(W[(size_t)(2 * kp) * DIM_H + n],
                                W[(size_t)(2 * kp + 1) * DIM_H + n]) : 0u;
  }
}

// ---------------- encoder via MFMA: hBf = bf16(x @ enc_W + enc_b) ----------
// K=128 (4 k-steps), N=64 (4 n-tiles, wave w owns n-tile w), M=32 (2 m-tiles).
// R10-verified fragment recipe; D written straight to global as ushort.

__global__ __launch_bounds__(256, 2) void k_encoder(const float* __restrict__ x,
                                                    const unsigned* __restrict__ Wp,
                                                    const float* __restrict__ bias,
                                                    unsigned short* __restrict__ hBf) {
  __shared__ __attribute__((aligned(16))) unsigned sW[WEP_SZ];    // 17.4KB [n<64][kp<64] s68
  __shared__ __attribute__((aligned(16))) unsigned sxp[32 * 68];  // 8.7KB [row][kp<64] s68
  int t = threadIdx.x;
  int node0 = blockIdx.x * 32;
  int w = t >> 6, lane = t & 63;
  int fr = lane & 15, fq = lane >> 4;
  const uint4* wv4 = (const uint4*)Wp;
  for (int i = t; i < WEP_SZ / 4; i += 256) *(uint4*)&sW[i * 4] = wv4[i];
  for (int i = t; i < 2048; i += 256) {  // 32 rows x 64 kp
    int row = i >> 6, kp = i & 63;
    float2 xv = *(const float2*)&x[(size_t)(node0 + row) * DIM_IN + 2 * kp];
    sxp[row * 68 + kp] = pack2bf(xv.x, xv.y);
  }
  __syncthreads();
  f32x4 acc0 = {0.f, 0.f, 0.f, 0.f}, acc1 = acc0;
#pragma unroll
  for (int s = 0; s < 4; s++) {
    int kp0 = s * 16 + fq * 4;
    bf16x8 a0 = *(const bf16x8*)&sxp[fr * 68 + kp0];
    bf16x8 a1 = *(const bf16x8*)&sxp[(16 + fr) * 68 + kp0];
    bf16x8 wf = *(const bf16x8*)&sW[(w * 16 + fr) * 68 + kp0];
    acc0 = __builtin_amdgcn_mfma_f32_16x16x32_bf16(a0, wf, acc0, 0, 0, 0);
    acc1 = __builtin_amdgcn_mfma_f32_16x16x32_bf16(a1, wf, acc1, 0, 0, 0);
  }
  float bv = bias[w * 16 + fr];
#pragma unroll
  for (int r = 0; r < 4; r++) {
    hBf[(size_t)(node0 + fq * 4 + r) * DIM_H + w * 16 + fr] =
        (unsigned short)bf16rne(acc0[r] + bv);
    hBf[(size_t)(node0 + 16 + fq * 4 + r) * DIM_H + w * 16 + fr] =
        (unsigned short)bf16rne(acc1[r] + bv);
  }
}

// ---------------- edge aggregation + MsgNorm (paired-channel, 2 nodes/wave) --
// Lane handles channels {2cl, 2cl+1} of node v; half-wave (32 lanes) per node.
// One uint load + 1 unpack serves 2 channels -> ~half the VALU/edge of R11.
// MsgNorm reductions are 5-step shuffles confined to each 32-lane half.
// uint[v*32+cl] layout is byte-identical to ushort[v*64+c] used downstream.

__global__ __launch_bounds__(256) void k_edge(const unsigned* __restrict__ xin32,
                                              const int* __restrict__ ssrc,
                                              const int* __restrict__ offs,
                                              const float* __restrict__ t_arr,
                                              const float* __restrict__ sc_arr, int layer,
                                              unsigned* __restrict__ hmid32) {
  int t = threadIdx.x;
  int wave = t >> 6, lane = t & 63;
  int half = lane >> 5, cl = lane & 31;
  int v = blockIdx.x * 8 + wave * 2 + half;
  float tval = t_arr[layer];
  float sc = sc_arr[layer];
  int beg = offs[v], end = offs[v + 1];
  unsigned xp = xin32[(size_t)v * 32 + cl];
  float xv0 = bflo(xp), xv1 = bfhi(xp);
  float D0 = 0.f, S0 = 0.f, D1 = 0.f, S1 = 0.f;
  float D2 = 0.f, S2 = 0.f, D3 = 0.f, S3 = 0.f;
  int e = beg;
  for (; e + 1 < end; e += 2) {
    int s0 = ssrc[e], s1 = ssrc[e + 1];
    unsigned u0 = xin32[(size_t)s0 * 32 + cl];
    unsigned u1 = xin32[(size_t)s1 * 32 + cl];
    float a0 = fmaxf(bflo(u0), 0.f) + 1e-7f;
    float a1 = fmaxf(bfhi(u0), 0.f) + 1e-7f;
    float b0 = fmaxf(bflo(u1), 0.f) + 1e-7f;
    float b1 = fmaxf(bfhi(u1), 0.f) + 1e-7f;
    float ea0 = __expf(tval * a0);
    float ea1 = __expf(tval * a1);
    float eb0 = __expf(tval * b0);
    float eb1 = __expf(tval * b1);
    D0 += ea0; S0 += a0 * ea0;
    D1 += ea1; S1 += a1 * ea1;
    D2 += eb0; S2 += b0 * eb0;
    D3 += eb1; S3 += b1 * eb1;
  }
  if (e < end) {
    int s0 = ssrc[e];
    unsigned u0 = xin32[(size_t)s0 * 32 + cl];
    float a0 = fmaxf(bflo(u0), 0.f) + 1e-7f;
    float a1 = fmaxf(bfhi(u0), 0.f) + 1e-7f;
    float ea0 = __expf(tval * a0);
    float ea1 = __expf(tval * a1);
    D0 += ea0; S0 += a0 * ea0;
    D1 += ea1; S1 += a1 * ea1;
  }
  float Da = D0 + D2, Sa = S0 + S2;  // channel 2cl
  float Db = D1 + D3, Sb = S1 + S3;  // channel 2cl+1
  int has = (end > beg);
  float agg0 = has ? (Sa / Da) : 0.f;
  float agg1 = has ? (Sb / Db) : 0.f;
  float na = agg0 * agg0 + agg1 * agg1;
  float nx = xv0 * xv0 + xv1 * xv1;
#pragma unroll
  for (int m = 1; m < 32; m <<= 1) {
    na += __shfl_xor(na, m, 64);
    nx += __shfl_xor(nx, m, 64);
  }
  float inv = sc * sqrtf(nx) / fmaxf(sqrtf(na), 1e-12f);
  float r0 = xv0 + inv * agg0;
  float r1 = xv1 + inv * agg1;
  hmid32[(size_t)v * 32 + cl] = pack2bf(r0, r1);
}

// ---------------- GENConv MLP via MFMA + fused next pre-norm ----------------
// R11-proven kernel, unchanged (passed, absmax 0.0042, ~45us, no spill).

__global__ __launch_bounds__(256, 2) void k_mlp(const unsigned short* __restrict__ xin,
                                                const float* __restrict__ hres,
                                                float* __restrict__ hout,
                                                unsigned short* __restrict__ rnext,
                                                const unsigned* __restrict__ W1p,
                                                const float* __restrict__ b1,
                                                const float* __restrict__ g1,
                                                const float* __restrict__ bb1,
                                                const unsigned* __restrict__ W2p,
                                                const float* __restrict__ b2,
                                                const float* __restrict__ gn,
                                                const float* __restrict__ bn, int residual) {
  __shared__ __attribute__((aligned(16))) unsigned sWb[W1P_SZ];          // 18.4KB
  __shared__ __attribute__((aligned(16))) unsigned sxp[32 * 36];         // 4.6KB
  __shared__ __attribute__((aligned(16))) float sf[32 * 132];            // 16.9KB
  __shared__ __attribute__((aligned(16))) unsigned short subu[32 * 136]; // 8.7KB
  int t = threadIdx.x;
  int node0 = blockIdx.x * 32;
  int w = t >> 6, lane = t & 63;
  int fr = lane & 15, fq = lane >> 4;

  // phase 1: stage W1 (uint4 copies) + X (raw uint copies of bf16 pairs)
  {
    const uint4* w1v = (const uint4*)W1p;
    for (int i = t; i < W1P_SZ / 4; i += 256) *(uint4*)&sWb[i * 4] = w1v[i];
    const unsigned* mc32 = (const unsigned*)xin;
    for (int i = t; i < 1024; i += 256)
      sxp[(i >> 5) * 36 + (i & 31)] = mc32[(size_t)node0 * 32 + i];
  }
  __syncthreads();

  // phase 2: GEMM1 — wave w owns n-tiles {2w, 2w+1}, m-tiles {0,1}
  {
    f32x4 acc00 = {0.f, 0.f, 0.f, 0.f}, acc01 = acc00, acc10 = acc00, acc11 = acc00;
#pragma unroll
    for (int s = 0; s < 2; s++) {
      int kp0 = s * 16 + fq * 4;
      bf16x8 a0 = *(const bf16x8*)&sxp[(0 * 16 + fr) * 36 + kp0];
      bf16x8 a1 = *(const bf16x8*)&sxp[(1 * 16 + fr) * 36 + kp0];
      bf16x8 w0 = *(const bf16x8*)&sWb[((2 * w) * 16 + fr) * 36 + kp0];
      bf16x8 w1 = *(const bf16x8*)&sWb[((2 * w + 1) * 16 + fr) * 36 + kp0];
      acc00 = __builtin_amdgcn_mfma_f32_16x16x32_bf16(a0, w0, acc00, 0, 0, 0);
      acc01 = __builtin_amdgcn_mfma_f32_16x16x32_bf16(a0, w1, acc01, 0, 0, 0);
      acc10 = __builtin_amdgcn_mfma_f32_16x16x32_bf16(a1, w0, acc10, 0, 0, 0);
      acc11 = __builtin_amdgcn_mfma_f32_16x16x32_bf16(a1, w1, acc11, 0, 0, 0);
    }
#pragma unroll
    for (int r = 0; r < 4; r++) {
      sf[(fq * 4 + r) * 132 + (2 * w) * 16 + fr] = acc00[r];
      sf[(fq * 4 + r) * 132 + (2 * w + 1) * 16 + fr] = acc01[r];
      sf[(16 + fq * 4 + r) * 132 + (2 * w) * 16 + fr] = acc10[r];
      sf[(16 + fq * 4 + r) * 132 + (2 * w + 1) * 16 + fr] = acc11[r];
    }
  }
  __syncthreads();

  // phase 3: restage W2 (uint4 copies) + LN/relu -> U bf16 (direct stores)
  {
    const uint4* w2v = (const uint4*)W2p;
    for (int i = t; i < W2P_SZ / 4; i += 256) *(uint4*)&sWb[i * 4] = w2v[i];
    float bias0 = b1[lane], bias1 = b1[64 + lane];
    float gg0 = g1[lane], gg1 = g1[64 + lane];
    float be0 = bb1[lane], be1 = bb1[64 + lane];
#pragma unroll
    for (int j = 0; j < 8; j++) {
      int row = w * 8 + j;
      float u0 = sf[row * 132 + lane] + bias0;
      float u1 = sf[row * 132 + 64 + lane] + bias1;
      float s = wsum(u0 + u1);
      float s2 = wsum(u0 * u0 + u1 * u1);
      float mu = s * (1.f / 128.f);
      float var = s2 * (1.f / 128.f) - mu * mu;
      float rs = rsqrtf(var + 1e-5f);
      u0 = fmaxf((u0 - mu) * rs * gg0 + be0, 0.f);
      u1 = fmaxf((u1 - mu) * rs * gg1 + be1, 0.f);
      subu[row * 136 + lane] = (unsigned short)bf16rne(u0);
      subu[row * 136 + 64 + lane] = (unsigned short)bf16rne(u1);
    }
  }
  __syncthreads();

  // phase 4: GEMM2 — wave w: m-tile w>>1, n-tiles {2*(w&1), 2*(w&1)+1}
  {
    int mt = w >> 1, nt0 = (w & 1) * 2;
    f32x4 acc0 = {0.f, 0.f, 0.f, 0.f}, acc1 = acc0;
#pragma unroll
    for (int s = 0; s < 4; s++) {
      int kp0 = s * 16 + fq * 4;
      bf16x8 a = *(const bf16x8*)&subu[(mt * 16 + fr) * 136 + 2 * kp0];
      bf16x8 w0 = *(const bf16x8*)&sWb[(nt0 * 16 + fr) * 68 + kp0];
      bf16x8 w1 = *(const bf16x8*)&sWb[((nt0 + 1) * 16 + fr) * 68 + kp0];
      acc0 = __builtin_amdgcn_mfma_f32_16x16x32_bf16(a, w0, acc0, 0, 0, 0);
      acc1 = __builtin_amdgcn_mfma_f32_16x16x32_bf16(a, w1, acc1, 0, 0, 0);
    }
#pragma unroll
    for (int r = 0; r < 4; r++) {
      sf[(mt * 16 + fq * 4 + r) * 68 + nt0 * 16 + fr] = acc0[r];
      sf[(mt * 16 + fq * 4 + r) * 68 + (nt0 + 1) * 16 + fr] = acc1[r];
    }
  }
  __syncthreads();

  // phase 5: epilogue — +b2 (+res) -> hout f32; prenorm -> rnext bf16
  {
    float b2v = b2[lane], gv = gn[lane], bv = bn[lane];
#pragma unroll
    for (int j = 0; j < 8; j++) {
      int row = w * 8 + j;
      int v = node0 + row;
      float o = sf[row * 68 + lane] + b2v;
      if (residual) o += hres[(size_t)v * DIM_H + lane];
      hout[(size_t)v * DIM_H + lane] = o;
      float s = wsum(o);
      float s2 = wsum(o * o);
      float mu = s * (1.f / 64.f);
      float var = s2 * (1.f / 64.f) - mu * mu;
      float rs = rsqrtf(var + 1e-5f);
      float r = fmaxf((o - mu) * rs * gv + bv, 0.f);
      rnext[(size_t)v * DIM_H + lane] = (unsigned short)bf16rne(r);
    }
  }
}

// ---------------- final: out = rB @ lin_W + lin_b (rB pre-normed, bf16) ------

__global__ void k_final(const unsigned short* __restrict__ rB, const float* __restrict__ W,
                        const float* __restrict__ bias, float* __restrict__ out) {
  __shared__ float sW[DIM_H * DIM_OUT];  // 28KB
  __shared__ float sx[8][DIM_H];         // 2KB
  int t = threadIdx.x;
  int node0 = blockIdx.x * 8;
  for (int i = t; i < DIM_H * DIM_OUT; i += 256) sW[i] = W[i];
  for (int i = t; i < 8 * DIM_H; i += 256) sx[i >> 6][i & 63] = bfu(rB[(size_t)node0 * DIM_H + i]);
  __syncthreads();
  int c = t & 127, g = t >> 7;
  int cc = (c < DIM_OUT) ? c : 0;  // keep inactive lanes in-bounds
  int r0 = g * 4;
  float a0 = 0.f, a1 = 0.f, a2 = 0.f, a3 = 0.f;
  for (int k = 0; k < DIM_H; ++k) {
    float wv = sW[k * DIM_OUT + cc];
    a0 += wv * sx[r0 + 0][k];
    a1 += wv * sx[r0 + 1][k];
    a2 += wv * sx[r0 + 2][k];
    a3 += wv * sx[r0 + 3][k];
  }
  if (c < DIM_OUT) {
    float bv = bias[c];
    out[(size_t)(node0 + r0 + 0) * DIM_OUT + c] = a0 + bv;
    out[(size_t)(node0 + r0 + 1) * DIM_OUT + c] = a1 + bv;
    out[(size_t)(node0 + r0 + 2) * DIM_OUT + c] = a2 + bv;
    out[(size_t)(node0 + r0 + 3) * DIM_OUT + c] = a3 + bv;
  }
}

// ---------------- launch ----------------

extern "C" void kernel_launch(void* const* d_in, const int* in_sizes, int n_in,
                              void* d_out, int out_size, void* d_ws, size_t ws_size,
                              hipStream_t stream) {
  const float* x = (const float*)d_in[0];
  const int* ei = (const int*)d_in[1];
  const float* encW = (const float*)d_in[2];
  const float* encb = (const float*)d_in[3];
  const float* t_arr = (const float*)d_in[4];
  const float* sc_arr = (const float*)d_in[5];
  const float* W1 = (const float*)d_in[6];
  const float* b1 = (const float*)d_in[7];
  const float* g1 = (const float*)d_in[8];
  const float* bb1 = (const float*)d_in[9];
  const float* W2 = (const float*)d_in[10];
  const float* b2 = (const float*)d_in[11];
  const float* ng = (const float*)d_in[12];
  const float* nbias = (const float*)d_in[13];
  const float* linW = (const float*)d_in[14];
  const float* linb = (const float*)d_in[15];

  float* hA = (float*)d_ws;                                             // N*64 f32 h-state
  unsigned short* mCbf = (unsigned short*)(hA + (size_t)N_NODES * DIM_H);  // N*64 bf16 edge-out
  unsigned short* rBf = mCbf + (size_t)N_NODES * DIM_H;                 // N*64 bf16
  unsigned short* hBf = rBf + (size_t)N_NODES * DIM_H;                  // N*64 bf16
  int* ssrc = (int*)(hBf + (size_t)N_NODES * DIM_H);                    // E
  int* offs = ssrc + N_EDGES;                                           // N+1
  int* cursor = offs + (N_NODES + 1);                                   // N
  int* counts = cursor + N_NODES;                                       // N
  int* bsums = counts + N_NODES;                                        // <=512
  unsigned* W1p = (unsigned*)(((uintptr_t)(bsums + 512) + 15) & ~(uintptr_t)15);
  unsigned* W2p = W1p + (size_t)N_LAYERS * W1P_SZ;
  unsigned* Wep = W2p + (size_t)N_LAYERS * W2P_SZ;

  const int* srcI = ei;
  const int* dstI = ei + N_EDGES;

  const int nbScan = (N_NODES + 255) / 256;  // 391
  const int nbEdge = (N_EDGES + 255) / 256;  // 4688

  // CSR build (dst-sorted src list) + weight pre-pack
  k_zero_i<<<nbScan, 256, 0, stream>>>(counts, N_NODES);
  k_hist<<<nbEdge, 256, 0, stream>>>(dstI, counts);
  k_prepack<<<dim3(3, N_LAYERS), 256, 0, stream>>>(W1, W2, W1p, W2p);
  k_prepack_enc<<<3, 256, 0, stream>>>(encW, Wep);
  k_scan1<<<nbScan, 256, 0, stream>>>(counts, bsums);
  k_scan2<<<1, 512, 0, stream>>>(bsums, nbScan);
  k_scan3<<<nbScan, 256, 0, stream>>>(counts, bsums, offs);
  k_copy_i<<<nbScan, 256, 0, stream>>>(offs, cursor, N_NODES);
  k_scatter<<<8 * nbEdge, 256, 0, stream>>>(srcI, dstI, cursor, ssrc);

  // encoder (MFMA) -> hBf (bf16)
  k_encoder<<<N_NODES / 32, 256, 0, stream>>>(x, Wep, encb, hBf);

  // layers 0..6: gather(paired bf16) -> mCbf -> MFMA MLP -> hA(f32) + rBf(bf16)
  for (int i = 0; i < N_LAYERS; i++) {
    int nx = (i + 1 < N_LAYERS) ? (i + 1) : 0;
    const unsigned* gin32 = (const unsigned*)((i == 0) ? hBf : rBf);
    k_edge<<<N_NODES / 8, 256, 0, stream>>>(gin32, ssrc, offs, t_arr, sc_arr, i,
                                            (unsigned*)mCbf);
    k_mlp<<<N_NODES / 32, 256, 0, stream>>>(
        mCbf, hA, hA, rBf, W1p + (size_t)i * W1P_SZ, b1 + i * DIM_H2, g1 + i * DIM_H2,
        bb1 + i * DIM_H2, W2p + (size_t)i * W2P_SZ, b2 + i * DIM_H,
        ng + nx * DIM_H, nbias + nx * DIM_H, (i > 0) ? 1 : 0);
  }

  // final: rBf = bf16(relu(LN(h, nrm_0))); pure GEMM
  k_final<<<N_NODES / 8, 256, 0, stream>>>(rBf, linW, linb, (float*)d_out);
}

// Round 13
// 693.056 us; speedup vs baseline: 2.4630x; 1.3775x over previous
//
#include <hip/hip_runtime.h>

#define N_NODES 100000
#define N_EDGES 1200000
#define DIM_IN 128
#define DIM_H 64
#define DIM_H2 128
#define DIM_OUT 112
#define N_LAYERS 7

// pre-packed weight sizes (uints), padded strides baked in
#define W1P_SZ 4608  // 128 n * 36 kp-stride (kp<32 valid)
#define W2P_SZ 4352  // 64 n * 68 kp-stride (kp<64 valid)
#define WEP_SZ 4352  // encoder: 64 n * 68 kp-stride (kp<64 valid)
#define WFP_SZ 4032  // final: 112 n * 36 kp-stride (kp<32 valid)

typedef __attribute__((ext_vector_type(8))) short bf16x8;
typedef __attribute__((ext_vector_type(4))) float f32x4;

__device__ __forceinline__ float wsum(float v) {
#pragma unroll
  for (int m = 1; m < 64; m <<= 1) v += __shfl_xor(v, m, 64);
  return v;
}

// bf16 pack/unpack: bf16->f32 is just <<16 (bit ops, no cvt instruction)
__device__ __forceinline__ unsigned bf16rne(float f) {
  unsigned u = __float_as_uint(f);
  return (u + 0x7fffu + ((u >> 16) & 1u)) >> 16;
}
__device__ __forceinline__ unsigned pack2bf(float lo, float hi) {
  return bf16rne(lo) | (bf16rne(hi) << 16);
}
__device__ __forceinline__ float bflo(unsigned p) { return __uint_as_float(p << 16); }
__device__ __forceinline__ float bfhi(unsigned p) { return __uint_as_float(p & 0xffff0000u); }
__device__ __forceinline__ float bfu(unsigned short u) {
  return __uint_as_float(((unsigned)u) << 16);
}

// ---------------- preprocessing: CSR build (dst-sorted) ----------------

__global__ void k_zero_i(int* __restrict__ p, int n) {
  int i = blockIdx.x * 256 + threadIdx.x;
  if (i < n) p[i] = 0;
}

__global__ void k_hist(const int* __restrict__ dst, int* __restrict__ counts) {
  int e = blockIdx.x * 256 + threadIdx.x;
  if (e < N_EDGES) atomicAdd(&counts[dst[e]], 1);
}

__global__ void k_scan1(const int* __restrict__ counts, int* __restrict__ bsums) {
  __shared__ int sd[256];
  int t = threadIdx.x;
  int i = blockIdx.x * 256 + t;
  sd[t] = (i < N_NODES) ? counts[i] : 0;
  __syncthreads();
  for (int s = 128; s > 0; s >>= 1) {
    if (t < s) sd[t] += sd[t + s];
    __syncthreads();
  }
  if (t == 0) bsums[blockIdx.x] = sd[0];
}

__global__ void k_scan2(int* __restrict__ bsums, int nb) {
  __shared__ int sd[512];
  int t = threadIdx.x;
  int v = (t < nb) ? bsums[t] : 0;
  sd[t] = v;
  __syncthreads();
  for (int o = 1; o < 512; o <<= 1) {
    int add = (t >= o) ? sd[t - o] : 0;
    __syncthreads();
    sd[t] += add;
    __syncthreads();
  }
  if (t < nb) bsums[t] = sd[t] - v;  // exclusive
}

__global__ void k_scan3(const int* __restrict__ counts, const int* __restrict__ bsums,
                        int* __restrict__ offs) {
  __shared__ int sd[256];
  int t = threadIdx.x;
  int i = blockIdx.x * 256 + t;
  int v = (i < N_NODES) ? counts[i] : 0;
  sd[t] = v;
  __syncthreads();
  for (int o = 1; o < 256; o <<= 1) {
    int add = (t >= o) ? sd[t - o] : 0;
    __syncthreads();
    sd[t] += add;
    __syncthreads();
  }
  int excl = sd[t] - v + bsums[blockIdx.x];
  if (i < N_NODES) offs[i] = excl;
  if (i == N_NODES - 1) offs[N_NODES] = excl + v;  // = E
}

__global__ void k_copy_i(const int* __restrict__ a, int* __restrict__ b, int n) {
  int i = blockIdx.x * 256 + threadIdx.x;
  if (i < n) b[i] = a[i];
}

// XCD-partitioned scatter (R11-proven): block b handles dst in [(b&7)*12500,+12500)
__global__ void k_scatter(const int* __restrict__ src, const int* __restrict__ dst,
                          int* __restrict__ cursor, int* __restrict__ ssrc) {
  int part = blockIdx.x & 7;
  int e = (blockIdx.x >> 3) * 256 + threadIdx.x;
  if (e < N_EDGES) {
    int d = dst[e];
    if ((unsigned)(d - part * (N_NODES / 8)) < (unsigned)(N_NODES / 8)) {
      int p = atomicAdd(&cursor[d], 1);
      ssrc[p] = src[e];
    }
  }
}

// ---------------- weight pre-pack (once per launch) ----------------
// W1p[L][n*36+kp] = pack2bf(W1[L][2kp][n], W1[L][2kp+1][n]); W2p same s68.
__global__ void k_prepack(const float* __restrict__ W1, const float* __restrict__ W2,
                          unsigned* __restrict__ W1p, unsigned* __restrict__ W2p) {
  int L = blockIdx.y;
  const float* w1 = W1 + (size_t)L * DIM_H * DIM_H2;
  const float* w2 = W2 + (size_t)L * DIM_H2 * DIM_H;
  unsigned* o1 = W1p + (size_t)L * W1P_SZ;
  unsigned* o2 = W2p + (size_t)L * W2P_SZ;
  for (int i = blockIdx.x * 256 + threadIdx.x; i < W1P_SZ; i += gridDim.x * 256) {
    int n = i / 36, kp = i - n * 36;
    o1[i] = (kp < 32) ? pack2bf(w1[(size_t)(2 * kp) * DIM_H2 + n],
                                w1[(size_t)(2 * kp + 1) * DIM_H2 + n]) : 0u;
  }
  for (int i = blockIdx.x * 256 + threadIdx.x; i < W2P_SZ; i += gridDim.x * 256) {
    int n = i / 68, kp = i - n * 68;
    o2[i] = (kp < 64) ? pack2bf(w2[(size_t)(2 * kp) * DIM_H + n],
                                w2[(size_t)(2 * kp + 1) * DIM_H + n]) : 0u;
  }
}

// encoder weights: encW [128][64] -> Wp [n<64][kp<64] stride 68 (W2 format)
__global__ void k_prepack_enc(const float* __restrict__ W, unsigned* __restrict__ Wp) {
  for (int i = blockIdx.x * 256 + threadIdx.x; i < WEP_SZ; i += gridDim.x * 256) {
    int n = i / 68, kp = i - n * 68;
    Wp[i] = (kp < 64) ? pack2bf(W[(size_t)(2 * kp) * DIM_H + n],
                                W[(size_t)(2 * kp + 1) * DIM_H + n]) : 0u;
  }
}

// final weights: linW [64][112] -> Wp [n<112][kp<32] stride 36
__global__ void k_prepack_fin(const float* __restrict__ W, unsigned* __restrict__ Wp) {
  for (int i = blockIdx.x * 256 + threadIdx.x; i < WFP_SZ; i += gridDim.x * 256) {
    int n = i / 36, kp = i - n * 36;
    Wp[i] = (kp < 32) ? pack2bf(W[(size_t)(2 * kp) * DIM_OUT + n],
                                W[(size_t)(2 * kp + 1) * DIM_OUT + n]) : 0u;
  }
}

// ---------------- encoder via MFMA: hBf = bf16(x @ enc_W + enc_b) ----------
// R12-proven (passed). K=128, N=64, M=32; wave w owns n-tile w.

__global__ __launch_bounds__(256, 2) void k_encoder(const float* __restrict__ x,
                                                    const unsigned* __restrict__ Wp,
                                                    const float* __restrict__ bias,
                                                    unsigned short* __restrict__ hBf) {
  __shared__ __attribute__((aligned(16))) unsigned sW[WEP_SZ];    // 17.4KB [n<64][kp<64] s68
  __shared__ __attribute__((aligned(16))) unsigned sxp[32 * 68];  // 8.7KB [row][kp<64] s68
  int t = threadIdx.x;
  int node0 = blockIdx.x * 32;
  int w = t >> 6, lane = t & 63;
  int fr = lane & 15, fq = lane >> 4;
  const uint4* wv4 = (const uint4*)Wp;
  for (int i = t; i < WEP_SZ / 4; i += 256) *(uint4*)&sW[i * 4] = wv4[i];
  for (int i = t; i < 2048; i += 256) {  // 32 rows x 64 kp
    int row = i >> 6, kp = i & 63;
    float2 xv = *(const float2*)&x[(size_t)(node0 + row) * DIM_IN + 2 * kp];
    sxp[row * 68 + kp] = pack2bf(xv.x, xv.y);
  }
  __syncthreads();
  f32x4 acc0 = {0.f, 0.f, 0.f, 0.f}, acc1 = acc0;
#pragma unroll
  for (int s = 0; s < 4; s++) {
    int kp0 = s * 16 + fq * 4;
    bf16x8 a0 = *(const bf16x8*)&sxp[fr * 68 + kp0];
    bf16x8 a1 = *(const bf16x8*)&sxp[(16 + fr) * 68 + kp0];
    bf16x8 wf = *(const bf16x8*)&sW[(w * 16 + fr) * 68 + kp0];
    acc0 = __builtin_amdgcn_mfma_f32_16x16x32_bf16(a0, wf, acc0, 0, 0, 0);
    acc1 = __builtin_amdgcn_mfma_f32_16x16x32_bf16(a1, wf, acc1, 0, 0, 0);
  }
  float bv = bias[w * 16 + fr];
#pragma unroll
  for (int r = 0; r < 4; r++) {
    hBf[(size_t)(node0 + fq * 4 + r) * DIM_H + w * 16 + fr] =
        (unsigned short)bf16rne(acc0[r] + bv);
    hBf[(size_t)(node0 + 16 + fq * 4 + r) * DIM_H + w * 16 + fr] =
        (unsigned short)bf16rne(acc1[r] + bv);
  }
}

// ---------------- edge aggregation + MsgNorm (paired-channel, 2 nodes/wave) --
// R12-proven, unchanged.

__global__ __launch_bounds__(256) void k_edge(const unsigned* __restrict__ xin32,
                                              const int* __restrict__ ssrc,
                                              const int* __restrict__ offs,
                                              const float* __restrict__ t_arr,
                                              const float* __restrict__ sc_arr, int layer,
                                              unsigned* __restrict__ hmid32) {
  int t = threadIdx.x;
  int wave = t >> 6, lane = t & 63;
  int half = lane >> 5, cl = lane & 31;
  int v = blockIdx.x * 8 + wave * 2 + half;
  float tval = t_arr[layer];
  float sc = sc_arr[layer];
  int beg = offs[v], end = offs[v + 1];
  unsigned xp = xin32[(size_t)v * 32 + cl];
  float xv0 = bflo(xp), xv1 = bfhi(xp);
  float D0 = 0.f, S0 = 0.f, D1 = 0.f, S1 = 0.f;
  float D2 = 0.f, S2 = 0.f, D3 = 0.f, S3 = 0.f;
  int e = beg;
  for (; e + 1 < end; e += 2) {
    int s0 = ssrc[e], s1 = ssrc[e + 1];
    unsigned u0 = xin32[(size_t)s0 * 32 + cl];
    unsigned u1 = xin32[(size_t)s1 * 32 + cl];
    float a0 = fmaxf(bflo(u0), 0.f) + 1e-7f;
    float a1 = fmaxf(bfhi(u0), 0.f) + 1e-7f;
    float b0 = fmaxf(bflo(u1), 0.f) + 1e-7f;
    float b1 = fmaxf(bfhi(u1), 0.f) + 1e-7f;
    float ea0 = __expf(tval * a0);
    float ea1 = __expf(tval * a1);
    float eb0 = __expf(tval * b0);
    float eb1 = __expf(tval * b1);
    D0 += ea0; S0 += a0 * ea0;
    D1 += ea1; S1 += a1 * ea1;
    D2 += eb0; S2 += b0 * eb0;
    D3 += eb1; S3 += b1 * eb1;
  }
  if (e < end) {
    int s0 = ssrc[e];
    unsigned u0 = xin32[(size_t)s0 * 32 + cl];
    float a0 = fmaxf(bflo(u0), 0.f) + 1e-7f;
    float a1 = fmaxf(bfhi(u0), 0.f) + 1e-7f;
    float ea0 = __expf(tval * a0);
    float ea1 = __expf(tval * a1);
    D0 += ea0; S0 += a0 * ea0;
    D1 += ea1; S1 += a1 * ea1;
  }
  float Da = D0 + D2, Sa = S0 + S2;  // channel 2cl
  float Db = D1 + D3, Sb = S1 + S3;  // channel 2cl+1
  int has = (end > beg);
  float agg0 = has ? (Sa / Da) : 0.f;
  float agg1 = has ? (Sb / Db) : 0.f;
  float na = agg0 * agg0 + agg1 * agg1;
  float nx = xv0 * xv0 + xv1 * xv1;
#pragma unroll
  for (int m = 1; m < 32; m <<= 1) {
    na += __shfl_xor(na, m, 64);
    nx += __shfl_xor(nx, m, 64);
  }
  float inv = sc * sqrtf(nx) / fmaxf(sqrtf(na), 1e-12f);
  float r0 = xv0 + inv * agg0;
  float r1 = xv1 + inv * agg1;
  hmid32[(size_t)v * 32 + cl] = pack2bf(r0, r1);
}

// ---------------- GENConv MLP: wave-autonomous, barrier-free MFMA ----------
// Wave = 16 nodes (6250 waves, grid 1563x4). No __syncthreads: A-frags from
// global (lane l: row l&15, m89-verified layout), W B-frags direct from
// pre-packed global (L2-hot), C1 in regs, LN via 16-lane shfl groups (D
// layout: row fq*4+r, col nt*16+fr -> each row's cols live in one fq group),
// U transposed through WAVE-PRIVATE LDS scratch (lgkmcnt orders it), GEMM2,
// epilogue straight to global. LDS 17.4KB, no barriers -> latency hidden by
// wave count, not phase overlap.

__global__ __launch_bounds__(256, 2) void k_mlp(const unsigned* __restrict__ xin32,
                                                float* __restrict__ h,
                                                unsigned short* __restrict__ rnext,
                                                const unsigned* __restrict__ W1p,
                                                const float* __restrict__ b1,
                                                const float* __restrict__ g1,
                                                const float* __restrict__ bb1,
                                                const unsigned* __restrict__ W2p,
                                                const float* __restrict__ b2,
                                                const float* __restrict__ gn,
                                                const float* __restrict__ bn, int residual) {
  __shared__ unsigned short scr[4][16][136];  // wave-private U scratch
  int t = threadIdx.x;
  int w = t >> 6, lane = t & 63;
  int wid = blockIdx.x * 4 + w;
  if (wid >= N_NODES / 16) return;  // 6250 waves exactly
  int node0 = wid * 16;
  int fr = lane & 15, fq = lane >> 4;

  // GEMM1: C1[16][128] = X[16][64] @ W1
  bf16x8 xa0 = *(const bf16x8*)&xin32[(size_t)(node0 + fr) * 32 + fq * 4];
  bf16x8 xa1 = *(const bf16x8*)&xin32[(size_t)(node0 + fr) * 32 + 16 + fq * 4];
  f32x4 c1[8];
#pragma unroll
  for (int nt = 0; nt < 8; nt++) {
    f32x4 a = {0.f, 0.f, 0.f, 0.f};
    bf16x8 w0 = *(const bf16x8*)&W1p[(size_t)(nt * 16 + fr) * 36 + fq * 4];
    bf16x8 w1 = *(const bf16x8*)&W1p[(size_t)(nt * 16 + fr) * 36 + 16 + fq * 4];
    a = __builtin_amdgcn_mfma_f32_16x16x32_bf16(xa0, w0, a, 0, 0, 0);
    a = __builtin_amdgcn_mfma_f32_16x16x32_bf16(xa1, w1, a, 0, 0, 0);
    c1[nt] = a;
  }
  // LN over 128 cols per row; lane holds C1[row=fq*4+r][col=nt*16+fr]
  float b1v[8], g1v[8], bb1v[8];
#pragma unroll
  for (int nt = 0; nt < 8; nt++) {
    b1v[nt] = b1[nt * 16 + fr];
    g1v[nt] = g1[nt * 16 + fr];
    bb1v[nt] = bb1[nt * 16 + fr];
  }
#pragma unroll
  for (int r = 0; r < 4; r++) {
    float s1 = 0.f, s2 = 0.f;
#pragma unroll
    for (int nt = 0; nt < 8; nt++) {
      float u = c1[nt][r] + b1v[nt];
      s1 += u;
      s2 += u * u;
    }
#pragma unroll
    for (int m = 1; m < 16; m <<= 1) {
      s1 += __shfl_xor(s1, m, 64);
      s2 += __shfl_xor(s2, m, 64);
    }
    float mu = s1 * (1.f / 128.f);
    float var = s2 * (1.f / 128.f) - mu * mu;
    float rs = rsqrtf(var + 1e-5f);
    int row = fq * 4 + r;
#pragma unroll
    for (int nt = 0; nt < 8; nt++) {
      float u = c1[nt][r] + b1v[nt];
      u = fmaxf((u - mu) * rs * g1v[nt] + bb1v[nt], 0.f);
      scr[w][row][nt * 16 + fr] = (unsigned short)bf16rne(u);
    }
  }
  // GEMM2: C2[16][64] = U[16][128] @ W2 (A-frag k = s*32+fq*8+e)
  bf16x8 ua[4];
#pragma unroll
  for (int s = 0; s < 4; s++) ua[s] = *(const bf16x8*)&scr[w][fr][s * 32 + fq * 8];
  f32x4 c2[4];
#pragma unroll
  for (int nt = 0; nt < 4; nt++) {
    f32x4 a = {0.f, 0.f, 0.f, 0.f};
#pragma unroll
    for (int s = 0; s < 4; s++) {
      bf16x8 wf = *(const bf16x8*)&W2p[(size_t)(nt * 16 + fr) * 68 + s * 16 + fq * 4];
      a = __builtin_amdgcn_mfma_f32_16x16x32_bf16(ua[s], wf, a, 0, 0, 0);
    }
    c2[nt] = a;
  }
  // epilogue: +b2 (+res) -> h f32; prenorm -> rnext bf16
  float b2v[4], gv[4], bv[4];
#pragma unroll
  for (int nt = 0; nt < 4; nt++) {
    b2v[nt] = b2[nt * 16 + fr];
    gv[nt] = gn[nt * 16 + fr];
    bv[nt] = bn[nt * 16 + fr];
  }
#pragma unroll
  for (int r = 0; r < 4; r++) {
    int row = fq * 4 + r;
    size_t base = (size_t)(node0 + row) * DIM_H;
    float o0, o1, o2, o3, s1, s2;
    o0 = c2[0][r] + b2v[0];
    o1 = c2[1][r] + b2v[1];
    o2 = c2[2][r] + b2v[2];
    o3 = c2[3][r] + b2v[3];
    if (residual) {
      o0 += h[base + 0 * 16 + fr];
      o1 += h[base + 1 * 16 + fr];
      o2 += h[base + 2 * 16 + fr];
      o3 += h[base + 3 * 16 + fr];
    }
    s1 = (o0 + o1) + (o2 + o3);
    s2 = (o0 * o0 + o1 * o1) + (o2 * o2 + o3 * o3);
#pragma unroll
    for (int m = 1; m < 16; m <<= 1) {
      s1 += __shfl_xor(s1, m, 64);
      s2 += __shfl_xor(s2, m, 64);
    }
    float mu = s1 * (1.f / 64.f);
    float var = s2 * (1.f / 64.f) - mu * mu;
    float rs = rsqrtf(var + 1e-5f);
    h[base + 0 * 16 + fr] = o0;
    h[base + 1 * 16 + fr] = o1;
    h[base + 2 * 16 + fr] = o2;
    h[base + 3 * 16 + fr] = o3;
    rnext[base + 0 * 16 + fr] = (unsigned short)bf16rne(fmaxf((o0 - mu) * rs * gv[0] + bv[0], 0.f));
    rnext[base + 1 * 16 + fr] = (unsigned short)bf16rne(fmaxf((o1 - mu) * rs * gv[1] + bv[1], 0.f));
    rnext[base + 2 * 16 + fr] = (unsigned short)bf16rne(fmaxf((o2 - mu) * rs * gv[2] + bv[2], 0.f));
    rnext[base + 3 * 16 + fr] = (unsigned short)bf16rne(fmaxf((o3 - mu) * rs * gv[3] + bv[3], 0.f));
  }
}

// ---------------- final via MFMA: out = rB @ lin_W + lin_b ------------------
// Wave = 16 nodes, 7 n-tiles, K=64. No LDS, no barriers; D -> global direct.

__global__ __launch_bounds__(256, 2) void k_final(const unsigned* __restrict__ rB32,
                                                  const unsigned* __restrict__ Wp,
                                                  const float* __restrict__ bias,
                                                  float* __restrict__ out) {
  int t = threadIdx.x;
  int w = t >> 6, lane = t & 63;
  int wid = blockIdx.x * 4 + w;
  if (wid >= N_NODES / 16) return;
  int node0 = wid * 16;
  int fr = lane & 15, fq = lane >> 4;
  bf16x8 xa0 = *(const bf16x8*)&rB32[(size_t)(node0 + fr) * 32 + fq * 4];
  bf16x8 xa1 = *(const bf16x8*)&rB32[(size_t)(node0 + fr) * 32 + 16 + fq * 4];
#pragma unroll
  for (int nt = 0; nt < 7; nt++) {
    f32x4 a = {0.f, 0.f, 0.f, 0.f};
    bf16x8 w0 = *(const bf16x8*)&Wp[(size_t)(nt * 16 + fr) * 36 + fq * 4];
    bf16x8 w1 = *(const bf16x8*)&Wp[(size_t)(nt * 16 + fr) * 36 + 16 + fq * 4];
    a = __builtin_amdgcn_mfma_f32_16x16x32_bf16(xa0, w0, a, 0, 0, 0);
    a = __builtin_amdgcn_mfma_f32_16x16x32_bf16(xa1, w1, a, 0, 0, 0);
    float bv = bias[nt * 16 + fr];
#pragma unroll
    for (int r = 0; r < 4; r++)
      out[(size_t)(node0 + fq * 4 + r) * DIM_OUT + nt * 16 + fr] = a[r] + bv;
  }
}

// ---------------- launch ----------------

extern "C" void kernel_launch(void* const* d_in, const int* in_sizes, int n_in,
                              void* d_out, int out_size, void* d_ws, size_t ws_size,
                              hipStream_t stream) {
  const float* x = (const float*)d_in[0];
  const int* ei = (const int*)d_in[1];
  const float* encW = (const float*)d_in[2];
  const float* encb = (const float*)d_in[3];
  const float* t_arr = (const float*)d_in[4];
  const float* sc_arr = (const float*)d_in[5];
  const float* W1 = (const float*)d_in[6];
  const float* b1 = (const float*)d_in[7];
  const float* g1 = (const float*)d_in[8];
  const float* bb1 = (const float*)d_in[9];
  const float* W2 = (const float*)d_in[10];
  const float* b2 = (const float*)d_in[11];
  const float* ng = (const float*)d_in[12];
  const float* nbias = (const float*)d_in[13];
  const float* linW = (const float*)d_in[14];
  const float* linb = (const float*)d_in[15];

  float* hA = (float*)d_ws;                                             // N*64 f32 h-state
  unsigned short* mCbf = (unsigned short*)(hA + (size_t)N_NODES * DIM_H);  // N*64 bf16 edge-out
  unsigned short* rBf = mCbf + (size_t)N_NODES * DIM_H;                 // N*64 bf16
  unsigned short* hBf = rBf + (size_t)N_NODES * DIM_H;                  // N*64 bf16
  int* ssrc = (int*)(hBf + (size_t)N_NODES * DIM_H);                    // E
  int* offs = ssrc + N_EDGES;                                           // N+1
  int* cursor = offs + (N_NODES + 1);                                   // N
  int* counts = cursor + N_NODES;                                       // N
  int* bsums = counts + N_NODES;                                        // <=512
  unsigned* W1p = (unsigned*)(((uintptr_t)(bsums + 512) + 15) & ~(uintptr_t)15);
  unsigned* W2p = W1p + (size_t)N_LAYERS * W1P_SZ;
  unsigned* Wep = W2p + (size_t)N_LAYERS * W2P_SZ;
  unsigned* Wfp = Wep + WEP_SZ;

  const int* srcI = ei;
  const int* dstI = ei + N_EDGES;

  const int nbScan = (N_NODES + 255) / 256;  // 391
  const int nbEdge = (N_EDGES + 255) / 256;  // 4688
  const int nbWave = (N_NODES / 16 + 3) / 4;  // 1563 blocks of 4 waves

  // CSR build (dst-sorted src list) + weight pre-pack
  k_zero_i<<<nbScan, 256, 0, stream>>>(counts, N_NODES);
  k_hist<<<nbEdge, 256, 0, stream>>>(dstI, counts);
  k_prepack<<<dim3(3, N_LAYERS), 256, 0, stream>>>(W1, W2, W1p, W2p);
  k_prepack_enc<<<3, 256, 0, stream>>>(encW, Wep);
  k_prepack_fin<<<3, 256, 0, stream>>>(linW, Wfp);
  k_scan1<<<nbScan, 256, 0, stream>>>(counts, bsums);
  k_scan2<<<1, 512, 0, stream>>>(bsums, nbScan);
  k_scan3<<<nbScan, 256, 0, stream>>>(counts, bsums, offs);
  k_copy_i<<<nbScan, 256, 0, stream>>>(offs, cursor, N_NODES);
  k_scatter<<<8 * nbEdge, 256, 0, stream>>>(srcI, dstI, cursor, ssrc);

  // encoder (MFMA) -> hBf (bf16)
  k_encoder<<<N_NODES / 32, 256, 0, stream>>>(x, Wep, encb, hBf);

  // layers 0..6: gather(paired bf16) -> mCbf -> wave-autonomous MFMA MLP
  for (int i = 0; i < N_LAYERS; i++) {
    int nx = (i + 1 < N_LAYERS) ? (i + 1) : 0;
    const unsigned* gin32 = (const unsigned*)((i == 0) ? hBf : rBf);
    k_edge<<<N_NODES / 8, 256, 0, stream>>>(gin32, ssrc, offs, t_arr, sc_arr, i,
                                            (unsigned*)mCbf);
    k_mlp<<<nbWave, 256, 0, stream>>>(
        (const unsigned*)mCbf, hA, rBf, W1p + (size_t)i * W1P_SZ, b1 + i * DIM_H2,
        g1 + i * DIM_H2, bb1 + i * DIM_H2, W2p + (size_t)i * W2P_SZ, b2 + i * DIM_H,
        ng + nx * DIM_H, nbias + nx * DIM_H, (i > 0) ? 1 : 0);
  }

  // final: rBf = bf16(relu(LN(h, nrm_0))); MFMA GEMM straight to out
  k_final<<<nbWave, 256, 0, stream>>>((const unsigned*)rBf, Wfp, linb, (float*)d_out);
}

// Round 15
// 625.105 us; speedup vs baseline: 2.7308x; 1.1087x over previous
//
#include <hip/hip_runtime.h>

#define N_NODES 100000
#define N_EDGES 1200000
#define DIM_IN 128
#define DIM_H 64
#define DIM_H2 128
#define DIM_OUT 112
#define N_LAYERS 7

// pre-packed weight sizes (uints), padded strides baked in
#define W1P_SZ 4608  // 128 n * 36 kp-stride (kp<32 valid)
#define W2P_SZ 4352  // 64 n * 68 kp-stride (kp<64 valid)
#define WEP_SZ 4352  // encoder: 64 n * 68 kp-stride (kp<64 valid)
#define WFP_SZ 4032  // final: 112 n * 36 kp-stride (kp<32 valid)

typedef __attribute__((ext_vector_type(8))) short bf16x8;
typedef __attribute__((ext_vector_type(4))) float f32x4;

__device__ __forceinline__ float wsum(float v) {
#pragma unroll
  for (int m = 1; m < 64; m <<= 1) v += __shfl_xor(v, m, 64);
  return v;
}

// bf16 pack/unpack: bf16->f32 is just <<16 (bit ops, no cvt instruction)
__device__ __forceinline__ unsigned bf16rne(float f) {
  unsigned u = __float_as_uint(f);
  return (u + 0x7fffu + ((u >> 16) & 1u)) >> 16;
}
__device__ __forceinline__ unsigned pack2bf(float lo, float hi) {
  return bf16rne(lo) | (bf16rne(hi) << 16);
}
__device__ __forceinline__ float bflo(unsigned p) { return __uint_as_float(p << 16); }
__device__ __forceinline__ float bfhi(unsigned p) { return __uint_as_float(p & 0xffff0000u); }
__device__ __forceinline__ float bfu(unsigned short u) {
  return __uint_as_float(((unsigned)u) << 16);
}
// raw v_exp_f32 (2^x); __exp2f does not exist in HIP device code (R14 lesson)
__device__ __forceinline__ float exp2r(float x) { return __builtin_amdgcn_exp2f(x); }

// ---------------- preprocessing: CSR build (dst-sorted) ----------------

__global__ void k_zero_i(int* __restrict__ p, int n) {
  int i = blockIdx.x * 256 + threadIdx.x;
  if (i < n) p[i] = 0;
}

__global__ void k_hist(const int* __restrict__ dst, int* __restrict__ counts) {
  int e = blockIdx.x * 256 + threadIdx.x;
  if (e < N_EDGES) atomicAdd(&counts[dst[e]], 1);
}

__global__ void k_scan1(const int* __restrict__ counts, int* __restrict__ bsums) {
  __shared__ int sd[256];
  int t = threadIdx.x;
  int i = blockIdx.x * 256 + t;
  sd[t] = (i < N_NODES) ? counts[i] : 0;
  __syncthreads();
  for (int s = 128; s > 0; s >>= 1) {
    if (t < s) sd[t] += sd[t + s];
    __syncthreads();
  }
  if (t == 0) bsums[blockIdx.x] = sd[0];
}

__global__ void k_scan2(int* __restrict__ bsums, int nb) {
  __shared__ int sd[512];
  int t = threadIdx.x;
  int v = (t < nb) ? bsums[t] : 0;
  sd[t] = v;
  __syncthreads();
  for (int o = 1; o < 512; o <<= 1) {
    int add = (t >= o) ? sd[t - o] : 0;
    __syncthreads();
    sd[t] += add;
    __syncthreads();
  }
  if (t < nb) bsums[t] = sd[t] - v;  // exclusive
}

__global__ void k_scan3(const int* __restrict__ counts, const int* __restrict__ bsums,
                        int* __restrict__ offs) {
  __shared__ int sd[256];
  int t = threadIdx.x;
  int i = blockIdx.x * 256 + t;
  int v = (i < N_NODES) ? counts[i] : 0;
  sd[t] = v;
  __syncthreads();
  for (int o = 1; o < 256; o <<= 1) {
    int add = (t >= o) ? sd[t - o] : 0;
    __syncthreads();
    sd[t] += add;
    __syncthreads();
  }
  int excl = sd[t] - v + bsums[blockIdx.x];
  if (i < N_NODES) offs[i] = excl;
  if (i == N_NODES - 1) offs[N_NODES] = excl + v;  // = E
}

__global__ void k_copy_i(const int* __restrict__ a, int* __restrict__ b, int n) {
  int i = blockIdx.x * 256 + threadIdx.x;
  if (i < n) b[i] = a[i];
}

// XCD-partitioned scatter (R11-proven): block b handles dst in [(b&7)*12500,+12500)
__global__ void k_scatter(const int* __restrict__ src, const int* __restrict__ dst,
                          int* __restrict__ cursor, int* __restrict__ ssrc) {
  int part = blockIdx.x & 7;
  int e = (blockIdx.x >> 3) * 256 + threadIdx.x;
  if (e < N_EDGES) {
    int d = dst[e];
    if ((unsigned)(d - part * (N_NODES / 8)) < (unsigned)(N_NODES / 8)) {
      int p = atomicAdd(&cursor[d], 1);
      ssrc[p] = src[e];
    }
  }
}

// ---------------- weight pre-pack (once per launch) ----------------
// W1p[L][n*36+kp] = pack2bf(W1[L][2kp][n], W1[L][2kp+1][n]); W2p same s68.
__global__ void k_prepack(const float* __restrict__ W1, const float* __restrict__ W2,
                          unsigned* __restrict__ W1p, unsigned* __restrict__ W2p) {
  int L = blockIdx.y;
  const float* w1 = W1 + (size_t)L * DIM_H * DIM_H2;
  const float* w2 = W2 + (size_t)L * DIM_H2 * DIM_H;
  unsigned* o1 = W1p + (size_t)L * W1P_SZ;
  unsigned* o2 = W2p + (size_t)L * W2P_SZ;
  for (int i = blockIdx.x * 256 + threadIdx.x; i < W1P_SZ; i += gridDim.x * 256) {
    int n = i / 36, kp = i - n * 36;
    o1[i] = (kp < 32) ? pack2bf(w1[(size_t)(2 * kp) * DIM_H2 + n],
                                w1[(size_t)(2 * kp + 1) * DIM_H2 + n]) : 0u;
  }
  for (int i = blockIdx.x * 256 + threadIdx.x; i < W2P_SZ; i += gridDim.x * 256) {
    int n = i / 68, kp = i - n * 68;
    o2[i] = (kp < 64) ? pack2bf(w2[(size_t)(2 * kp) * DIM_H + n],
                                w2[(size_t)(2 * kp + 1) * DIM_H + n]) : 0u;
  }
}

// encoder weights: encW [128][64] -> Wp [n<64][kp<64] stride 68 (W2 format)
__global__ void k_prepack_enc(const float* __restrict__ W, unsigned* __restrict__ Wp) {
  for (int i = blockIdx.x * 256 + threadIdx.x; i < WEP_SZ; i += gridDim.x * 256) {
    int n = i / 68, kp = i - n * 68;
    Wp[i] = (kp < 64) ? pack2bf(W[(size_t)(2 * kp) * DIM_H + n],
                                W[(size_t)(2 * kp + 1) * DIM_H + n]) : 0u;
  }
}

// final weights: linW [64][112] -> Wp [n<112][kp<32] stride 36
__global__ void k_prepack_fin(const float* __restrict__ W, unsigned* __restrict__ Wp) {
  for (int i = blockIdx.x * 256 + threadIdx.x; i < WFP_SZ; i += gridDim.x * 256) {
    int n = i / 36, kp = i - n * 36;
    Wp[i] = (kp < 32) ? pack2bf(W[(size_t)(2 * kp) * DIM_OUT + n],
                                W[(size_t)(2 * kp + 1) * DIM_OUT + n]) : 0u;
  }
}

// ---------------- encoder via MFMA: hBf = bf16(x @ enc_W + enc_b) ----------
// R12-proven (passed). K=128, N=64, M=32; wave w owns n-tile w.

__global__ __launch_bounds__(256, 2) void k_encoder(const float* __restrict__ x,
                                                    const unsigned* __restrict__ Wp,
                                                    const float* __restrict__ bias,
                                                    unsigned short* __restrict__ hBf) {
  __shared__ __attribute__((aligned(16))) unsigned sW[WEP_SZ];    // 17.4KB [n<64][kp<64] s68
  __shared__ __attribute__((aligned(16))) unsigned sxp[32 * 68];  // 8.7KB [row][kp<64] s68
  int t = threadIdx.x;
  int node0 = blockIdx.x * 32;
  int w = t >> 6, lane = t & 63;
  int fr = lane & 15, fq = lane >> 4;
  const uint4* wv4 = (const uint4*)Wp;
  for (int i = t; i < WEP_SZ / 4; i += 256) *(uint4*)&sW[i * 4] = wv4[i];
  for (int i = t; i < 2048; i += 256) {  // 32 rows x 64 kp
    int row = i >> 6, kp = i & 63;
    float2 xv = *(const float2*)&x[(size_t)(node0 + row) * DIM_IN + 2 * kp];
    sxp[row * 68 + kp] = pack2bf(xv.x, xv.y);
  }
  __syncthreads();
  f32x4 acc0 = {0.f, 0.f, 0.f, 0.f}, acc1 = acc0;
#pragma unroll
  for (int s = 0; s < 4; s++) {
    int kp0 = s * 16 + fq * 4;
    bf16x8 a0 = *(const bf16x8*)&sxp[fr * 68 + kp0];
    bf16x8 a1 = *(const bf16x8*)&sxp[(16 + fr) * 68 + kp0];
    bf16x8 wf = *(const bf16x8*)&sW[(w * 16 + fr) * 68 + kp0];
    acc0 = __builtin_amdgcn_mfma_f32_16x16x32_bf16(a0, wf, acc0, 0, 0, 0);
    acc1 = __builtin_amdgcn_mfma_f32_16x16x32_bf16(a1, wf, acc1, 0, 0, 0);
  }
  float bv = bias[w * 16 + fr];
#pragma unroll
  for (int r = 0; r < 4; r++) {
    hBf[(size_t)(node0 + fq * 4 + r) * DIM_H + w * 16 + fr] =
        (unsigned short)bf16rne(acc0[r] + bv);
    hBf[(size_t)(node0 + 16 + fq * 4 + r) * DIM_H + w * 16 + fr] =
        (unsigned short)bf16rne(acc1[r] + bv);
  }
}

// ---------------- edge aggregation + MsgNorm (paired, lean loop) ------------
// Half-wave per node, lane covers channels {2cl, 2cl+1}.
// eps moved OUT of the loop: exp(t*(x+eps)) = exp(t*x)*const cancels in the
// softmax, and S/D with S=sum(x*e) equals agg_true - eps EXACTLY, so
// agg = S/D + 1e-7. log2e folded into c2 -> body per channel:
// fmax, mul, v_exp, add, fma. 32-bit voffset addressing vs SGPR base.

__global__ __launch_bounds__(256) void k_edge(const unsigned* __restrict__ xin32,
                                              const int* __restrict__ ssrc,
                                              const int* __restrict__ offs,
                                              const float* __restrict__ t_arr,
                                              const float* __restrict__ sc_arr, int layer,
                                              unsigned* __restrict__ hmid32) {
  int t = threadIdx.x;
  int wave = t >> 6, lane = t & 63;
  int half = lane >> 5, cl = lane & 31;
  int v = blockIdx.x * 8 + wave * 2 + half;
  float c2 = t_arr[layer] * 1.4426950408889634f;  // t * log2(e)
  float sc = sc_arr[layer];
  int beg = offs[v], end = offs[v + 1];
  unsigned cl4 = cl << 2;
  const char* xbase = (const char*)xin32;
  unsigned xp = *(const unsigned*)(xbase + (((unsigned)v << 7) + cl4));
  float xv0 = bflo(xp), xv1 = bfhi(xp);
  float D0 = 0.f, S0 = 0.f, D1 = 0.f, S1 = 0.f;
  float D2 = 0.f, S2 = 0.f, D3 = 0.f, S3 = 0.f;
  float D4 = 0.f, S4 = 0.f, D5 = 0.f, S5 = 0.f;
  float D6 = 0.f, S6 = 0.f, D7 = 0.f, S7 = 0.f;
  int e = beg;
  for (; e + 3 < end; e += 4) {
    unsigned o0 = ((unsigned)ssrc[e] << 7) + cl4;
    unsigned o1 = ((unsigned)ssrc[e + 1] << 7) + cl4;
    unsigned o2 = ((unsigned)ssrc[e + 2] << 7) + cl4;
    unsigned o3 = ((unsigned)ssrc[e + 3] << 7) + cl4;
    unsigned u0 = *(const unsigned*)(xbase + o0);
    unsigned u1 = *(const unsigned*)(xbase + o1);
    unsigned u2 = *(const unsigned*)(xbase + o2);
    unsigned u3 = *(const unsigned*)(xbase + o3);
    float a0 = fmaxf(bflo(u0), 0.f), a1 = fmaxf(bfhi(u0), 0.f);
    float b0 = fmaxf(bflo(u1), 0.f), b1 = fmaxf(bfhi(u1), 0.f);
    float g0 = fmaxf(bflo(u2), 0.f), g1 = fmaxf(bfhi(u2), 0.f);
    float h0 = fmaxf(bflo(u3), 0.f), h1 = fmaxf(bfhi(u3), 0.f);
    float ea0 = exp2r(c2 * a0), ea1 = exp2r(c2 * a1);
    float eb0 = exp2r(c2 * b0), eb1 = exp2r(c2 * b1);
    float eg0 = exp2r(c2 * g0), eg1 = exp2r(c2 * g1);
    float eh0 = exp2r(c2 * h0), eh1 = exp2r(c2 * h1);
    D0 += ea0; S0 += a0 * ea0;
    D1 += ea1; S1 += a1 * ea1;
    D2 += eb0; S2 += b0 * eb0;
    D3 += eb1; S3 += b1 * eb1;
    D4 += eg0; S4 += g0 * eg0;
    D5 += eg1; S5 += g1 * eg1;
    D6 += eh0; S6 += h0 * eh0;
    D7 += eh1; S7 += h1 * eh1;
  }
  for (; e < end; ++e) {
    unsigned o0 = ((unsigned)ssrc[e] << 7) + cl4;
    unsigned u0 = *(const unsigned*)(xbase + o0);
    float a0 = fmaxf(bflo(u0), 0.f), a1 = fmaxf(bfhi(u0), 0.f);
    float ea0 = exp2r(c2 * a0), ea1 = exp2r(c2 * a1);
    D0 += ea0; S0 += a0 * ea0;
    D1 += ea1; S1 += a1 * ea1;
  }
  float Da = (D0 + D2) + (D4 + D6), Sa = (S0 + S2) + (S4 + S6);  // ch 2cl
  float Db = (D1 + D3) + (D5 + D7), Sb = (S1 + S3) + (S5 + S7);  // ch 2cl+1
  int has = (end > beg);
  float agg0 = has ? (Sa / Da + 1e-7f) : 0.f;
  float agg1 = has ? (Sb / Db + 1e-7f) : 0.f;
  float na = agg0 * agg0 + agg1 * agg1;
  float nx = xv0 * xv0 + xv1 * xv1;
#pragma unroll
  for (int m = 1; m < 32; m <<= 1) {
    na += __shfl_xor(na, m, 64);
    nx += __shfl_xor(nx, m, 64);
  }
  float inv = sc * sqrtf(nx) / fmaxf(sqrtf(na), 1e-12f);
  float r0 = xv0 + inv * agg0;
  float r1 = xv1 + inv * agg1;
  hmid32[(size_t)v * 32 + cl] = pack2bf(r0, r1);
}

// ---------------- GENConv MLP: wave-autonomous, barrier-free MFMA ----------
// R13-proven, unchanged (passed, absmax 0.0045, dropped out of top-5).

__global__ __launch_bounds__(256, 2) void k_mlp(const unsigned* __restrict__ xin32,
                                                float* __restrict__ h,
                                                unsigned short* __restrict__ rnext,
                                                const unsigned* __restrict__ W1p,
                                                const float* __restrict__ b1,
                                                const float* __restrict__ g1,
                                                const float* __restrict__ bb1,
                                                const unsigned* __restrict__ W2p,
                                                const float* __restrict__ b2,
                                                const float* __restrict__ gn,
                                                const float* __restrict__ bn, int residual) {
  __shared__ unsigned short scr[4][16][136];  // wave-private U scratch
  int t = threadIdx.x;
  int w = t >> 6, lane = t & 63;
  int wid = blockIdx.x * 4 + w;
  if (wid >= N_NODES / 16) return;  // 6250 waves exactly
  int node0 = wid * 16;
  int fr = lane & 15, fq = lane >> 4;

  // GEMM1: C1[16][128] = X[16][64] @ W1
  bf16x8 xa0 = *(const bf16x8*)&xin32[(size_t)(node0 + fr) * 32 + fq * 4];
  bf16x8 xa1 = *(const bf16x8*)&xin32[(size_t)(node0 + fr) * 32 + 16 + fq * 4];
  f32x4 c1[8];
#pragma unroll
  for (int nt = 0; nt < 8; nt++) {
    f32x4 a = {0.f, 0.f, 0.f, 0.f};
    bf16x8 w0 = *(const bf16x8*)&W1p[(size_t)(nt * 16 + fr) * 36 + fq * 4];
    bf16x8 w1 = *(const bf16x8*)&W1p[(size_t)(nt * 16 + fr) * 36 + 16 + fq * 4];
    a = __builtin_amdgcn_mfma_f32_16x16x32_bf16(xa0, w0, a, 0, 0, 0);
    a = __builtin_amdgcn_mfma_f32_16x16x32_bf16(xa1, w1, a, 0, 0, 0);
    c1[nt] = a;
  }
  // LN over 128 cols per row; lane holds C1[row=fq*4+r][col=nt*16+fr]
  float b1v[8], g1v[8], bb1v[8];
#pragma unroll
  for (int nt = 0; nt < 8; nt++) {
    b1v[nt] = b1[nt * 16 + fr];
    g1v[nt] = g1[nt * 16 + fr];
    bb1v[nt] = bb1[nt * 16 + fr];
  }
#pragma unroll
  for (int r = 0; r < 4; r++) {
    float s1 = 0.f, s2 = 0.f;
#pragma unroll
    for (int nt = 0; nt < 8; nt++) {
      float u = c1[nt][r] + b1v[nt];
      s1 += u;
      s2 += u * u;
    }
#pragma unroll
    for (int m = 1; m < 16; m <<= 1) {
      s1 += __shfl_xor(s1, m, 64);
      s2 += __shfl_xor(s2, m, 64);
    }
    float mu = s1 * (1.f / 128.f);
    float var = s2 * (1.f / 128.f) - mu * mu;
    float rs = rsqrtf(var + 1e-5f);
    int row = fq * 4 + r;
#pragma unroll
    for (int nt = 0; nt < 8; nt++) {
      float u = c1[nt][r] + b1v[nt];
      u = fmaxf((u - mu) * rs * g1v[nt] + bb1v[nt], 0.f);
      scr[w][row][nt * 16 + fr] = (unsigned short)bf16rne(u);
    }
  }
  // GEMM2: C2[16][64] = U[16][128] @ W2 (A-frag k = s*32+fq*8+e)
  bf16x8 ua[4];
#pragma unroll
  for (int s = 0; s < 4; s++) ua[s] = *(const bf16x8*)&scr[w][fr][s * 32 + fq * 8];
  f32x4 c2[4];
#pragma unroll
  for (int nt = 0; nt < 4; nt++) {
    f32x4 a = {0.f, 0.f, 0.f, 0.f};
#pragma unroll
    for (int s = 0; s < 4; s++) {
      bf16x8 wf = *(const bf16x8*)&W2p[(size_t)(nt * 16 + fr) * 68 + s * 16 + fq * 4];
      a = __builtin_amdgcn_mfma_f32_16x16x32_bf16(ua[s], wf, a, 0, 0, 0);
    }
    c2[nt] = a;
  }
  // epilogue: +b2 (+res) -> h f32; prenorm -> rnext bf16
  float b2v[4], gv[4], bv[4];
#pragma unroll
  for (int nt = 0; nt < 4; nt++) {
    b2v[nt] = b2[nt * 16 + fr];
    gv[nt] = gn[nt * 16 + fr];
    bv[nt] = bn[nt * 16 + fr];
  }
#pragma unroll
  for (int r = 0; r < 4; r++) {
    int row = fq * 4 + r;
    size_t base = (size_t)(node0 + row) * DIM_H;
    float o0, o1, o2, o3, s1, s2;
    o0 = c2[0][r] + b2v[0];
    o1 = c2[1][r] + b2v[1];
    o2 = c2[2][r] + b2v[2];
    o3 = c2[3][r] + b2v[3];
    if (residual) {
      o0 += h[base + 0 * 16 + fr];
      o1 += h[base + 1 * 16 + fr];
      o2 += h[base + 2 * 16 + fr];
      o3 += h[base + 3 * 16 + fr];
    }
    s1 = (o0 + o1) + (o2 + o3);
    s2 = (o0 * o0 + o1 * o1) + (o2 * o2 + o3 * o3);
#pragma unroll
    for (int m = 1; m < 16; m <<= 1) {
      s1 += __shfl_xor(s1, m, 64);
      s2 += __shfl_xor(s2, m, 64);
    }
    float mu = s1 * (1.f / 64.f);
    float var = s2 * (1.f / 64.f) - mu * mu;
    float rs = rsqrtf(var + 1e-5f);
    h[base + 0 * 16 + fr] = o0;
    h[base + 1 * 16 + fr] = o1;
    h[base + 2 * 16 + fr] = o2;
    h[base + 3 * 16 + fr] = o3;
    rnext[base + 0 * 16 + fr] = (unsigned short)bf16rne(fmaxf((o0 - mu) * rs * gv[0] + bv[0], 0.f));
    rnext[base + 1 * 16 + fr] = (unsigned short)bf16rne(fmaxf((o1 - mu) * rs * gv[1] + bv[1], 0.f));
    rnext[base + 2 * 16 + fr] = (unsigned short)bf16rne(fmaxf((o2 - mu) * rs * gv[2] + bv[2], 0.f));
    rnext[base + 3 * 16 + fr] = (unsigned short)bf16rne(fmaxf((o3 - mu) * rs * gv[3] + bv[3], 0.f));
  }
}

// ---------------- final via MFMA: out = rB @ lin_W + lin_b ------------------
// R13-proven, unchanged.

__global__ __launch_bounds__(256, 2) void k_final(const unsigned* __restrict__ rB32,
                                                  const unsigned* __restrict__ Wp,
                                                  const float* __restrict__ bias,
                                                  float* __restrict__ out) {
  int t = threadIdx.x;
  int w = t >> 6, lane = t & 63;
  int wid = blockIdx.x * 4 + w;
  if (wid >= N_NODES / 16) return;
  int node0 = wid * 16;
  int fr = lane & 15, fq = lane >> 4;
  bf16x8 xa0 = *(const bf16x8*)&rB32[(size_t)(node0 + fr) * 32 + fq * 4];
  bf16x8 xa1 = *(const bf16x8*)&rB32[(size_t)(node0 + fr) * 32 + 16 + fq * 4];
#pragma unroll
  for (int nt = 0; nt < 7; nt++) {
    f32x4 a = {0.f, 0.f, 0.f, 0.f};
    bf16x8 w0 = *(const bf16x8*)&Wp[(size_t)(nt * 16 + fr) * 36 + fq * 4];
    bf16x8 w1 = *(const bf16x8*)&Wp[(size_t)(nt * 16 + fr) * 36 + 16 + fq * 4];
    a = __builtin_amdgcn_mfma_f32_16x16x32_bf16(xa0, w0, a, 0, 0, 0);
    a = __builtin_amdgcn_mfma_f32_16x16x32_bf16(xa1, w1, a, 0, 0, 0);
    float bv = bias[nt * 16 + fr];
#pragma unroll
    for (int r = 0; r < 4; r++)
      out[(size_t)(node0 + fq * 4 + r) * DIM_OUT + nt * 16 + fr] = a[r] + bv;
  }
}

// ---------------- launch ----------------

extern "C" void kernel_launch(void* const* d_in, const int* in_sizes, int n_in,
                              void* d_out, int out_size, void* d_ws, size_t ws_size,
                              hipStream_t stream) {
  const float* x = (const float*)d_in[0];
  const int* ei = (const int*)d_in[1];
  const float* encW = (const float*)d_in[2];
  const float* encb = (const float*)d_in[3];
  const float* t_arr = (const float*)d_in[4];
  const float* sc_arr = (const float*)d_in[5];
  const float* W1 = (const float*)d_in[6];
  const float* b1 = (const float*)d_in[7];
  const float* g1 = (const float*)d_in[8];
  const float* bb1 = (const float*)d_in[9];
  const float* W2 = (const float*)d_in[10];
  const float* b2 = (const float*)d_in[11];
  const float* ng = (const float*)d_in[12];
  const float* nbias = (const float*)d_in[13];
  const float* linW = (const float*)d_in[14];
  const float* linb = (const float*)d_in[15];

  float* hA = (float*)d_ws;                                             // N*64 f32 h-state
  unsigned short* mCbf = (unsigned short*)(hA + (size_t)N_NODES * DIM_H);  // N*64 bf16 edge-out
  unsigned short* rBf = mCbf + (size_t)N_NODES * DIM_H;                 // N*64 bf16
  unsigned short* hBf = rBf + (size_t)N_NODES * DIM_H;                  // N*64 bf16
  int* ssrc = (int*)(hBf + (size_t)N_NODES * DIM_H);                    // E
  int* offs = ssrc + N_EDGES;                                           // N+1
  int* cursor = offs + (N_NODES + 1);                                   // N
  int* counts = cursor + N_NODES;                                       // N
  int* bsums = counts + N_NODES;                                        // <=512
  unsigned* W1p = (unsigned*)(((uintptr_t)(bsums + 512) + 15) & ~(uintptr_t)15);
  unsigned* W2p = W1p + (size_t)N_LAYERS * W1P_SZ;
  unsigned* Wep = W2p + (size_t)N_LAYERS * W2P_SZ;
  unsigned* Wfp = Wep + WEP_SZ;

  const int* srcI = ei;
  const int* dstI = ei + N_EDGES;

  const int nbScan = (N_NODES + 255) / 256;  // 391
  const int nbEdge = (N_EDGES + 255) / 256;  // 4688
  const int nbWave = (N_NODES / 16 + 3) / 4;  // 1563 blocks of 4 waves

  // CSR build (dst-sorted src list) + weight pre-pack
  k_zero_i<<<nbScan, 256, 0, stream>>>(counts, N_NODES);
  k_hist<<<nbEdge, 256, 0, stream>>>(dstI, counts);
  k_prepack<<<dim3(3, N_LAYERS), 256, 0, stream>>>(W1, W2, W1p, W2p);
  k_prepack_enc<<<3, 256, 0, stream>>>(encW, Wep);
  k_prepack_fin<<<3, 256, 0, stream>>>(linW, Wfp);
  k_scan1<<<nbScan, 256, 0, stream>>>(counts, bsums);
  k_scan2<<<1, 512, 0, stream>>>(bsums, nbScan);
  k_scan3<<<nbScan, 256, 0, stream>>>(counts, bsums, offs);
  k_copy_i<<<nbScan, 256, 0, stream>>>(offs, cursor, N_NODES);
  k_scatter<<<8 * nbEdge, 256, 0, stream>>>(srcI, dstI, cursor, ssrc);

  // encoder (MFMA) -> hBf (bf16)
  k_encoder<<<N_NODES / 32, 256, 0, stream>>>(x, Wep, encb, hBf);

  // layers 0..6: gather(paired bf16) -> mCbf -> wave-autonomous MFMA MLP
  for (int i = 0; i < N_LAYERS; i++) {
    int nx = (i + 1 < N_LAYERS) ? (i + 1) : 0;
    const unsigned* gin32 = (const unsigned*)((i == 0) ? hBf : rBf);
    k_edge<<<N_NODES / 8, 256, 0, stream>>>(gin32, ssrc, offs, t_arr, sc_arr, i,
                                            (unsigned*)mCbf);
    k_mlp<<<nbWave, 256, 0, stream>>>(
        (const unsigned*)mCbf, hA, rBf, W1p + (size_t)i * W1P_SZ, b1 + i * DIM_H2,
        g1 + i * DIM_H2, bb1 + i * DIM_H2, W2p + (size_t)i * W2P_SZ, b2 + i * DIM_H,
        ng + nx * DIM_H, nbias + nx * DIM_H, (i > 0) ? 1 : 0);
  }

  // final: rBf = bf16(relu(LN(h, nrm_0))); MFMA GEMM straight to out
  k_final<<<nbWave, 256, 0, stream>>>((const unsigned*)rBf, Wfp, linb, (float*)d_out);
}

// Round 16
// 585.599 us; speedup vs baseline: 2.9150x; 1.0675x over previous
//
#include <hip/hip_runtime.h>

#define N_NODES 100000
#define N_EDGES 1200000
#define DIM_IN 128
#define DIM_H 64
#define DIM_H2 128
#define DIM_OUT 112
#define N_LAYERS 7

// pre-packed weight sizes (uints), padded strides baked in
#define W1P_SZ 4608  // 128 n * 36 kp-stride (kp<32 valid)
#define W2P_SZ 4352  // 64 n * 68 kp-stride (kp<64 valid)
#define WEP_SZ 4352  // encoder: 64 n * 68 kp-stride (kp<64 valid)
#define WFP_SZ 4032  // final: 112 n * 36 kp-stride (kp<32 valid)

typedef __attribute__((ext_vector_type(8))) short bf16x8;
typedef __attribute__((ext_vector_type(4))) float f32x4;

__device__ __forceinline__ float wsum(float v) {
#pragma unroll
  for (int m = 1; m < 64; m <<= 1) v += __shfl_xor(v, m, 64);
  return v;
}

// bf16 pack/unpack: bf16->f32 is just <<16 (bit ops, no cvt instruction)
__device__ __forceinline__ unsigned bf16rne(float f) {
  unsigned u = __float_as_uint(f);
  return (u + 0x7fffu + ((u >> 16) & 1u)) >> 16;
}
__device__ __forceinline__ unsigned pack2bf(float lo, float hi) {
  return bf16rne(lo) | (bf16rne(hi) << 16);
}
__device__ __forceinline__ float bflo(unsigned p) { return __uint_as_float(p << 16); }
__device__ __forceinline__ float bfhi(unsigned p) { return __uint_as_float(p & 0xffff0000u); }
__device__ __forceinline__ float bfu(unsigned short u) {
  return __uint_as_float(((unsigned)u) << 16);
}
// raw v_exp_f32 (2^x); __exp2f does not exist in HIP device code (R14 lesson)
__device__ __forceinline__ float exp2r(float x) { return __builtin_amdgcn_exp2f(x); }

// ---------------- preprocessing: CSR build (dst-sorted, rank-based) ---------

__global__ void k_zero_i(int* __restrict__ p, int n) {
  int i = blockIdx.x * 256 + threadIdx.x;
  if (i < n) p[i] = 0;
}

// hist + per-edge rank capture: rank[e] = old count. Removes the need for a
// cursor pass + scatter atomics (R15: scatter WRITE 51MB ~= atomic line traffic).
__global__ void k_hist(const int* __restrict__ dst, int* __restrict__ counts,
                       int* __restrict__ rank) {
  int e = blockIdx.x * 256 + threadIdx.x;
  if (e < N_EDGES) rank[e] = atomicAdd(&counts[dst[e]], 1);
}

__global__ void k_scan1(const int* __restrict__ counts, int* __restrict__ bsums) {
  __shared__ int sd[256];
  int t = threadIdx.x;
  int i = blockIdx.x * 256 + t;
  sd[t] = (i < N_NODES) ? counts[i] : 0;
  __syncthreads();
  for (int s = 128; s > 0; s >>= 1) {
    if (t < s) sd[t] += sd[t + s];
    __syncthreads();
  }
  if (t == 0) bsums[blockIdx.x] = sd[0];
}

__global__ void k_scan2(int* __restrict__ bsums, int nb) {
  __shared__ int sd[512];
  int t = threadIdx.x;
  int v = (t < nb) ? bsums[t] : 0;
  sd[t] = v;
  __syncthreads();
  for (int o = 1; o < 512; o <<= 1) {
    int add = (t >= o) ? sd[t - o] : 0;
    __syncthreads();
    sd[t] += add;
    __syncthreads();
  }
  if (t < nb) bsums[t] = sd[t] - v;  // exclusive
}

__global__ void k_scan3(const int* __restrict__ counts, const int* __restrict__ bsums,
                        int* __restrict__ offs) {
  __shared__ int sd[256];
  int t = threadIdx.x;
  int i = blockIdx.x * 256 + t;
  int v = (i < N_NODES) ? counts[i] : 0;
  sd[t] = v;
  __syncthreads();
  for (int o = 1; o < 256; o <<= 1) {
    int add = (t >= o) ? sd[t - o] : 0;
    __syncthreads();
    sd[t] += add;
    __syncthreads();
  }
  int excl = sd[t] - v + bsums[blockIdx.x];
  if (i < N_NODES) offs[i] = excl;
  if (i == N_NODES - 1) offs[N_NODES] = excl + v;  // = E
}

// atomic-free scatter: position = offs[dst] + rank. Single pass over edges.
__global__ void k_scatter(const int* __restrict__ src, const int* __restrict__ dst,
                          const int* __restrict__ rank, const int* __restrict__ offs,
                          int* __restrict__ ssrc) {
  int e = blockIdx.x * 256 + threadIdx.x;
  if (e < N_EDGES) {
    int p = offs[dst[e]] + rank[e];
    ssrc[p] = src[e];
  }
}

// ---------------- weight pre-pack (once per launch) ----------------
// W1p[L][n*36+kp] = pack2bf(W1[L][2kp][n], W1[L][2kp+1][n]); W2p same s68.
__global__ void k_prepack(const float* __restrict__ W1, const float* __restrict__ W2,
                          unsigned* __restrict__ W1p, unsigned* __restrict__ W2p) {
  int L = blockIdx.y;
  const float* w1 = W1 + (size_t)L * DIM_H * DIM_H2;
  const float* w2 = W2 + (size_t)L * DIM_H2 * DIM_H;
  unsigned* o1 = W1p + (size_t)L * W1P_SZ;
  unsigned* o2 = W2p + (size_t)L * W2P_SZ;
  for (int i = blockIdx.x * 256 + threadIdx.x; i < W1P_SZ; i += gridDim.x * 256) {
    int n = i / 36, kp = i - n * 36;
    o1[i] = (kp < 32) ? pack2bf(w1[(size_t)(2 * kp) * DIM_H2 + n],
                                w1[(size_t)(2 * kp + 1) * DIM_H2 + n]) : 0u;
  }
  for (int i = blockIdx.x * 256 + threadIdx.x; i < W2P_SZ; i += gridDim.x * 256) {
    int n = i / 68, kp = i - n * 68;
    o2[i] = (kp < 64) ? pack2bf(w2[(size_t)(2 * kp) * DIM_H + n],
                                w2[(size_t)(2 * kp + 1) * DIM_H + n]) : 0u;
  }
}

// encoder weights: encW [128][64] -> Wp [n<64][kp<64] stride 68 (W2 format)
__global__ void k_prepack_enc(const float* __restrict__ W, unsigned* __restrict__ Wp) {
  for (int i = blockIdx.x * 256 + threadIdx.x; i < WEP_SZ; i += gridDim.x * 256) {
    int n = i / 68, kp = i - n * 68;
    Wp[i] = (kp < 64) ? pack2bf(W[(size_t)(2 * kp) * DIM_H + n],
                                W[(size_t)(2 * kp + 1) * DIM_H + n]) : 0u;
  }
}

// final weights: linW [64][112] -> Wp [n<112][kp<32] stride 36
__global__ void k_prepack_fin(const float* __restrict__ W, unsigned* __restrict__ Wp) {
  for (int i = blockIdx.x * 256 + threadIdx.x; i < WFP_SZ; i += gridDim.x * 256) {
    int n = i / 36, kp = i - n * 36;
    Wp[i] = (kp < 32) ? pack2bf(W[(size_t)(2 * kp) * DIM_OUT + n],
                                W[(size_t)(2 * kp + 1) * DIM_OUT + n]) : 0u;
  }
}

// ---------------- encoder via MFMA: hBf = bf16(x @ enc_W + enc_b) ----------
// R12-proven (passed). K=128, N=64, M=32; wave w owns n-tile w.

__global__ __launch_bounds__(256, 2) void k_encoder(const float* __restrict__ x,
                                                    const unsigned* __restrict__ Wp,
                                                    const float* __restrict__ bias,
                                                    unsigned short* __restrict__ hBf) {
  __shared__ __attribute__((aligned(16))) unsigned sW[WEP_SZ];    // 17.4KB [n<64][kp<64] s68
  __shared__ __attribute__((aligned(16))) unsigned sxp[32 * 68];  // 8.7KB [row][kp<64] s68
  int t = threadIdx.x;
  int node0 = blockIdx.x * 32;
  int w = t >> 6, lane = t & 63;
  int fr = lane & 15, fq = lane >> 4;
  const uint4* wv4 = (const uint4*)Wp;
  for (int i = t; i < WEP_SZ / 4; i += 256) *(uint4*)&sW[i * 4] = wv4[i];
  for (int i = t; i < 2048; i += 256) {  // 32 rows x 64 kp
    int row = i >> 6, kp = i & 63;
    float2 xv = *(const float2*)&x[(size_t)(node0 + row) * DIM_IN + 2 * kp];
    sxp[row * 68 + kp] = pack2bf(xv.x, xv.y);
  }
  __syncthreads();
  f32x4 acc0 = {0.f, 0.f, 0.f, 0.f}, acc1 = acc0;
#pragma unroll
  for (int s = 0; s < 4; s++) {
    int kp0 = s * 16 + fq * 4;
    bf16x8 a0 = *(const bf16x8*)&sxp[fr * 68 + kp0];
    bf16x8 a1 = *(const bf16x8*)&sxp[(16 + fr) * 68 + kp0];
    bf16x8 wf = *(const bf16x8*)&sW[(w * 16 + fr) * 68 + kp0];
    acc0 = __builtin_amdgcn_mfma_f32_16x16x32_bf16(a0, wf, acc0, 0, 0, 0);
    acc1 = __builtin_amdgcn_mfma_f32_16x16x32_bf16(a1, wf, acc1, 0, 0, 0);
  }
  float bv = bias[w * 16 + fr];
#pragma unroll
  for (int r = 0; r < 4; r++) {
    hBf[(size_t)(node0 + fq * 4 + r) * DIM_H + w * 16 + fr] =
        (unsigned short)bf16rne(acc0[r] + bv);
    hBf[(size_t)(node0 + 16 + fq * 4 + r) * DIM_H + w * 16 + fr] =
        (unsigned short)bf16rne(acc1[r] + bv);
  }
}

// ---------------- edge aggregation + MsgNorm (paired, lean loop) ------------
// R15-proven, unchanged.

__global__ __launch_bounds__(256) void k_edge(const unsigned* __restrict__ xin32,
                                              const int* __restrict__ ssrc,
                                              const int* __restrict__ offs,
                                              const float* __restrict__ t_arr,
                                              const float* __restrict__ sc_arr, int layer,
                                              unsigned* __restrict__ hmid32) {
  int t = threadIdx.x;
  int wave = t >> 6, lane = t & 63;
  int half = lane >> 5, cl = lane & 31;
  int v = blockIdx.x * 8 + wave * 2 + half;
  float c2 = t_arr[layer] * 1.4426950408889634f;  // t * log2(e)
  float sc = sc_arr[layer];
  int beg = offs[v], end = offs[v + 1];
  unsigned cl4 = cl << 2;
  const char* xbase = (const char*)xin32;
  unsigned xp = *(const unsigned*)(xbase + (((unsigned)v << 7) + cl4));
  float xv0 = bflo(xp), xv1 = bfhi(xp);
  float D0 = 0.f, S0 = 0.f, D1 = 0.f, S1 = 0.f;
  float D2 = 0.f, S2 = 0.f, D3 = 0.f, S3 = 0.f;
  float D4 = 0.f, S4 = 0.f, D5 = 0.f, S5 = 0.f;
  float D6 = 0.f, S6 = 0.f, D7 = 0.f, S7 = 0.f;
  int e = beg;
  for (; e + 3 < end; e += 4) {
    unsigned o0 = ((unsigned)ssrc[e] << 7) + cl4;
    unsigned o1 = ((unsigned)ssrc[e + 1] << 7) + cl4;
    unsigned o2 = ((unsigned)ssrc[e + 2] << 7) + cl4;
    unsigned o3 = ((unsigned)ssrc[e + 3] << 7) + cl4;
    unsigned u0 = *(const unsigned*)(xbase + o0);
    unsigned u1 = *(const unsigned*)(xbase + o1);
    unsigned u2 = *(const unsigned*)(xbase + o2);
    unsigned u3 = *(const unsigned*)(xbase + o3);
    float a0 = fmaxf(bflo(u0), 0.f), a1 = fmaxf(bfhi(u0), 0.f);
    float b0 = fmaxf(bflo(u1), 0.f), b1 = fmaxf(bfhi(u1), 0.f);
    float g0 = fmaxf(bflo(u2), 0.f), g1 = fmaxf(bfhi(u2), 0.f);
    float h0 = fmaxf(bflo(u3), 0.f), h1 = fmaxf(bfhi(u3), 0.f);
    float ea0 = exp2r(c2 * a0), ea1 = exp2r(c2 * a1);
    float eb0 = exp2r(c2 * b0), eb1 = exp2r(c2 * b1);
    float eg0 = exp2r(c2 * g0), eg1 = exp2r(c2 * g1);
    float eh0 = exp2r(c2 * h0), eh1 = exp2r(c2 * h1);
    D0 += ea0; S0 += a0 * ea0;
    D1 += ea1; S1 += a1 * ea1;
    D2 += eb0; S2 += b0 * eb0;
    D3 += eb1; S3 += b1 * eb1;
    D4 += eg0; S4 += g0 * eg0;
    D5 += eg1; S5 += g1 * eg1;
    D6 += eh0; S6 += h0 * eh0;
    D7 += eh1; S7 += h1 * eh1;
  }
  for (; e < end; ++e) {
    unsigned o0 = ((unsigned)ssrc[e] << 7) + cl4;
    unsigned u0 = *(const unsigned*)(xbase + o0);
    float a0 = fmaxf(bflo(u0), 0.f), a1 = fmaxf(bfhi(u0), 0.f);
    float ea0 = exp2r(c2 * a0), ea1 = exp2r(c2 * a1);
    D0 += ea0; S0 += a0 * ea0;
    D1 += ea1; S1 += a1 * ea1;
  }
  float Da = (D0 + D2) + (D4 + D6), Sa = (S0 + S2) + (S4 + S6);  // ch 2cl
  float Db = (D1 + D3) + (D5 + D7), Sb = (S1 + S3) + (S5 + S7);  // ch 2cl+1
  int has = (end > beg);
  float agg0 = has ? (Sa / Da + 1e-7f) : 0.f;
  float agg1 = has ? (Sb / Db + 1e-7f) : 0.f;
  float na = agg0 * agg0 + agg1 * agg1;
  float nx = xv0 * xv0 + xv1 * xv1;
#pragma unroll
  for (int m = 1; m < 32; m <<= 1) {
    na += __shfl_xor(na, m, 64);
    nx += __shfl_xor(nx, m, 64);
  }
  float inv = sc * sqrtf(nx) / fmaxf(sqrtf(na), 1e-12f);
  float r0 = xv0 + inv * agg0;
  float r1 = xv1 + inv * agg1;
  hmid32[(size_t)v * 32 + cl] = pack2bf(r0, r1);
}

// ---------------- GENConv MLP: wave-autonomous, barrier-free MFMA ----------
// R13-proven, unchanged.

__global__ __launch_bounds__(256, 2) void k_mlp(const unsigned* __restrict__ xin32,
                                                float* __restrict__ h,
                                                unsigned short* __restrict__ rnext,
                                                const unsigned* __restrict__ W1p,
                                                const float* __restrict__ b1,
                                                const float* __restrict__ g1,
                                                const float* __restrict__ bb1,
                                                const unsigned* __restrict__ W2p,
                                                const float* __restrict__ b2,
                                                const float* __restrict__ gn,
                                                const float* __restrict__ bn, int residual) {
  __shared__ unsigned short scr[4][16][136];  // wave-private U scratch
  int t = threadIdx.x;
  int w = t >> 6, lane = t & 63;
  int wid = blockIdx.x * 4 + w;
  if (wid >= N_NODES / 16) return;  // 6250 waves exactly
  int node0 = wid * 16;
  int fr = lane & 15, fq = lane >> 4;

  // GEMM1: C1[16][128] = X[16][64] @ W1
  bf16x8 xa0 = *(const bf16x8*)&xin32[(size_t)(node0 + fr) * 32 + fq * 4];
  bf16x8 xa1 = *(const bf16x8*)&xin32[(size_t)(node0 + fr) * 32 + 16 + fq * 4];
  f32x4 c1[8];
#pragma unroll
  for (int nt = 0; nt < 8; nt++) {
    f32x4 a = {0.f, 0.f, 0.f, 0.f};
    bf16x8 w0 = *(const bf16x8*)&W1p[(size_t)(nt * 16 + fr) * 36 + fq * 4];
    bf16x8 w1 = *(const bf16x8*)&W1p[(size_t)(nt * 16 + fr) * 36 + 16 + fq * 4];
    a = __builtin_amdgcn_mfma_f32_16x16x32_bf16(xa0, w0, a, 0, 0, 0);
    a = __builtin_amdgcn_mfma_f32_16x16x32_bf16(xa1, w1, a, 0, 0, 0);
    c1[nt] = a;
  }
  // LN over 128 cols per row; lane holds C1[row=fq*4+r][col=nt*16+fr]
  float b1v[8], g1v[8], bb1v[8];
#pragma unroll
  for (int nt = 0; nt < 8; nt++) {
    b1v[nt] = b1[nt * 16 + fr];
    g1v[nt] = g1[nt * 16 + fr];
    bb1v[nt] = bb1[nt * 16 + fr];
  }
#pragma unroll
  for (int r = 0; r < 4; r++) {
    float s1 = 0.f, s2 = 0.f;
#pragma unroll
    for (int nt = 0; nt < 8; nt++) {
      float u = c1[nt][r] + b1v[nt];
      s1 += u;
      s2 += u * u;
    }
#pragma unroll
    for (int m = 1; m < 16; m <<= 1) {
      s1 += __shfl_xor(s1, m, 64);
      s2 += __shfl_xor(s2, m, 64);
    }
    float mu = s1 * (1.f / 128.f);
    float var = s2 * (1.f / 128.f) - mu * mu;
    float rs = rsqrtf(var + 1e-5f);
    int row = fq * 4 + r;
#pragma unroll
    for (int nt = 0; nt < 8; nt++) {
      float u = c1[nt][r] + b1v[nt];
      u = fmaxf((u - mu) * rs * g1v[nt] + bb1v[nt], 0.f);
      scr[w][row][nt * 16 + fr] = (unsigned short)bf16rne(u);
    }
  }
  // GEMM2: C2[16][64] = U[16][128] @ W2 (A-frag k = s*32+fq*8+e)
  bf16x8 ua[4];
#pragma unroll
  for (int s = 0; s < 4; s++) ua[s] = *(const bf16x8*)&scr[w][fr][s * 32 + fq * 8];
  f32x4 c2[4];
#pragma unroll
  for (int nt = 0; nt < 4; nt++) {
    f32x4 a = {0.f, 0.f, 0.f, 0.f};
#pragma unroll
    for (int s = 0; s < 4; s++) {
      bf16x8 wf = *(const bf16x8*)&W2p[(size_t)(nt * 16 + fr) * 68 + s * 16 + fq * 4];
      a = __builtin_amdgcn_mfma_f32_16x16x32_bf16(ua[s], wf, a, 0, 0, 0);
    }
    c2[nt] = a;
  }
  // epilogue: +b2 (+res) -> h f32; prenorm -> rnext bf16
  float b2v[4], gv[4], bv[4];
#pragma unroll
  for (int nt = 0; nt < 4; nt++) {
    b2v[nt] = b2[nt * 16 + fr];
    gv[nt] = gn[nt * 16 + fr];
    bv[nt] = bn[nt * 16 + fr];
  }
#pragma unroll
  for (int r = 0; r < 4; r++) {
    int row = fq * 4 + r;
    size_t base = (size_t)(node0 + row) * DIM_H;
    float o0, o1, o2, o3, s1, s2;
    o0 = c2[0][r] + b2v[0];
    o1 = c2[1][r] + b2v[1];
    o2 = c2[2][r] + b2v[2];
    o3 = c2[3][r] + b2v[3];
    if (residual) {
      o0 += h[base + 0 * 16 + fr];
      o1 += h[base + 1 * 16 + fr];
      o2 += h[base + 2 * 16 + fr];
      o3 += h[base + 3 * 16 + fr];
    }
    s1 = (o0 + o1) + (o2 + o3);
    s2 = (o0 * o0 + o1 * o1) + (o2 * o2 + o3 * o3);
#pragma unroll
    for (int m = 1; m < 16; m <<= 1) {
      s1 += __shfl_xor(s1, m, 64);
      s2 += __shfl_xor(s2, m, 64);
    }
    float mu = s1 * (1.f / 64.f);
    float var = s2 * (1.f / 64.f) - mu * mu;
    float rs = rsqrtf(var + 1e-5f);
    h[base + 0 * 16 + fr] = o0;
    h[base + 1 * 16 + fr] = o1;
    h[base + 2 * 16 + fr] = o2;
    h[base + 3 * 16 + fr] = o3;
    rnext[base + 0 * 16 + fr] = (unsigned short)bf16rne(fmaxf((o0 - mu) * rs * gv[0] + bv[0], 0.f));
    rnext[base + 1 * 16 + fr] = (unsigned short)bf16rne(fmaxf((o1 - mu) * rs * gv[1] + bv[1], 0.f));
    rnext[base + 2 * 16 + fr] = (unsigned short)bf16rne(fmaxf((o2 - mu) * rs * gv[2] + bv[2], 0.f));
    rnext[base + 3 * 16 + fr] = (unsigned short)bf16rne(fmaxf((o3 - mu) * rs * gv[3] + bv[3], 0.f));
  }
}

// ---------------- final via MFMA: out = rB @ lin_W + lin_b ------------------
// R13-proven, unchanged.

__global__ __launch_bounds__(256, 2) void k_final(const unsigned* __restrict__ rB32,
                                                  const unsigned* __restrict__ Wp,
                                                  const float* __restrict__ bias,
                                                  float* __restrict__ out) {
  int t = threadIdx.x;
  int w = t >> 6, lane = t & 63;
  int wid = blockIdx.x * 4 + w;
  if (wid >= N_NODES / 16) return;
  int node0 = wid * 16;
  int fr = lane & 15, fq = lane >> 4;
  bf16x8 xa0 = *(const bf16x8*)&rB32[(size_t)(node0 + fr) * 32 + fq * 4];
  bf16x8 xa1 = *(const bf16x8*)&rB32[(size_t)(node0 + fr) * 32 + 16 + fq * 4];
#pragma unroll
  for (int nt = 0; nt < 7; nt++) {
    f32x4 a = {0.f, 0.f, 0.f, 0.f};
    bf16x8 w0 = *(const bf16x8*)&Wp[(size_t)(nt * 16 + fr) * 36 + fq * 4];
    bf16x8 w1 = *(const bf16x8*)&Wp[(size_t)(nt * 16 + fr) * 36 + 16 + fq * 4];
    a = __builtin_amdgcn_mfma_f32_16x16x32_bf16(xa0, w0, a, 0, 0, 0);
    a = __builtin_amdgcn_mfma_f32_16x16x32_bf16(xa1, w1, a, 0, 0, 0);
    float bv = bias[nt * 16 + fr];
#pragma unroll
    for (int r = 0; r < 4; r++)
      out[(size_t)(node0 + fq * 4 + r) * DIM_OUT + nt * 16 + fr] = a[r] + bv;
  }
}

// ---------------- launch ----------------

extern "C" void kernel_launch(void* const* d_in, const int* in_sizes, int n_in,
                              void* d_out, int out_size, void* d_ws, size_t ws_size,
                              hipStream_t stream) {
  const float* x = (const float*)d_in[0];
  const int* ei = (const int*)d_in[1];
  const float* encW = (const float*)d_in[2];
  const float* encb = (const float*)d_in[3];
  const float* t_arr = (const float*)d_in[4];
  const float* sc_arr = (const float*)d_in[5];
  const float* W1 = (const float*)d_in[6];
  const float* b1 = (const float*)d_in[7];
  const float* g1 = (const float*)d_in[8];
  const float* bb1 = (const float*)d_in[9];
  const float* W2 = (const float*)d_in[10];
  const float* b2 = (const float*)d_in[11];
  const float* ng = (const float*)d_in[12];
  const float* nbias = (const float*)d_in[13];
  const float* linW = (const float*)d_in[14];
  const float* linb = (const float*)d_in[15];

  float* hA = (float*)d_ws;                                             // N*64 f32 h-state
  unsigned short* mCbf = (unsigned short*)(hA + (size_t)N_NODES * DIM_H);  // N*64 bf16 edge-out
  unsigned short* rBf = mCbf + (size_t)N_NODES * DIM_H;                 // N*64 bf16
  unsigned short* hBf = rBf + (size_t)N_NODES * DIM_H;                  // N*64 bf16
  int* ssrc = (int*)(hBf + (size_t)N_NODES * DIM_H);                    // E
  int* rank = ssrc + N_EDGES;                                           // E
  int* offs = rank + N_EDGES;                                           // N+1
  int* counts = offs + (N_NODES + 1);                                   // N
  int* bsums = counts + N_NODES;                                        // <=512
  unsigned* W1p = (unsigned*)(((uintptr_t)(bsums + 512) + 15) & ~(uintptr_t)15);
  unsigned* W2p = W1p + (size_t)N_LAYERS * W1P_SZ;
  unsigned* Wep = W2p + (size_t)N_LAYERS * W2P_SZ;
  unsigned* Wfp = Wep + WEP_SZ;

  const int* srcI = ei;
  const int* dstI = ei + N_EDGES;

  const int nbScan = (N_NODES + 255) / 256;  // 391
  const int nbEdge = (N_EDGES + 255) / 256;  // 4688
  const int nbWave = (N_NODES / 16 + 3) / 4;  // 1563 blocks of 4 waves

  // CSR build (rank-based: no cursor pass, no scatter atomics) + weight pre-pack
  k_zero_i<<<nbScan, 256, 0, stream>>>(counts, N_NODES);
  k_hist<<<nbEdge, 256, 0, stream>>>(dstI, counts, rank);
  k_prepack<<<dim3(3, N_LAYERS), 256, 0, stream>>>(W1, W2, W1p, W2p);
  k_prepack_enc<<<3, 256, 0, stream>>>(encW, Wep);
  k_prepack_fin<<<3, 256, 0, stream>>>(linW, Wfp);
  k_scan1<<<nbScan, 256, 0, stream>>>(counts, bsums);
  k_scan2<<<1, 512, 0, stream>>>(bsums, nbScan);
  k_scan3<<<nbScan, 256, 0, stream>>>(counts, bsums, offs);
  k_scatter<<<nbEdge, 256, 0, stream>>>(srcI, dstI, rank, offs, ssrc);

  // encoder (MFMA) -> hBf (bf16)
  k_encoder<<<N_NODES / 32, 256, 0, stream>>>(x, Wep, encb, hBf);

  // layers 0..6: gather(paired bf16) -> mCbf -> wave-autonomous MFMA MLP
  for (int i = 0; i < N_LAYERS; i++) {
    int nx = (i + 1 < N_LAYERS) ? (i + 1) : 0;
    const unsigned* gin32 = (const unsigned*)((i == 0) ? hBf : rBf);
    k_edge<<<N_NODES / 8, 256, 0, stream>>>(gin32, ssrc, offs, t_arr, sc_arr, i,
                                            (unsigned*)mCbf);
    k_mlp<<<nbWave, 256, 0, stream>>>(
        (const unsigned*)mCbf, hA, rBf, W1p + (size_t)i * W1P_SZ, b1 + i * DIM_H2,
        g1 + i * DIM_H2, bb1 + i * DIM_H2, W2p + (size_t)i * W2P_SZ, b2 + i * DIM_H,
        ng + nx * DIM_H, nbias + nx * DIM_H, (i > 0) ? 1 : 0);
  }

  // final: rBf = bf16(relu(LN(h, nrm_0))); MFMA GEMM straight to out
  k_final<<<nbWave, 256, 0, stream>>>((const unsigned*)rBf, Wfp, linb, (float*)d_out);
}

// Round 17
// 555.789 us; speedup vs baseline: 3.0713x; 1.0536x over previous
//
#include <hip/hip_runtime.h>

#define N_NODES 100000
#define N_EDGES 1200000
#define DIM_IN 128
#define DIM_H 64
#define DIM_H2 128
#define DIM_OUT 112
#define N_LAYERS 7

// pre-packed weight sizes (uints), padded strides baked in
#define W1P_SZ 4608  // 128 n * 36 kp-stride (kp<32 valid)
#define W2P_SZ 4352  // 64 n * 68 kp-stride (kp<64 valid)
#define WEP_SZ 4352  // encoder: 64 n * 68 kp-stride (kp<64 valid)
#define WFP_SZ 4032  // final: 112 n * 36 kp-stride (kp<32 valid)

typedef __attribute__((ext_vector_type(8))) short bf16x8;
typedef __attribute__((ext_vector_type(4))) float f32x4;

__device__ __forceinline__ float wsum(float v) {
#pragma unroll
  for (int m = 1; m < 64; m <<= 1) v += __shfl_xor(v, m, 64);
  return v;
}

// bf16 pack/unpack: bf16->f32 is just <<16 (bit ops, no cvt instruction)
__device__ __forceinline__ unsigned bf16rne(float f) {
  unsigned u = __float_as_uint(f);
  return (u + 0x7fffu + ((u >> 16) & 1u)) >> 16;
}
__device__ __forceinline__ unsigned pack2bf(float lo, float hi) {
  return bf16rne(lo) | (bf16rne(hi) << 16);
}
__device__ __forceinline__ float bflo(unsigned p) { return __uint_as_float(p << 16); }
__device__ __forceinline__ float bfhi(unsigned p) { return __uint_as_float(p & 0xffff0000u); }
__device__ __forceinline__ float bfu(unsigned short u) {
  return __uint_as_float(((unsigned)u) << 16);
}
// raw v_exp_f32 (2^x); __exp2f does not exist in HIP device code (R14 lesson)
__device__ __forceinline__ float exp2r(float x) { return __builtin_amdgcn_exp2f(x); }

// ---------------- preprocessing: CSR build (sharded, atomic-local) ----------

__global__ void k_zero_i(int* __restrict__ p, int n) {
  int i = blockIdx.x * 256 + threadIdx.x;
  if (i < n) p[i] = 0;
}

// Sharded hist: shard = blockIdx&7 (XCD-local under round-robin dispatch) ->
// counter-line atomics stay on one XCD (R16: 42MB WRITE was cross-XCD
// ping-pong). rank[e] = in-shard rank (coalesced write).
__global__ void k_hist(const int* __restrict__ dst, int* __restrict__ counts8,
                       int* __restrict__ rank) {
  int e = blockIdx.x * 256 + threadIdx.x;
  int p = blockIdx.x & 7;
  if (e < N_EDGES) rank[e] = atomicAdd(&counts8[(size_t)p * N_NODES + dst[e]], 1);
}

__global__ void k_scan1(const int* __restrict__ counts8, int* __restrict__ bsums) {
  __shared__ int sd[256];
  int t = threadIdx.x;
  int i = blockIdx.x * 256 + t;
  int v = 0;
  if (i < N_NODES) {
#pragma unroll
    for (int p = 0; p < 8; p++) v += counts8[(size_t)p * N_NODES + i];
  }
  sd[t] = v;
  __syncthreads();
  for (int s = 128; s > 0; s >>= 1) {
    if (t < s) sd[t] += sd[t + s];
    __syncthreads();
  }
  if (t == 0) bsums[blockIdx.x] = sd[0];
}

__global__ void k_scan2(int* __restrict__ bsums, int nb) {
  __shared__ int sd[512];
  int t = threadIdx.x;
  int v = (t < nb) ? bsums[t] : 0;
  sd[t] = v;
  __syncthreads();
  for (int o = 1; o < 512; o <<= 1) {
    int add = (t >= o) ? sd[t - o] : 0;
    __syncthreads();
    sd[t] += add;
    __syncthreads();
  }
  if (t < nb) bsums[t] = sd[t] - v;  // exclusive
}

// scan3: offs[] from totals; rewrite counts8[p][d] in place to the per-d
// shard-exclusive prefix (each thread owns column d -> safe).
__global__ void k_scan3(int* __restrict__ counts8, const int* __restrict__ bsums,
                        int* __restrict__ offs) {
  __shared__ int sd[256];
  int t = threadIdx.x;
  int i = blockIdx.x * 256 + t;
  int c[8];
  int v = 0;
  if (i < N_NODES) {
#pragma unroll
    for (int p = 0; p < 8; p++) {
      c[p] = counts8[(size_t)p * N_NODES + i];
      v += c[p];
    }
  }
  sd[t] = v;
  __syncthreads();
  for (int o = 1; o < 256; o <<= 1) {
    int add = (t >= o) ? sd[t - o] : 0;
    __syncthreads();
    sd[t] += add;
    __syncthreads();
  }
  int excl = sd[t] - v + bsums[blockIdx.x];
  if (i < N_NODES) {
    offs[i] = excl;
    int run = 0;
#pragma unroll
    for (int p = 0; p < 8; p++) {
      counts8[(size_t)p * N_NODES + i] = run;
      run += c[p];
    }
  }
  if (i == N_NODES - 1) offs[N_NODES] = excl + v;  // = E
}

// atomic-free scatter: shard of edge e is (e>>8)&7 (hist blockIdx = e/256).
__global__ void k_scatter(const int* __restrict__ src, const int* __restrict__ dst,
                          const int* __restrict__ rank, const int* __restrict__ offs,
                          const int* __restrict__ soff8, int* __restrict__ ssrc) {
  int e = blockIdx.x * 256 + threadIdx.x;
  if (e < N_EDGES) {
    int d = dst[e];
    int part = (e >> 8) & 7;
    int p = offs[d] + soff8[(size_t)part * N_NODES + d] + rank[e];
    ssrc[p] = src[e];
  }
}

// ---------------- weight pre-pack (once per launch) ----------------
// W1p[L][n*36+kp] = pack2bf(W1[L][2kp][n], W1[L][2kp+1][n]); W2p same s68.
__global__ void k_prepack(const float* __restrict__ W1, const float* __restrict__ W2,
                          unsigned* __restrict__ W1p, unsigned* __restrict__ W2p) {
  int L = blockIdx.y;
  const float* w1 = W1 + (size_t)L * DIM_H * DIM_H2;
  const float* w2 = W2 + (size_t)L * DIM_H2 * DIM_H;
  unsigned* o1 = W1p + (size_t)L * W1P_SZ;
  unsigned* o2 = W2p + (size_t)L * W2P_SZ;
  for (int i = blockIdx.x * 256 + threadIdx.x; i < W1P_SZ; i += gridDim.x * 256) {
    int n = i / 36, kp = i - n * 36;
    o1[i] = (kp < 32) ? pack2bf(w1[(size_t)(2 * kp) * DIM_H2 + n],
                                w1[(size_t)(2 * kp + 1) * DIM_H2 + n]) : 0u;
  }
  for (int i = blockIdx.x * 256 + threadIdx.x; i < W2P_SZ; i += gridDim.x * 256) {
    int n = i / 68, kp = i - n * 68;
    o2[i] = (kp < 64) ? pack2bf(w2[(size_t)(2 * kp) * DIM_H + n],
                                w2[(size_t)(2 * kp + 1) * DIM_H + n]) : 0u;
  }
}

// encoder weights: encW [128][64] -> Wp [n<64][kp<64] stride 68 (W2 format)
__global__ void k_prepack_enc(const float* __restrict__ W, unsigned* __restrict__ Wp) {
  for (int i = blockIdx.x * 256 + threadIdx.x; i < WEP_SZ; i += gridDim.x * 256) {
    int n = i / 68, kp = i - n * 68;
    Wp[i] = (kp < 64) ? pack2bf(W[(size_t)(2 * kp) * DIM_H + n],
                                W[(size_t)(2 * kp + 1) * DIM_H + n]) : 0u;
  }
}

// final weights: linW [64][112] -> Wp [n<112][kp<32] stride 36
__global__ void k_prepack_fin(const float* __restrict__ W, unsigned* __restrict__ Wp) {
  for (int i = blockIdx.x * 256 + threadIdx.x; i < WFP_SZ; i += gridDim.x * 256) {
    int n = i / 36, kp = i - n * 36;
    Wp[i] = (kp < 32) ? pack2bf(W[(size_t)(2 * kp) * DIM_OUT + n],
                                W[(size_t)(2 * kp + 1) * DIM_OUT + n]) : 0u;
  }
}

// ---------------- encoder via MFMA: hBf = bf16(x @ enc_W + enc_b) ----------
// R12-proven (passed). K=128, N=64, M=32; wave w owns n-tile w.

__global__ __launch_bounds__(256, 2) void k_encoder(const float* __restrict__ x,
                                                    const unsigned* __restrict__ Wp,
                                                    const float* __restrict__ bias,
                                                    unsigned short* __restrict__ hBf) {
  __shared__ __attribute__((aligned(16))) unsigned sW[WEP_SZ];    // 17.4KB [n<64][kp<64] s68
  __shared__ __attribute__((aligned(16))) unsigned sxp[32 * 68];  // 8.7KB [row][kp<64] s68
  int t = threadIdx.x;
  int node0 = blockIdx.x * 32;
  int w = t >> 6, lane = t & 63;
  int fr = lane & 15, fq = lane >> 4;
  const uint4* wv4 = (const uint4*)Wp;
  for (int i = t; i < WEP_SZ / 4; i += 256) *(uint4*)&sW[i * 4] = wv4[i];
  for (int i = t; i < 2048; i += 256) {  // 32 rows x 64 kp
    int row = i >> 6, kp = i & 63;
    float2 xv = *(const float2*)&x[(size_t)(node0 + row) * DIM_IN + 2 * kp];
    sxp[row * 68 + kp] = pack2bf(xv.x, xv.y);
  }
  __syncthreads();
  f32x4 acc0 = {0.f, 0.f, 0.f, 0.f}, acc1 = acc0;
#pragma unroll
  for (int s = 0; s < 4; s++) {
    int kp0 = s * 16 + fq * 4;
    bf16x8 a0 = *(const bf16x8*)&sxp[fr * 68 + kp0];
    bf16x8 a1 = *(const bf16x8*)&sxp[(16 + fr) * 68 + kp0];
    bf16x8 wf = *(const bf16x8*)&sW[(w * 16 + fr) * 68 + kp0];
    acc0 = __builtin_amdgcn_mfma_f32_16x16x32_bf16(a0, wf, acc0, 0, 0, 0);
    acc1 = __builtin_amdgcn_mfma_f32_16x16x32_bf16(a1, wf, acc1, 0, 0, 0);
  }
  float bv = bias[w * 16 + fr];
#pragma unroll
  for (int r = 0; r < 4; r++) {
    hBf[(size_t)(node0 + fq * 4 + r) * DIM_H + w * 16 + fr] =
        (unsigned short)bf16rne(acc0[r] + bv);
    hBf[(size_t)(node0 + 16 + fq * 4 + r) * DIM_H + w * 16 + fr] =
        (unsigned short)bf16rne(acc1[r] + bv);
  }
}

// ---------------- edge aggregation + MsgNorm (paired, lean, unroll 8) -------
// Half-wave per node, lane covers channels {2cl, 2cl+1}.
// RELU template: layers 1..6 gather rBf = relu(...) >= 0, so fmax is a no-op
// and removed at compile time. Layer 0 (encoder output, signed) keeps it.
// 8/4/1 tail; 8 outstanding 128B gathers per half-wave for L3 latency.

template <int RELU>
__global__ __launch_bounds__(256) void k_edge(const unsigned* __restrict__ xin32,
                                              const int* __restrict__ ssrc,
                                              const int* __restrict__ offs,
                                              const float* __restrict__ t_arr,
                                              const float* __restrict__ sc_arr, int layer,
                                              unsigned* __restrict__ hmid32) {
  int t = threadIdx.x;
  int wave = t >> 6, lane = t & 63;
  int half = lane >> 5, cl = lane & 31;
  int v = blockIdx.x * 8 + wave * 2 + half;
  float c2 = t_arr[layer] * 1.4426950408889634f;  // t * log2(e)
  float sc = sc_arr[layer];
  int beg = offs[v], end = offs[v + 1];
  unsigned cl4 = cl << 2;
  const char* xbase = (const char*)xin32;
  unsigned xp = *(const unsigned*)(xbase + (((unsigned)v << 7) + cl4));
  float xv0 = bflo(xp), xv1 = bfhi(xp);
  float D0 = 0.f, S0 = 0.f, D1 = 0.f, S1 = 0.f;
  float D2 = 0.f, S2 = 0.f, D3 = 0.f, S3 = 0.f;
  float D4 = 0.f, S4 = 0.f, D5 = 0.f, S5 = 0.f;
  float D6 = 0.f, S6 = 0.f, D7 = 0.f, S7 = 0.f;
  int e = beg;
#define CH(u, lo, hi)                                   \
  float lo = RELU ? fmaxf(bflo(u), 0.f) : bflo(u);      \
  float hi = RELU ? fmaxf(bfhi(u), 0.f) : bfhi(u);
  for (; e + 7 < end; e += 8) {
    unsigned o0 = ((unsigned)ssrc[e] << 7) + cl4;
    unsigned o1 = ((unsigned)ssrc[e + 1] << 7) + cl4;
    unsigned o2 = ((unsigned)ssrc[e + 2] << 7) + cl4;
    unsigned o3 = ((unsigned)ssrc[e + 3] << 7) + cl4;
    unsigned o4 = ((unsigned)ssrc[e + 4] << 7) + cl4;
    unsigned o5 = ((unsigned)ssrc[e + 5] << 7) + cl4;
    unsigned o6 = ((unsigned)ssrc[e + 6] << 7) + cl4;
    unsigned o7 = ((unsigned)ssrc[e + 7] << 7) + cl4;
    unsigned u0 = *(const unsigned*)(xbase + o0);
    unsigned u1 = *(const unsigned*)(xbase + o1);
    unsigned u2 = *(const unsigned*)(xbase + o2);
    unsigned u3 = *(const unsigned*)(xbase + o3);
    unsigned u4 = *(const unsigned*)(xbase + o4);
    unsigned u5 = *(const unsigned*)(xbase + o5);
    unsigned u6 = *(const unsigned*)(xbase + o6);
    unsigned u7 = *(const unsigned*)(xbase + o7);
    CH(u0, a0, a1) CH(u1, b0, b1) CH(u2, g0, g1) CH(u3, h0, h1)
    CH(u4, i0, i1) CH(u5, j0, j1) CH(u6, k0, k1) CH(u7, l0, l1)
    float ea0 = exp2r(c2 * a0), ea1 = exp2r(c2 * a1);
    float eb0 = exp2r(c2 * b0), eb1 = exp2r(c2 * b1);
    float eg0 = exp2r(c2 * g0), eg1 = exp2r(c2 * g1);
    float eh0 = exp2r(c2 * h0), eh1 = exp2r(c2 * h1);
    float ei0 = exp2r(c2 * i0), ei1 = exp2r(c2 * i1);
    float ej0 = exp2r(c2 * j0), ej1 = exp2r(c2 * j1);
    float ek0 = exp2r(c2 * k0), ek1 = exp2r(c2 * k1);
    float el0 = exp2r(c2 * l0), el1 = exp2r(c2 * l1);
    D0 += ea0; S0 += a0 * ea0;
    D1 += ea1; S1 += a1 * ea1;
    D2 += eb0; S2 += b0 * eb0;
    D3 += eb1; S3 += b1 * eb1;
    D4 += eg0; S4 += g0 * eg0;
    D5 += eg1; S5 += g1 * eg1;
    D6 += eh0; S6 += h0 * eh0;
    D7 += eh1; S7 += h1 * eh1;
    D0 += ei0; S0 += i0 * ei0;
    D1 += ei1; S1 += i1 * ei1;
    D2 += ej0; S2 += j0 * ej0;
    D3 += ej1; S3 += j1 * ej1;
    D4 += ek0; S4 += k0 * ek0;
    D5 += ek1; S5 += k1 * ek1;
    D6 += el0; S6 += l0 * el0;
    D7 += el1; S7 += l1 * el1;
  }
  if (e + 3 < end) {
    unsigned o0 = ((unsigned)ssrc[e] << 7) + cl4;
    unsigned o1 = ((unsigned)ssrc[e + 1] << 7) + cl4;
    unsigned o2 = ((unsigned)ssrc[e + 2] << 7) + cl4;
    unsigned o3 = ((unsigned)ssrc[e + 3] << 7) + cl4;
    unsigned u0 = *(const unsigned*)(xbase + o0);
    unsigned u1 = *(const unsigned*)(xbase + o1);
    unsigned u2 = *(const unsigned*)(xbase + o2);
    unsigned u3 = *(const unsigned*)(xbase + o3);
    CH(u0, a0, a1) CH(u1, b0, b1) CH(u2, g0, g1) CH(u3, h0, h1)
    float ea0 = exp2r(c2 * a0), ea1 = exp2r(c2 * a1);
    float eb0 = exp2r(c2 * b0), eb1 = exp2r(c2 * b1);
    float eg0 = exp2r(c2 * g0), eg1 = exp2r(c2 * g1);
    float eh0 = exp2r(c2 * h0), eh1 = exp2r(c2 * h1);
    D0 += ea0; S0 += a0 * ea0;
    D1 += ea1; S1 += a1 * ea1;
    D2 += eb0; S2 += b0 * eb0;
    D3 += eb1; S3 += b1 * eb1;
    D4 += eg0; S4 += g0 * eg0;
    D5 += eg1; S5 += g1 * eg1;
    D6 += eh0; S6 += h0 * eh0;
    D7 += eh1; S7 += h1 * eh1;
    e += 4;
  }
  for (; e < end; ++e) {
    unsigned o0 = ((unsigned)ssrc[e] << 7) + cl4;
    unsigned u0 = *(const unsigned*)(xbase + o0);
    CH(u0, a0, a1)
    float ea0 = exp2r(c2 * a0), ea1 = exp2r(c2 * a1);
    D0 += ea0; S0 += a0 * ea0;
    D1 += ea1; S1 += a1 * ea1;
  }
#undef CH
  float Da = (D0 + D2) + (D4 + D6), Sa = (S0 + S2) + (S4 + S6);  // ch 2cl
  float Db = (D1 + D3) + (D5 + D7), Sb = (S1 + S3) + (S5 + S7);  // ch 2cl+1
  int has = (end > beg);
  float agg0 = has ? (Sa / Da + 1e-7f) : 0.f;
  float agg1 = has ? (Sb / Db + 1e-7f) : 0.f;
  float na = agg0 * agg0 + agg1 * agg1;
  float nx = xv0 * xv0 + xv1 * xv1;
#pragma unroll
  for (int m = 1; m < 32; m <<= 1) {
    na += __shfl_xor(na, m, 64);
    nx += __shfl_xor(nx, m, 64);
  }
  float inv = sc * sqrtf(nx) / fmaxf(sqrtf(na), 1e-12f);
  float r0 = xv0 + inv * agg0;
  float r1 = xv1 + inv * agg1;
  hmid32[(size_t)v * 32 + cl] = pack2bf(r0, r1);
}

// ---------------- GENConv MLP: wave-autonomous, barrier-free MFMA ----------
// R13-proven, unchanged.

__global__ __launch_bounds__(256, 2) void k_mlp(const unsigned* __restrict__ xin32,
                                                float* __restrict__ h,
                                                unsigned short* __restrict__ rnext,
                                                const unsigned* __restrict__ W1p,
                                                const float* __restrict__ b1,
                                                const float* __restrict__ g1,
                                                const float* __restrict__ bb1,
                                                const unsigned* __restrict__ W2p,
                                                const float* __restrict__ b2,
                                                const float* __restrict__ gn,
                                                const float* __restrict__ bn, int residual) {
  __shared__ unsigned short scr[4][16][136];  // wave-private U scratch
  int t = threadIdx.x;
  int w = t >> 6, lane = t & 63;
  int wid = blockIdx.x * 4 + w;
  if (wid >= N_NODES / 16) return;  // 6250 waves exactly
  int node0 = wid * 16;
  int fr = lane & 15, fq = lane >> 4;

  // GEMM1: C1[16][128] = X[16][64] @ W1
  bf16x8 xa0 = *(const bf16x8*)&xin32[(size_t)(node0 + fr) * 32 + fq * 4];
  bf16x8 xa1 = *(const bf16x8*)&xin32[(size_t)(node0 + fr) * 32 + 16 + fq * 4];
  f32x4 c1[8];
#pragma unroll
  for (int nt = 0; nt < 8; nt++) {
    f32x4 a = {0.f, 0.f, 0.f, 0.f};
    bf16x8 w0 = *(const bf16x8*)&W1p[(size_t)(nt * 16 + fr) * 36 + fq * 4];
    bf16x8 w1 = *(const bf16x8*)&W1p[(size_t)(nt * 16 + fr) * 36 + 16 + fq * 4];
    a = __builtin_amdgcn_mfma_f32_16x16x32_bf16(xa0, w0, a, 0, 0, 0);
    a = __builtin_amdgcn_mfma_f32_16x16x32_bf16(xa1, w1, a, 0, 0, 0);
    c1[nt] = a;
  }
  // LN over 128 cols per row; lane holds C1[row=fq*4+r][col=nt*16+fr]
  float b1v[8], g1v[8], bb1v[8];
#pragma unroll
  for (int nt = 0; nt < 8; nt++) {
    b1v[nt] = b1[nt * 16 + fr];
    g1v[nt] = g1[nt * 16 + fr];
    bb1v[nt] = bb1[nt * 16 + fr];
  }
#pragma unroll
  for (int r = 0; r < 4; r++) {
    float s1 = 0.f, s2 = 0.f;
#pragma unroll
    for (int nt = 0; nt < 8; nt++) {
      float u = c1[nt][r] + b1v[nt];
      s1 += u;
      s2 += u * u;
    }
#pragma unroll
    for (int m = 1; m < 16; m <<= 1) {
      s1 += __shfl_xor(s1, m, 64);
      s2 += __shfl_xor(s2, m, 64);
    }
    float mu = s1 * (1.f / 128.f);
    float var = s2 * (1.f / 128.f) - mu * mu;
    float rs = rsqrtf(var + 1e-5f);
    int row = fq * 4 + r;
#pragma unroll
    for (int nt = 0; nt < 8; nt++) {
      float u = c1[nt][r] + b1v[nt];
      u = fmaxf((u - mu) * rs * g1v[nt] + bb1v[nt], 0.f);
      scr[w][row][nt * 16 + fr] = (unsigned short)bf16rne(u);
    }
  }
  // GEMM2: C2[16][64] = U[16][128] @ W2 (A-frag k = s*32+fq*8+e)
  bf16x8 ua[4];
#pragma unroll
  for (int s = 0; s < 4; s++) ua[s] = *(const bf16x8*)&scr[w][fr][s * 32 + fq * 8];
  f32x4 c2[4];
#pragma unroll
  for (int nt = 0; nt < 4; nt++) {
    f32x4 a = {0.f, 0.f, 0.f, 0.f};
#pragma unroll
    for (int s = 0; s < 4; s++) {
      bf16x8 wf = *(const bf16x8*)&W2p[(size_t)(nt * 16 + fr) * 68 + s * 16 + fq * 4];
      a = __builtin_amdgcn_mfma_f32_16x16x32_bf16(ua[s], wf, a, 0, 0, 0);
    }
    c2[nt] = a;
  }
  // epilogue: +b2 (+res) -> h f32; prenorm -> rnext bf16
  float b2v[4], gv[4], bv[4];
#pragma unroll
  for (int nt = 0; nt < 4; nt++) {
    b2v[nt] = b2[nt * 16 + fr];
    gv[nt] = gn[nt * 16 + fr];
    bv[nt] = bn[nt * 16 + fr];
  }
#pragma unroll
  for (int r = 0; r < 4; r++) {
    int row = fq * 4 + r;
    size_t base = (size_t)(node0 + row) * DIM_H;
    float o0, o1, o2, o3, s1, s2;
    o0 = c2[0][r] + b2v[0];
    o1 = c2[1][r] + b2v[1];
    o2 = c2[2][r] + b2v[2];
    o3 = c2[3][r] + b2v[3];
    if (residual) {
      o0 += h[base + 0 * 16 + fr];
      o1 += h[base + 1 * 16 + fr];
      o2 += h[base + 2 * 16 + fr];
      o3 += h[base + 3 * 16 + fr];
    }
    s1 = (o0 + o1) + (o2 + o3);
    s2 = (o0 * o0 + o1 * o1) + (o2 * o2 + o3 * o3);
#pragma unroll
    for (int m = 1; m < 16; m <<= 1) {
      s1 += __shfl_xor(s1, m, 64);
      s2 += __shfl_xor(s2, m, 64);
    }
    float mu = s1 * (1.f / 64.f);
    float var = s2 * (1.f / 64.f) - mu * mu;
    float rs = rsqrtf(var + 1e-5f);
    h[base + 0 * 16 + fr] = o0;
    h[base + 1 * 16 + fr] = o1;
    h[base + 2 * 16 + fr] = o2;
    h[base + 3 * 16 + fr] = o3;
    rnext[base + 0 * 16 + fr] = (unsigned short)bf16rne(fmaxf((o0 - mu) * rs * gv[0] + bv[0], 0.f));
    rnext[base + 1 * 16 + fr] = (unsigned short)bf16rne(fmaxf((o1 - mu) * rs * gv[1] + bv[1], 0.f));
    rnext[base + 2 * 16 + fr] = (unsigned short)bf16rne(fmaxf((o2 - mu) * rs * gv[2] + bv[2], 0.f));
    rnext[base + 3 * 16 + fr] = (unsigned short)bf16rne(fmaxf((o3 - mu) * rs * gv[3] + bv[3], 0.f));
  }
}

// ---------------- final via MFMA: out = rB @ lin_W + lin_b ------------------
// R13-proven, unchanged.

__global__ __launch_bounds__(256, 2) void k_final(const unsigned* __restrict__ rB32,
                                                  const unsigned* __restrict__ Wp,
                                                  const float* __restrict__ bias,
                                                  float* __restrict__ out) {
  int t = threadIdx.x;
  int w = t >> 6, lane = t & 63;
  int wid = blockIdx.x * 4 + w;
  if (wid >= N_NODES / 16) return;
  int node0 = wid * 16;
  int fr = lane & 15, fq = lane >> 4;
  bf16x8 xa0 = *(const bf16x8*)&rB32[(size_t)(node0 + fr) * 32 + fq * 4];
  bf16x8 xa1 = *(const bf16x8*)&rB32[(size_t)(node0 + fr) * 32 + 16 + fq * 4];
#pragma unroll
  for (int nt = 0; nt < 7; nt++) {
    f32x4 a = {0.f, 0.f, 0.f, 0.f};
    bf16x8 w0 = *(const bf16x8*)&Wp[(size_t)(nt * 16 + fr) * 36 + fq * 4];
    bf16x8 w1 = *(const bf16x8*)&Wp[(size_t)(nt * 16 + fr) * 36 + 16 + fq * 4];
    a = __builtin_amdgcn_mfma_f32_16x16x32_bf16(xa0, w0, a, 0, 0, 0);
    a = __builtin_amdgcn_mfma_f32_16x16x32_bf16(xa1, w1, a, 0, 0, 0);
    float bv = bias[nt * 16 + fr];
#pragma unroll
    for (int r = 0; r < 4; r++)
      out[(size_t)(node0 + fq * 4 + r) * DIM_OUT + nt * 16 + fr] = a[r] + bv;
  }
}

// ---------------- launch ----------------

extern "C" void kernel_launch(void* const* d_in, const int* in_sizes, int n_in,
                              void* d_out, int out_size, void* d_ws, size_t ws_size,
                              hipStream_t stream) {
  const float* x = (const float*)d_in[0];
  const int* ei = (const int*)d_in[1];
  const float* encW = (const float*)d_in[2];
  const float* encb = (const float*)d_in[3];
  const float* t_arr = (const float*)d_in[4];
  const float* sc_arr = (const float*)d_in[5];
  const float* W1 = (const float*)d_in[6];
  const float* b1 = (const float*)d_in[7];
  const float* g1 = (const float*)d_in[8];
  const float* bb1 = (const float*)d_in[9];
  const float* W2 = (const float*)d_in[10];
  const float* b2 = (const float*)d_in[11];
  const float* ng = (const float*)d_in[12];
  const float* nbias = (const float*)d_in[13];
  const float* linW = (const float*)d_in[14];
  const float* linb = (const float*)d_in[15];

  float* hA = (float*)d_ws;                                             // N*64 f32 h-state
  unsigned short* mCbf = (unsigned short*)(hA + (size_t)N_NODES * DIM_H);  // N*64 bf16 edge-out
  unsigned short* rBf = mCbf + (size_t)N_NODES * DIM_H;                 // N*64 bf16
  unsigned short* hBf = rBf + (size_t)N_NODES * DIM_H;                  // N*64 bf16
  int* ssrc = (int*)(hBf + (size_t)N_NODES * DIM_H);                    // E
  int* rank = ssrc + N_EDGES;                                           // E
  int* offs = rank + N_EDGES;                                           // N+1
  int* counts8 = offs + (N_NODES + 1);                                  // 8*N
  int* bsums = counts8 + 8 * N_NODES;                                   // <=512
  unsigned* W1p = (unsigned*)(((uintptr_t)(bsums + 512) + 15) & ~(uintptr_t)15);
  unsigned* W2p = W1p + (size_t)N_LAYERS * W1P_SZ;
  unsigned* Wep = W2p + (size_t)N_LAYERS * W2P_SZ;
  unsigned* Wfp = Wep + WEP_SZ;

  const int* srcI = ei;
  const int* dstI = ei + N_EDGES;

  const int nbScan = (N_NODES + 255) / 256;  // 391
  const int nbEdge = (N_EDGES + 255) / 256;  // 4688
  const int nbWave = (N_NODES / 16 + 3) / 4;  // 1563 blocks of 4 waves

  // CSR build (sharded hist, atomic-free scatter) + weight pre-pack
  k_zero_i<<<(8 * N_NODES + 255) / 256, 256, 0, stream>>>(counts8, 8 * N_NODES);
  k_hist<<<nbEdge, 256, 0, stream>>>(dstI, counts8, rank);
  k_prepack<<<dim3(3, N_LAYERS), 256, 0, stream>>>(W1, W2, W1p, W2p);
  k_prepack_enc<<<3, 256, 0, stream>>>(encW, Wep);
  k_prepack_fin<<<3, 256, 0, stream>>>(linW, Wfp);
  k_scan1<<<nbScan, 256, 0, stream>>>(counts8, bsums);
  k_scan2<<<1, 512, 0, stream>>>(bsums, nbScan);
  k_scan3<<<nbScan, 256, 0, stream>>>(counts8, bsums, offs);
  k_scatter<<<nbEdge, 256, 0, stream>>>(srcI, dstI, rank, offs, counts8, ssrc);

  // encoder (MFMA) -> hBf (bf16)
  k_encoder<<<N_NODES / 32, 256, 0, stream>>>(x, Wep, encb, hBf);

  // layers 0..6: gather(paired bf16) -> mCbf -> wave-autonomous MFMA MLP
  for (int i = 0; i < N_LAYERS; i++) {
    int nx = (i + 1 < N_LAYERS) ? (i + 1) : 0;
    const unsigned* gin32 = (const unsigned*)((i == 0) ? hBf : rBf);
    if (i == 0)
      k_edge<1><<<N_NODES / 8, 256, 0, stream>>>(gin32, ssrc, offs, t_arr, sc_arr, i,
                                                 (unsigned*)mCbf);
    else
      k_edge<0><<<N_NODES / 8, 256, 0, stream>>>(gin32, ssrc, offs, t_arr, sc_arr, i,
                                                 (unsigned*)mCbf);
    k_mlp<<<nbWave, 256, 0, stream>>>(
        (const unsigned*)mCbf, hA, rBf, W1p + (size_t)i * W1P_SZ, b1 + i * DIM_H2,
        g1 + i * DIM_H2, bb1 + i * DIM_H2, W2p + (size_t)i * W2P_SZ, b2 + i * DIM_H,
        ng + nx * DIM_H, nbias + nx * DIM_H, (i > 0) ? 1 : 0);
  }

  // final: rBf = bf16(relu(LN(h, nrm_0))); MFMA GEMM straight to out
  k_final<<<nbWave, 256, 0, stream>>>((const unsigned*)rBf, Wfp, linb, (float*)d_out);
}